// Round 7
// baseline (995.745 us; speedup 1.0000x reference)
//
#include <hip/hip_runtime.h>
#include <hip/hip_bf16.h>
#include <math.h>

#define NUM_NET 5
#define NN 10000
#define NE 160000
#define BB 512
#define FXD 62
#define FXT 954
#define MP 10112  // NN padded to multiple of 128

typedef __bf16 bf16x8 __attribute__((ext_vector_type(8)));
typedef float f32x4 __attribute__((ext_vector_type(4)));
typedef __hip_bfloat16 bf16;

// ---------------- helpers (inputs/outputs are f32 — R7-verified) ----------------
__device__ __forceinline__ float ldf(const void* p, size_t i) {
  return ((const float*)p)[i];
}
__device__ __forceinline__ float lky(float v) { return v > 0.f ? v : 0.2f * v; }
__device__ __forceinline__ float eluf(float v) { return v > 0.f ? v : (__expf(v) - 1.f); }
__device__ __forceinline__ unsigned int packbf(float a, float b) {
  __hip_bfloat162 t;
  t.x = __float2bfloat16(a);
  t.y = __float2bfloat16(b);
  return *(unsigned int*)&t;  // a in low 16, b in high 16
}

// ---------------- mega convert: flattened exact grid (no no-op blocks) ----------------
struct ConvDesc {
  const void* src;
  bf16* dst;
  int M, K, Mp, Kp, mult, add, batch, rowBlocks;
};
struct ConvTable { ConvDesc d[11]; int blk0[12]; };

__global__ void convert_all_kernel(ConvTable tab) {
  int bid = blockIdx.x;
  int di = 0;
#pragma unroll
  for (int d = 1; d < 11; d++) di += (bid >= tab.blk0[d]);
  ConvDesc c = tab.d[di];
  int local = bid - tab.blk0[di];
  int b = local / c.rowBlocks;
  int rb = local - b * c.rowBlocks;
  int wave = threadIdx.x >> 6, lane = threadIdx.x & 63;
  int r = rb * 4 + wave;
  if (r >= c.Mp) return;
  const float* srow = (const float*)c.src + ((size_t)b * c.M + r) * c.K;
  bf16* drow = c.dst + (((size_t)(b * c.mult + c.add)) * c.Mp + r) * c.Kp;
  bool rowok = r < c.M;
  for (int k = lane; k < c.Kp; k += 64) {
    float v = (rowok && k < c.K) ? srow[k] : 0.f;
    drow[k] = __float2bfloat16(v);
  }
}

// ---------------- CSR build (planes = net*2+br) ----------------
__global__ void hist_kernel(const int* __restrict__ ei1, const int* __restrict__ ei2,
                            int* __restrict__ counts) {
  int z = blockIdx.z;
  int br = z & 1, net = z >> 1;
  const int* base = (br ? ei2 : ei1) + (size_t)net * 2 * NE;
  const int* dst = base + NE;
  int* cnt = counts + (size_t)z * NN;
  int i = blockIdx.x * 256 + threadIdx.x;
  if (i < NE) atomicAdd(&cnt[dst[i]], 1);
}

// 4-wide scan: 1024 counts per round
__global__ void scan_kernel(const int* __restrict__ counts, int* __restrict__ offs) {
  int z = blockIdx.x;
  counts += (size_t)z * NN;
  offs += (size_t)z * (NN + 1);
  __shared__ int sdata[256];
  __shared__ int s_carry;
  int t = threadIdx.x;
  if (t == 0) { s_carry = 0; offs[0] = 0; }
  __syncthreads();
  for (int base = 0; base < NN; base += 1024) {
    int loc = base + t * 4;
    int v[4];
#pragma unroll
    for (int j = 0; j < 4; j++) v[j] = (loc + j < NN) ? counts[loc + j] : 0;
    int sum4 = v[0] + v[1] + v[2] + v[3];
    sdata[t] = sum4;
    __syncthreads();
    for (int o = 1; o < 256; o <<= 1) {
      int x = (t >= o) ? sdata[t - o] : 0;
      __syncthreads();
      sdata[t] += x;
      __syncthreads();
    }
    int running = sdata[t] - sum4 + s_carry;  // exclusive prefix + carry
#pragma unroll
    for (int j = 0; j < 4; j++) {
      running += v[j];
      if (loc + j < NN) offs[loc + j + 1] = running;
    }
    int tot = sdata[255];
    __syncthreads();
    if (t == 0) s_carry += tot;
    __syncthreads();
  }
}

__global__ void scatter_kernel(const int* __restrict__ ei1, const int* __restrict__ ei2,
                               const int* __restrict__ offs, int* __restrict__ fill,
                               int* __restrict__ csrc) {
  int z = blockIdx.z;
  int br = z & 1, net = z >> 1;
  const int* base = (br ? ei2 : ei1) + (size_t)net * 2 * NE;
  const int* src = base;
  const int* dst = base + NE;
  const int* offz = offs + (size_t)z * (NN + 1);
  int* fillz = fill + (size_t)z * NN;
  int* out = csrc + (size_t)z * NE;
  int i = blockIdx.x * 256 + threadIdx.x;
  if (i < NE) {
    int d = dst[i];
    int p = offz[d] + atomicAdd(&fillz[d], 1);
    out[p] = src[i];
  }
}

// ---------------- w_al/w_ar precompute -> bf16 [net][64][64] rows 0-9 al, 16-25 ar ----------
__global__ __launch_bounds__(256) void walr_kernel(const void* __restrict__ W1,
                                                   const void* __restrict__ a1s,
                                                   const void* __restrict__ a1d,
                                                   bf16* __restrict__ walrb) {
  int net = blockIdx.x / 10, head = blockIdx.x % 10;
  int t = threadIdx.x, w = t >> 6, k = t & 63;
  __shared__ float ps[8][64];
  float accs = 0.f, accd = 0.f;
  for (int c = w; c < 128; c += 4) {
    float wv = (k < FXD)
        ? ldf(W1, (size_t)net * 1280 * FXD + (size_t)(head * 128 + c) * FXD + k) : 0.f;
    float vs = ldf(a1s, (size_t)net * 1280 + head * 128 + c);
    float vd = ldf(a1d, (size_t)net * 1280 + head * 128 + c);
    accs = fmaf(wv, vs, accs);
    accd = fmaf(wv, vd, accd);
  }
  ps[w][k] = accs;
  ps[4 + w][k] = accd;
  __syncthreads();
  if (w == 0) {
    float s = ps[0][k] + ps[1][k] + ps[2][k] + ps[3][k];
    float dd = ps[4][k] + ps[5][k] + ps[6][k] + ps[7][k];
    walrb[(size_t)net * 4096 + head * 64 + k] = __float2bfloat16(s);
    walrb[(size_t)net * 4096 + (16 + head) * 64 + k] = __float2bfloat16(dd);
  }
}

// ---------------- alpha precompute: wave per dst, per-head softmax -> bf16 alphas ----------
// Row layout (24B): [5 x u32 packed bf16 alpha pairs][u32 dl], dl = d & 15.
// Real edges at CSR position e -> row e; self-loop of dst d -> row NE + d.
__global__ __launch_bounds__(256) void alpha_kernel(
    const float* __restrict__ alrA, const int* __restrict__ offsA,
    const int* __restrict__ srcsA, unsigned int* __restrict__ alphaG, int planeBase) {
  int z = blockIdx.z;
  int plane = planeBase + z;
  const float* alr = alrA + (size_t)plane * MP * 32;
  const int* offs = offsA + (size_t)plane * (NN + 1);
  const int* srcs = srcsA + (size_t)plane * NE;
  unsigned int* ag = alphaG + (size_t)z * (NE + NN) * 6;
  int wave = threadIdx.x >> 6, lane = threadIdx.x & 63;
  int d = blockIdx.x * 4 + wave;
  if (d >= NN) return;
  int e0 = offs[d], ne = offs[d + 1] - e0;
  int total = ne + 1;  // + self loop
  float arh[10];
#pragma unroll
  for (int h = 0; h < 10; h++) arh[h] = alr[(size_t)d * 32 + 16 + h];
  if (total <= 64) {
    int sc = (lane < ne) ? srcs[e0 + lane] : d;
    bool act = lane < total;
    const float* ap = &alr[(size_t)sc * 32];
    float v[10], m[10];
#pragma unroll
    for (int h = 0; h < 10; h++) {
      v[h] = act ? lky(ap[h] + arh[h]) : -1e30f;
      m[h] = v[h];
    }
#pragma unroll
    for (int o = 32; o > 0; o >>= 1)
#pragma unroll
      for (int h = 0; h < 10; h++) m[h] = fmaxf(m[h], __shfl_xor(m[h], o));
    float p[10], s[10];
#pragma unroll
    for (int h = 0; h < 10; h++) {
      p[h] = act ? __expf(v[h] - m[h]) : 0.f;
      s[h] = p[h];
    }
#pragma unroll
    for (int o = 32; o > 0; o >>= 1)
#pragma unroll
      for (int h = 0; h < 10; h++) s[h] += __shfl_xor(s[h], o);
    if (act) {
      float inv[10];
#pragma unroll
      for (int h = 0; h < 10; h++) inv[h] = 1.f / s[h];
      unsigned int wv[6];
#pragma unroll
      for (int hp = 0; hp < 5; hp++)
        wv[hp] = packbf(p[2 * hp] * inv[2 * hp], p[2 * hp + 1] * inv[2 * hp + 1]);
      wv[5] = (unsigned int)(d & 15);
      size_t row = (lane < ne) ? (size_t)(e0 + lane) : (size_t)(NE + d);
      unsigned int* rp = ag + row * 6;
#pragma unroll
      for (int j = 0; j < 6; j++) rp[j] = wv[j];
    }
  } else {
    // rare fallback: degree+1 > 64, two-pass strided
    float m[10], s[10];
#pragma unroll
    for (int h = 0; h < 10; h++) { m[h] = -1e30f; s[h] = 0.f; }
    for (int idx = lane; idx < total; idx += 64) {
      int sc = (idx < ne) ? srcs[e0 + idx] : d;
      const float* ap = &alr[(size_t)sc * 32];
#pragma unroll
      for (int h = 0; h < 10; h++) {
        float v = lky(ap[h] + arh[h]);
        if (v > m[h]) { s[h] = s[h] * __expf(m[h] - v) + 1.f; m[h] = v; }
        else s[h] += __expf(v - m[h]);
      }
    }
#pragma unroll
    for (int o = 32; o > 0; o >>= 1)
#pragma unroll
      for (int h = 0; h < 10; h++) {
        float mo = __shfl_xor(m[h], o), so = __shfl_xor(s[h], o);
        if (so > 0.f) {
          if (mo > m[h]) { s[h] = s[h] * __expf(m[h] - mo) + so; m[h] = mo; }
          else s[h] += so * __expf(mo - m[h]);
        }
      }
    for (int idx = lane; idx < total; idx += 64) {
      int sc = (idx < ne) ? srcs[e0 + idx] : d;
      const float* ap = &alr[(size_t)sc * 32];
      unsigned int wv[6];
#pragma unroll
      for (int hp = 0; hp < 5; hp++) {
        float v0 = lky(ap[2 * hp] + arh[2 * hp]);
        float v1 = lky(ap[2 * hp + 1] + arh[2 * hp + 1]);
        wv[hp] = packbf(__expf(v0 - m[2 * hp]) / s[2 * hp],
                        __expf(v1 - m[2 * hp + 1]) / s[2 * hp + 1]);
      }
      wv[5] = (unsigned int)(d & 15);
      size_t row = (idx < ne) ? (size_t)(e0 + idx) : (size_t)(NE + d);
      unsigned int* rp = ag + row * 6;
#pragma unroll
      for (int j = 0; j < 6; j++) rp[j] = wv[j];
    }
  }
}

// ---------------- xagg: MFMA alpha @ X, prefetched 2-barrier pipeline ----------------
struct Pref {
  uint4 xv;
  unsigned int a0, a1, a2, a3, a4;
  int dl;
  int av;
};

__device__ __forceinline__ void issue_pref(
    Pref& P, int kb, int e, int fblk, int tid, int nreal, int K_len, int e_begin,
    int d0, const int* __restrict__ srcs, const bf16* __restrict__ xp,
    const unsigned int* __restrict__ ag) {
  int ke = kb + e;
  int src;
  if (ke < nreal) {
    src = srcs[e_begin + ke];
  } else {
    int sl = ke - nreal;
    src = d0 + (sl < 16 ? sl : 0);
  }
  P.xv = *(const uint4*)&xp[(size_t)src * 64 + fblk * 8];
  P.av = 0;
  if (tid < 32 && ke < K_len) {
    P.av = 1;
    size_t row = (ke < nreal) ? (size_t)(e_begin + ke) : (size_t)(NE + d0 + (ke - nreal));
    const unsigned int* rp = ag + row * 6;
    P.a0 = rp[0]; P.a1 = rp[1]; P.a2 = rp[2]; P.a3 = rp[3]; P.a4 = rp[4];
    P.dl = (int)rp[5];
  }
}

__global__ __launch_bounds__(256) void xagg_kernel(
    const bf16* __restrict__ xpadA, const unsigned int* __restrict__ alphaG,
    const int* __restrict__ offsA, const int* __restrict__ srcsA,
    bf16* __restrict__ xagg2, int planeBase) {
  int z = blockIdx.z;
  int plane = planeBase + z;
  bf16* xagg = xagg2 + (size_t)z * 10 * MP * 64;
  int d0 = blockIdx.x * 16;
  int tid = threadIdx.x;

  if (d0 >= NN) {  // padding rows: zero-fill output tile (rows NN..MP-1)
    uint4 zz; zz.x = zz.y = zz.z = zz.w = 0u;
#pragma unroll
    for (int k = 0; k < 5; k++) {
      int i = tid + k * 256;  // 10*16*8 = 1280 uint4
      int h = i >> 7, rem = i & 127, row = rem >> 3, seg = rem & 7;
      *(uint4*)&xagg[((size_t)h * MP + d0 + row) * 64 + seg * 8] = zz;
    }
    return;
  }

  const bf16* xp = xpadA + (size_t)plane * MP * 64;
  const int* offs = offsA + (size_t)plane * (NN + 1);
  const int* srcs = srcsA + (size_t)plane * NE;
  const unsigned int* ag = alphaG + (size_t)z * (NE + NN) * 6;

  __shared__ __align__(16) short A_s[10 * 16 * 40];  // 12800 B
  __shared__ __align__(16) short Xt_s[64 * 40];      // 5120 B

  int e_begin = offs[d0];
  int nreal = offs[d0 + 16] - e_begin;
  int K_len = nreal + 16;

  int e = tid & 31, fblk = tid >> 5;
  int lane = tid & 63, wave = tid >> 6;
  int l15 = lane & 15, quad = lane >> 4;
  int hbase = (wave >> 1) * 5;   // waves 0,1 -> heads 0-4; waves 2,3 -> heads 5-9
  int wcol = (wave & 1) * 32;    // 32 feat cols per wave

  Pref Pn;
  issue_pref(Pn, 0, e, fblk, tid, nreal, K_len, e_begin, d0, srcs, xp, ag);

  // prologue: zero A fully
  {
    f32x4 z4 = (f32x4){0.f, 0.f, 0.f, 0.f};
    for (int i = tid; i < 800; i += 256) ((f32x4*)A_s)[i] = z4;
  }
  f32x4 acc[5][2];
#pragma unroll
  for (int i = 0; i < 5; i++)
#pragma unroll
    for (int j = 0; j < 2; j++) acc[i][j] = (f32x4){0.f, 0.f, 0.f, 0.f};
  int prev_dl = -1;
  __syncthreads();  // A zeroed

  for (int kb = 0; kb < K_len; kb += 32) {
    Pref Pc = Pn;
    // ---- W phase: A clear+scatter (tid<32), Xt stage (all) ----
    if (tid < 32) {
      if (prev_dl >= 0) {
#pragma unroll
        for (int h = 0; h < 10; h++) A_s[(h * 16 + prev_dl) * 40 + e] = 0;
      }
      prev_dl = -1;
      if (Pc.av) {
        int dlc = Pc.dl;
        A_s[(0 * 16 + dlc) * 40 + e] = (short)(Pc.a0 & 0xffff);
        A_s[(1 * 16 + dlc) * 40 + e] = (short)(Pc.a0 >> 16);
        A_s[(2 * 16 + dlc) * 40 + e] = (short)(Pc.a1 & 0xffff);
        A_s[(3 * 16 + dlc) * 40 + e] = (short)(Pc.a1 >> 16);
        A_s[(4 * 16 + dlc) * 40 + e] = (short)(Pc.a2 & 0xffff);
        A_s[(5 * 16 + dlc) * 40 + e] = (short)(Pc.a2 >> 16);
        A_s[(6 * 16 + dlc) * 40 + e] = (short)(Pc.a3 & 0xffff);
        A_s[(7 * 16 + dlc) * 40 + e] = (short)(Pc.a3 >> 16);
        A_s[(8 * 16 + dlc) * 40 + e] = (short)(Pc.a4 & 0xffff);
        A_s[(9 * 16 + dlc) * 40 + e] = (short)(Pc.a4 >> 16);
        prev_dl = dlc;
      }
    }
    {
      int fb8 = fblk * 8;
#pragma unroll
      for (int j = 0; j < 4; j++) {
        unsigned int w = ((const unsigned int*)&Pc.xv)[j];
        Xt_s[(fb8 + 2 * j) * 40 + e] = (short)(w & 0xffff);
        Xt_s[(fb8 + 2 * j + 1) * 40 + e] = (short)(w >> 16);
      }
    }
    // prefetch next chunk (flies over the MFMA phase)
    if (kb + 32 < K_len)
      issue_pref(Pn, kb + 32, e, fblk, tid, nreal, K_len, e_begin, d0, srcs, xp, ag);
    __syncthreads();  // A + Xt ready
    // ---- MFMA phase ----
    bf16x8 b0 = *(const bf16x8*)&Xt_s[(wcol + l15) * 40 + quad * 8];
    bf16x8 b1 = *(const bf16x8*)&Xt_s[(wcol + 16 + l15) * 40 + quad * 8];
#pragma unroll
    for (int hh = 0; hh < 5; hh++) {
      bf16x8 af = *(const bf16x8*)&A_s[((hbase + hh) * 16 + l15) * 40 + quad * 8];
      acc[hh][0] = __builtin_amdgcn_mfma_f32_16x16x32_bf16(af, b0, acc[hh][0], 0, 0, 0);
      acc[hh][1] = __builtin_amdgcn_mfma_f32_16x16x32_bf16(af, b1, acc[hh][1], 0, 0, 0);
    }
    __syncthreads();  // MFMA reads done before next W phase
  }

  // ---- epilogue: direct global stores (D map: row=quad*4+r, col=l15) ----
#pragma unroll
  for (int hh = 0; hh < 5; hh++) {
    int h = hbase + hh;
#pragma unroll
    for (int ft = 0; ft < 2; ft++) {
#pragma unroll
      for (int r = 0; r < 4; r++) {
        int drow = d0 + quad * 4 + r;
        xagg[((size_t)h * MP + drow) * 64 + wcol + ft * 16 + l15] =
            __float2bfloat16(acc[hh][ft][r]);
      }
    }
  }
}

// ---------------- fused L1+L2 GEMM + dots, split-k W2 staging for occupancy --------
// R2-proven staging pattern (direct global->LDS, no reg-held-across-barrier prefetch).
// W2 staged in two 64-k halves (128x72 each) instead of one 128x136 buffer:
// uraw 52224 -> 35840 B (total LDS 37.9KB) => 4 blocks/CU instead of 3 (R6: Occ 27%).
// Cost: +2 barriers per h (6 vs 4). acc2 accumulates across kh halves.
__global__ __launch_bounds__(256) void fused_l1l2_kernel(
    const bf16* __restrict__ xagg2, const bf16* __restrict__ W1b,
    const void* __restrict__ b1raw, const bf16* __restrict__ W2b,
    const void* __restrict__ a2s, const void* __restrict__ a2d,
    float* __restrict__ al2A, float* __restrict__ ar2A,
    bf16* __restrict__ h2all, int planeBase) {
  int zz = blockIdx.z;
  int plane = planeBase + zz;
  int net = plane >> 1;
  long ow1 = (long)net * 1280 * 64;
  long ob1 = (long)net * 1280;
  long ow2 = (long)net * 128 * 1280;
  long oa2 = (long)net * 128;
  const bf16* xagg = xagg2 + (size_t)zz * 10 * MP * 64;
  float* al2p = al2A + (size_t)plane * NN;
  float* ar2p = ar2A + (size_t)plane * NN;
  bf16* h2 = h2all + (size_t)plane * MP * 128;
  int r0 = blockIdx.y * 64;
  __shared__ __align__(16) char uraw[35840];
  bf16* Ah = (bf16*)uraw;             // 64 x 72   (9216 B)
  bf16* W1s = Ah + 64 * 72;           // 128 x 72  (18432 B) -> phase1 27648
  bf16* Ps = (bf16*)uraw;             // 64 x 136  (17408 B, overlays Ah/W1s)
  bf16* W2s = Ps + 64 * 136;          // 128 x 72  (18432 B) -> phase2 35840
  __shared__ float s_dot[2][2][32][2];  // [rowHalf][colHalf][rowLocal][al/ar]
  int tid = threadIdx.x, lane = tid & 63, wave = tid >> 6;
  int l15 = lane & 15, quad = lane >> 4;
  int rowHalf = wave >> 1, colHalf = wave & 1;
  int wr = rowHalf * 32, wc = colHalf * 64;
  f32x4 acc2[2][4];
#pragma unroll
  for (int i = 0; i < 2; i++)
#pragma unroll
    for (int j = 0; j < 4; j++) acc2[i][j] = (f32x4){0.f, 0.f, 0.f, 0.f};

  for (int h = 0; h < 10; h++) {
    __syncthreads();  // prior stage2 done with Ps/W2s
    for (int i = tid; i < 512; i += 256) {
      int r = i >> 3, seg = i & 7;
      *(uint4*)&Ah[r * 72 + seg * 8] =
          *(const uint4*)&xagg[((size_t)h * MP + r0 + r) * 64 + seg * 8];
    }
    for (int i = tid; i < 1024; i += 256) {
      int r = i >> 3, seg = i & 7;
      *(uint4*)&W1s[r * 72 + seg * 8] =
          *(const uint4*)&W1b[ow1 + (size_t)(h * 128 + r) * 64 + seg * 8];
    }
    __syncthreads();
    // stage 1: P = xagg_h @ W1_h^T (each wave -> 32 of 128 P-cols, all 64 rows)
    f32x4 acc1[4][2];
#pragma unroll
    for (int i = 0; i < 4; i++)
#pragma unroll
      for (int j = 0; j < 2; j++) acc1[i][j] = (f32x4){0.f, 0.f, 0.f, 0.f};
#pragma unroll
    for (int kc = 0; kc < 2; kc++) {
      bf16x8 af[4], bfr[2];
#pragma unroll
      for (int mi = 0; mi < 4; mi++)
        af[mi] = *(const bf16x8*)&Ah[(mi * 16 + l15) * 72 + kc * 32 + quad * 8];
#pragma unroll
      for (int ni = 0; ni < 2; ni++)
        bfr[ni] = *(const bf16x8*)&W1s[(wave * 32 + ni * 16 + l15) * 72 + kc * 32 + quad * 8];
#pragma unroll
      for (int mi = 0; mi < 4; mi++)
#pragma unroll
        for (int ni = 0; ni < 2; ni++)
          acc1[mi][ni] = __builtin_amdgcn_mfma_f32_16x16x32_bf16(af[mi], bfr[ni], acc1[mi][ni], 0, 0, 0);
    }
    __syncthreads();  // all waves done reading Ah/W1s before Ps overwrite
    // write P (bias + ELU) and stage W2 half kh=0 (128 rows x 64 k-cols)
#pragma unroll
    for (int ni = 0; ni < 2; ni++) {
      int pcol = wave * 32 + ni * 16 + l15;
      float bv = ldf(b1raw, ob1 + h * 128 + pcol);
#pragma unroll
      for (int mi = 0; mi < 4; mi++)
#pragma unroll
        for (int r = 0; r < 4; r++)
          Ps[(mi * 16 + quad * 4 + r) * 136 + pcol] =
              __float2bfloat16(eluf(acc1[mi][ni][r] + bv));
    }
    for (int i = tid; i < 1024; i += 256) {
      int r = i >> 3, seg = i & 7;
      *(uint4*)&W2s[r * 72 + seg * 8] =
          *(const uint4*)&W2b[ow2 + (size_t)r * 1280 + h * 128 + seg * 8];
    }
    __syncthreads();
    // stage 2: acc2 += P @ W2_h^T in two k-halves (wave: 32 rows x 64 cols)
#pragma unroll
    for (int kh = 0; kh < 2; kh++) {
      if (kh) {
        __syncthreads();  // waves done reading W2s half 0
        for (int i = tid; i < 1024; i += 256) {
          int r = i >> 3, seg = i & 7;
          *(uint4*)&W2s[r * 72 + seg * 8] =
              *(const uint4*)&W2b[ow2 + (size_t)r * 1280 + h * 128 + 64 + seg * 8];
        }
        __syncthreads();
      }
#pragma unroll
      for (int kc = 0; kc < 2; kc++) {
        bf16x8 pa[2], pb[4];
#pragma unroll
        for (int mi = 0; mi < 2; mi++)
          pa[mi] = *(const bf16x8*)&Ps[(wr + mi * 16 + l15) * 136 + kh * 64 + kc * 32 + quad * 8];
#pragma unroll
        for (int ni = 0; ni < 4; ni++)
          pb[ni] = *(const bf16x8*)&W2s[(wc + ni * 16 + l15) * 72 + kc * 32 + quad * 8];
#pragma unroll
        for (int mi = 0; mi < 2; mi++)
#pragma unroll
          for (int ni = 0; ni < 4; ni++)
            acc2[mi][ni] = __builtin_amdgcn_mfma_f32_16x16x32_bf16(pa[mi], pb[ni], acc2[mi][ni], 0, 0, 0);
      }
    }
  }
  // epilogue: h2 write + attention dots (combined across col-halves in LDS)
  float asv[4], adv[4];
#pragma unroll
  for (int ni = 0; ni < 4; ni++) {
    int col = wc + ni * 16 + l15;
    asv[ni] = ldf(a2s, oa2 + col);
    adv[ni] = ldf(a2d, oa2 + col);
  }
#pragma unroll
  for (int mi = 0; mi < 2; mi++) {
#pragma unroll
    for (int r = 0; r < 4; r++) {
      int rl = mi * 16 + quad * 4 + r;  // row-local within this wave's 32
      int row = r0 + wr + rl;
      float psum = 0.f, pdum = 0.f;
#pragma unroll
      for (int ni = 0; ni < 4; ni++) {
        float v = acc2[mi][ni][r];
        h2[(size_t)row * 128 + wc + ni * 16 + l15] = __float2bfloat16(v);
        psum = fmaf(v, asv[ni], psum);
        pdum = fmaf(v, adv[ni], pdum);
      }
#pragma unroll
      for (int o = 1; o < 16; o <<= 1) {
        psum += __shfl_xor(psum, o);
        pdum += __shfl_xor(pdum, o);
      }
      if (l15 == 0) {
        s_dot[rowHalf][colHalf][rl][0] = psum;
        s_dot[rowHalf][colHalf][rl][1] = pdum;
      }
    }
  }
  __syncthreads();
  if (tid < 64) {
    int row = r0 + tid;
    if (row < NN) {
      int rh = tid >> 5, rl = tid & 31;
      al2p[row] = s_dot[rh][0][rl][0] + s_dot[rh][1][rl][0];
      ar2p[row] = s_dot[rh][0][rl][1] + s_dot[rh][1][rl][1];
    }
  }
}

// ---------------- MFMA GEMM 64x64 tile (bias is raw f32 input) ----------------
__global__ __launch_bounds__(256) void mfma_gemm64(
    const bf16* __restrict__ A, long Az, const bf16* __restrict__ B, long Bz, int bdiv,
    const void* __restrict__ bias, long biasoff, long biaszs,
    float* __restrict__ Cf, long Cfz, int ldcf, int accum, int ncols, int brcol,
    bf16* __restrict__ Cb, long Cbz, int ldcb,
    int K, int act, float scale) {
  int z = blockIdx.z;
  int zb = bdiv ? (z >> 1) : z;
  A += (size_t)z * Az;
  B += (size_t)zb * Bz;
  if (Cf) Cf += (size_t)z * Cfz + (size_t)(z & 1) * brcol;
  if (Cb) Cb += (size_t)z * Cbz;
  const bf16* Ag = A + (size_t)blockIdx.y * 64 * K;
  const bf16* Bg = B + (size_t)blockIdx.x * 64 * K;
  __shared__ __align__(16) bf16 Asm[64 * 40];
  __shared__ __align__(16) bf16 Bsm[64 * 40];
  int tid = threadIdx.x;
  int lane = tid & 63, wave = tid >> 6;
  int wr = (wave >> 1) * 32, wc = (wave & 1) * 32;
  int l15 = lane & 15, quad = lane >> 4;
  f32x4 acc[2][2];
#pragma unroll
  for (int i = 0; i < 2; i++)
#pragma unroll
    for (int j = 0; j < 2; j++) acc[i][j] = (f32x4){0.f, 0.f, 0.f, 0.f};
  int isB = tid >> 7;
  int srow = (tid & 127) >> 1, shalf = tid & 1;
  const bf16* G = isB ? Bg : Ag;
  bf16* S = isB ? Bsm : Asm;
  for (int k0 = 0; k0 < K; k0 += 32) {
    const uint4* g = (const uint4*)(G + (size_t)srow * K + k0 + shalf * 16);
    uint4 v0 = g[0], v1 = g[1];
    __syncthreads();
    *(uint4*)&S[srow * 40 + shalf * 16] = v0;
    *(uint4*)&S[srow * 40 + shalf * 16 + 8] = v1;
    __syncthreads();
    bf16x8 af[2], bfr[2];
#pragma unroll
    for (int mi = 0; mi < 2; mi++)
      af[mi] = *(const bf16x8*)&Asm[(wr + mi * 16 + l15) * 40 + quad * 8];
#pragma unroll
    for (int ni = 0; ni < 2; ni++)
      bfr[ni] = *(const bf16x8*)&Bsm[(wc + ni * 16 + l15) * 40 + quad * 8];
#pragma unroll
    for (int mi = 0; mi < 2; mi++)
#pragma unroll
      for (int ni = 0; ni < 2; ni++)
        acc[mi][ni] = __builtin_amdgcn_mfma_f32_16x16x32_bf16(af[mi], bfr[ni], acc[mi][ni], 0, 0, 0);
  }
#pragma unroll
  for (int ni = 0; ni < 2; ni++) {
    int col = blockIdx.x * 64 + wc + ni * 16 + l15;
    if (col >= ncols) continue;
    float bv = bias ? ldf(bias, biasoff + (size_t)zb * biaszs + col) : 0.f;
#pragma unroll
    for (int mi = 0; mi < 2; mi++) {
      int rbase = blockIdx.y * 64 + wr + mi * 16 + quad * 4;
      f32x4 c = acc[mi][ni];
#pragma unroll
      for (int r = 0; r < 4; r++) {
        float v = c[r] + bv;
        if (act == 1) v = fmaxf(v, 0.f);
        else if (act == 2) v = eluf(v);
        v *= scale;
        if (Cf) {
          size_t ci = (size_t)(rbase + r) * ldcf + col;
          if (accum == 1) Cf[ci] += v;
          else if (accum == 2) atomicAdd(&Cf[ci], v);
          else Cf[ci] = v;
        }
        if (Cb) Cb[(size_t)(rbase + r) * ldcb + col] = __float2bfloat16(v);
      }
    }
  }
}

// ---------------- GAT layer-2 aggregation: wave per dst, LDS (src,alpha) pairs ------------
__global__ __launch_bounds__(256) void gat_agg1_kernel(
    const bf16* __restrict__ h2all, const float* __restrict__ alA, const float* __restrict__ arA,
    const int* __restrict__ offsA, const int* __restrict__ srcsA,
    const void* __restrict__ b2, bf16* __restrict__ out2all) {
  int z = blockIdx.z;
  int net = z >> 1;
  const bf16* h = h2all + (size_t)z * MP * 128;
  const float* al = alA + (size_t)z * NN;
  const float* ar = arA + (size_t)z * NN;
  const int* offs = offsA + (size_t)z * (NN + 1);
  const int* srcs = srcsA + (size_t)z * NE;
  __shared__ float2 s_pair[4][64];
  int wave = threadIdx.x >> 6, lane = threadIdx.x & 63;
  int d = blockIdx.x * 4 + wave;
  if (d >= NN) return;
  int e0 = offs[d], ne = offs[d + 1] - e0;
  int total = ne + 1;
  float ard = ar[d];
  float m, s, vcache = -1e30f;
  if (total <= 64) {
    int sc = (lane < ne) ? srcs[e0 + lane] : d;
    bool act = lane < total;
    vcache = act ? lky(al[sc] + ard) : -1e30f;
    m = vcache;
    s = act ? 1.f : 0.f;
#pragma unroll
    for (int o = 32; o > 0; o >>= 1) {
      float mo = __shfl_xor(m, o), so = __shfl_xor(s, o);
      if (so > 0.f) {
        if (mo > m) { s = s * __expf(m - mo) + so; m = mo; }
        else s += so * __expf(mo - m);
      }
    }
  } else {
    m = -1e30f; s = 0.f;
    for (int idx = lane; idx < total; idx += 64) {
      int sc = (idx < ne) ? srcs[e0 + idx] : d;
      float v = lky(al[sc] + ard);
      if (v > m) { s = s * __expf(m - v) + 1.f; m = v; }
      else s += __expf(v - m);
    }
#pragma unroll
    for (int o = 32; o > 0; o >>= 1) {
      float mo = __shfl_xor(m, o), so = __shfl_xor(s, o);
      if (so > 0.f) {
        if (mo > m) { s = s * __expf(m - mo) + so; m = mo; }
        else s += so * __expf(mo - m);
      }
    }
  }
  float inv_s = 1.f / s;
  float acc0 = 0.f, acc1v = 0.f;
  for (int c0 = 0; c0 < total; c0 += 64) {
    int idx = c0 + lane;
    int cnt = min(64, total - c0);
    if (idx < total) {
      int sc = (idx < ne) ? srcs[e0 + idx] : d;
      float v = (total <= 64) ? vcache : lky(al[sc] + ard);
      float a = __expf(v - m) * inv_s;
      s_pair[wave][lane] = make_float2(__int_as_float(sc), a);
    }
    // wave-private LDS: same-wave program order + compiler lgkmcnt waits ensure RAW
    int i = 0;
    for (; i + 2 <= cnt; i += 2) {
      float2 pA = s_pair[wave][i];
      float2 pB = s_pair[wave][i + 1];
      __hip_bfloat162 vA =
          ((const __hip_bfloat162*)(h + (size_t)__float_as_int(pA.x) * 128))[lane];
      __hip_bfloat162 vB =
          ((const __hip_bfloat162*)(h + (size_t)__float_as_int(pB.x) * 128))[lane];
      acc0 = fmaf(__bfloat162float(vA.x), pA.y, acc0);
      acc1v = fmaf(__bfloat162float(vA.y), pA.y, acc1v);
      acc0 = fmaf(__bfloat162float(vB.x), pB.y, acc0);
      acc1v = fmaf(__bfloat162float(vB.y), pB.y, acc1v);
    }
    if (i < cnt) {
      float2 pA = s_pair[wave][i];
      __hip_bfloat162 vA =
          ((const __hip_bfloat162*)(h + (size_t)__float_as_int(pA.x) * 128))[lane];
      acc0 = fmaf(__bfloat162float(vA.x), pA.y, acc0);
      acc1v = fmaf(__bfloat162float(vA.y), pA.y, acc1v);
    }
  }
  float b0 = ldf(b2, (size_t)net * 128 + 2 * lane);
  float b1v = ldf(b2, (size_t)net * 128 + 2 * lane + 1);
  __hip_bfloat162 o;
  o.x = __float2bfloat16(eluf(acc0 + b0));
  o.y = __float2bfloat16(eluf(acc1v + b1v));
  ((__hip_bfloat162*)(out2all + ((size_t)z * NN + d) * 128))[lane] = o;
}

// ---------------- global max pool (bf16 in/out), z = plane ----------------
__global__ __launch_bounds__(256) void pool_max_kernel(const bf16* __restrict__ out2all,
                                                       bf16* __restrict__ gall) {
  int z = blockIdx.z;
  const bf16* h = out2all + (size_t)z * NN * 128;
  bf16* g = gall + (size_t)z * BB * 128;
  int wave = threadIdx.x >> 6, lane = threadIdx.x & 63;
  int b = blockIdx.x * 4 + wave;
  if (b >= BB) return;
  int n0 = (b * NN + BB - 1) / BB;
  int n1 = ((b + 1) * NN + BB - 1) / BB;
  if (n1 > NN) n1 = NN;
  float mx = -1e30f, my = -1e30f;
  for (int n = n0; n < n1; n++) {
    __hip_bfloat162 v = ((const __hip_bfloat162*)(h + (size_t)n * 128))[lane];
    mx = fmaxf(mx, __bfloat162float(v.x));
    my = fmaxf(my, __bfloat162float(v.y));
  }
  __hip_bfloat162 o;
  o.x = __float2bfloat16(mx);
  o.y = __float2bfloat16(my);
  ((__hip_bfloat162*)(g + (size_t)b * 128))[lane] = o;
}

// ---------------- l2 normalize rows (f32 in) -> padded bf16 ----------------
__global__ __launch_bounds__(256) void l2norm_b_kernel(const float* __restrict__ x,
                                                       bf16* __restrict__ y, int Din, int Kp) {
  int r = blockIdx.x, t = threadIdx.x;
  __shared__ float red[256];
  float s = 0.f;
  for (int i = t; i < Din; i += 256) {
    float v = x[(size_t)r * Din + i];
    s += v * v;
  }
  red[t] = s;
  __syncthreads();
  for (int o = 128; o > 0; o >>= 1) { if (t < o) red[t] += red[t + o]; __syncthreads(); }
  float inv = 1.f / fmaxf(sqrtf(red[0]), 1e-12f);
  for (int i = t; i < Kp; i += 256) {
    float v = (i < Din) ? x[(size_t)r * Din + i] : 0.f;
    y[(size_t)r * Kp + i] = __float2bfloat16(v * inv);
  }
}

// ---------------- final 512x2 output (f32 out) ----------------
__global__ void final_out_kernel(const float* __restrict__ f3, const void* __restrict__ Wo,
                                 const void* __restrict__ bo, float* __restrict__ out) {
  int r = blockIdx.x;
  int lane = threadIdx.x;
  float x0 = f3[(size_t)r * 128 + lane], x1v = f3[(size_t)r * 128 + 64 + lane];
  float s0 = x0 * ldf(Wo, lane) + x1v * ldf(Wo, 64 + lane);
  float s1 = x0 * ldf(Wo, 128 + lane) + x1v * ldf(Wo, 192 + lane);
#pragma unroll
  for (int o = 32; o > 0; o >>= 1) { s0 += __shfl_down(s0, o); s1 += __shfl_down(s1, o); }
  if (lane == 0) {
    out[r * 2] = s0 + ldf(bo, 0);
    out[r * 2 + 1] = s1 + ldf(bo, 1);
  }
}

// ---------------- host ----------------

extern "C" void kernel_launch(void* const* d_in, const int* in_sizes, int n_in,
                              void* d_out, int out_size, void* d_ws, size_t ws_size,
                              hipStream_t stream) {
  const void* x1 = d_in[0];
  const int* ei1 = (const int*)d_in[1];
  const void* x2 = d_in[3];
  const int* ei2 = (const int*)d_in[4];
  const void* cell = d_in[6];
  const void* W1 = d_in[7];
  const void* a1s = d_in[8];
  const void* a1d = d_in[9];
  const void* b1 = d_in[10];
  const void* W2 = d_in[11];
  const void* a2s = d_in[12];
  const void* a2d = d_in[13];
  const void* b2 = d_in[14];
  const void* Wg = d_in[15];
  const void* bg = d_in[16];
  const void* Wr1 = d_in[17]; const void* br1 = d_in[18];
  const void* Wr2 = d_in[19]; const void* br2 = d_in[20];
  const void* Wr3 = d_in[21]; const void* br3 = d_in[22];
  const void* Wf1 = d_in[23]; const void* bf1 = d_in[24];
  const void* Wf2 = d_in[25]; const void* bf2 = d_in[26];
  const void* Wf3 = d_in[27]; const void* bf3 = d_in[28];
  const void* Wo = d_in[29]; const void* bo = d_in[30];

  char* base = (char*)d_ws;
  size_t off = 0;
  auto alloc = [&](size_t bytes) -> void* {
    void* p = base + off;
    off = (off + bytes + 255) & ~(size_t)255;
    return p;
  };
  bf16* d_xpad = (bf16*)alloc((size_t)10 * MP * 64 * 2);
  bf16* d_W1b = (bf16*)alloc((size_t)5 * 1280 * 64 * 2);
  bf16* d_W2b = (bf16*)alloc((size_t)5 * 128 * 1280 * 2);
  bf16* d_Wgb = (bf16*)alloc((size_t)5 * 128 * 128 * 2);
  bf16* d_Wr1b = (bf16*)alloc((size_t)2048 * 960 * 2);
  bf16* d_Wr2b = (bf16*)alloc((size_t)512 * 2048 * 2);
  bf16* d_Wr3b = (bf16*)alloc((size_t)256 * 512 * 2);
  bf16* d_Wf1b = (bf16*)alloc((size_t)2048 * 512 * 2);
  bf16* d_Wf2b = (bf16*)alloc((size_t)512 * 2048 * 2);
  bf16* d_Wf3b = (bf16*)alloc((size_t)128 * 512 * 2);
  int* d_offs = (int*)alloc((size_t)10 * (NN + 1) * 4);
  int* d_srcs = (int*)alloc((size_t)10 * NE * 4);
  int* d_cnt = (int*)alloc((size_t)10 * NN * 4);
  bf16* d_walrb = (bf16*)alloc((size_t)5 * 64 * 64 * 2);
  float* d_alr = (float*)alloc((size_t)10 * MP * 32 * 4);
  float* d_al2 = (float*)alloc((size_t)20 * NN * 4);  // al2 [10][NN] then ar2 [10][NN]
  float* d_ar2 = d_al2 + (size_t)10 * NN;
  bf16* d_h2all = (bf16*)alloc((size_t)10 * MP * 128 * 2);
  // alpha rows for up to 10 planes: [(NE+NN) rows][24B]
  unsigned int* d_alphaG = (unsigned int*)alloc((size_t)10 * (NE + NN) * 24);
  // uni region: xagg2 (G planes) overlaid with tail buffers.
  char* uni = base + off;
  size_t avail = (ws_size > off) ? (ws_size - off) : 0;
  size_t need10 = (size_t)10 * 10 * MP * 64 * 2;  // 129,433,600
  int G = (avail >= need10 + 65536) ? 10 : 5;
  bf16* d_xagg2 = (bf16*)uni;                // G x 10 x MP x 64 x 2
  bf16* d_out2all = (bf16*)uni;              // 10 x NN x 128 x 2 = 25,600,000 B
  bf16* d_gall = (bf16*)(uni + 25600000);    // 1,310,720 B
  float* d_xc = (float*)(uni + 26910720);    // 1,048,576 B
  bf16* d_xcb = (bf16*)(uni + 27959296);     // 524,288 B
  bf16* d_cnb = (bf16*)(uni + 28483584);     // 983,040 B
  bf16* d_m1b = (bf16*)(uni + 29466624);     // 2,097,152 B
  bf16* d_m2b = (bf16*)(uni + 31563776);     // 524,288 B
  float* d_f3 = (float*)(uni + 32088064);    // 262,144 B

  ConvTable tab;
  tab.d[0] = {x1, d_xpad, NN, FXD, MP, 64, 2, 0, 5, (MP + 3) / 4};
  tab.d[1] = {x2, d_xpad, NN, FXD, MP, 64, 2, 1, 5, (MP + 3) / 4};
  tab.d[2] = {W1, d_W1b, 1280, FXD, 1280, 64, 1, 0, 5, 320};
  tab.d[3] = {W2, d_W2b, 128, 1280, 128, 1280, 1, 0, 5, 32};
  tab.d[4] = {Wg, d_Wgb, 128, 128, 128, 128, 1, 0, 5, 32};
  tab.d[5] = {Wr1, d_Wr1b, 2048, FXT, 2048, 960, 1, 0, 1, 512};
  tab.d[6] = {Wr2, d_Wr2b, 512, 2048, 512, 2048, 1, 0, 1, 128};
  tab.d[7] = {Wr3, d_Wr3b, 256, 512, 256, 512, 1, 0, 1, 64};
  tab.d[8] = {Wf1, d_Wf1b, 2048, 512, 2048, 512, 1, 0, 1, 512};
  tab.d[9] = {Wf2, d_Wf2b, 512, 2048, 512, 2048, 1, 0, 1, 128};
  tab.d[10] = {Wf3, d_Wf3b, 128, 512, 128, 512, 1, 0, 1, 32};
  {
    int cum = 0;
    tab.blk0[0] = 0;
    for (int i = 0; i < 11; i++) {
      cum += tab.d[i].rowBlocks * tab.d[i].batch;
      tab.blk0[i + 1] = cum;
    }
    convert_all_kernel<<<dim3(cum), 256, 0, stream>>>(tab);
  }

  // CSR for all 10 planes
  hipMemsetAsync(d_cnt, 0, (size_t)10 * NN * 4, stream);
  hist_kernel<<<dim3((NE + 255) / 256, 1, 10), 256, 0, stream>>>(ei1, ei2, d_cnt);
  scan_kernel<<<10, 256, 0, stream>>>(d_cnt, d_offs);
  hipMemsetAsync(d_cnt, 0, (size_t)10 * NN * 4, stream);
  scatter_kernel<<<dim3((NE + 255) / 256, 1, 10), 256, 0, stream>>>(ei1, ei2, d_offs, d_cnt, d_srcs);

  // layer-1 attention logits: alr = xpad @ walrb^T (cols 0-9 al, 16-25 ar; others unused)
  walr_kernel<<<50, 256, 0, stream>>>(W1, a1s, a1d, d_walrb);
  mfma_gemm64<<<dim3(1, MP / 64, 10), 256, 0, stream>>>(
      d_xpad, (long)MP * 64, d_walrb, 4096, 1, nullptr, 0, 0,
      d_alr, (long)MP * 32, 32, 0, 32, 0, nullptr, 0, 0, 64, 0, 1.f);

  for (int pb = 0; pb < 10; pb += G) {
    alpha_kernel<<<dim3(NN / 4, 1, G), 256, 0, stream>>>(d_alr, d_offs, d_srcs, d_alphaG, pb);
    xagg_kernel<<<dim3(MP / 16, 1, G), 256, 0, stream>>>(d_xpad, d_alphaG, d_offs, d_srcs, d_xagg2, pb);
    fused_l1l2_kernel<<<dim3(1, MP / 64, G), 256, 0, stream>>>(
        d_xagg2, d_W1b, b1, d_W2b, a2s, a2d, d_al2, d_ar2, d_h2all, pb);
  }

  // batched tail over all 10 planes
  hipMemsetAsync(d_xc, 0, (size_t)BB * 512 * 4, stream);
  gat_agg1_kernel<<<dim3(2500, 1, 10), 256, 0, stream>>>(
      d_h2all, d_al2, d_ar2, d_offs, d_srcs, b2, d_out2all);
  pool_max_kernel<<<dim3(BB / 4, 1, 10), 256, 0, stream>>>(d_out2all, d_gall);
  // xc[:, (z&1)*128 : +128] += relu(g_z @ Wg_{z>>1}^T + bg_{z>>1}) * 0.2, one dispatch
  mfma_gemm64<<<dim3(2, BB / 64, 10), 256, 0, stream>>>(
      d_gall, (long)BB * 128, d_Wgb, 128 * 128, 1,
      bg, 0, 128,
      d_xc, 0, 512, 2, 128, 128, nullptr, 0, 0, 128, 1, 0.2f);

  // cell reduction MLP -> xc[:,256:512]
  l2norm_b_kernel<<<BB, 256, 0, stream>>>((const float*)cell, d_cnb, FXT, 960);
  mfma_gemm64<<<dim3(32, 8, 1), 256, 0, stream>>>(
      d_cnb, 0, d_Wr1b, 0, 0, br1, 0, 0, nullptr, 0, 0, 0, 1 << 30, 0, d_m1b, 0, 2048, 960, 1, 1.f);
  mfma_gemm64<<<dim3(8, 8, 1), 256, 0, stream>>>(
      d_m1b, 0, d_Wr2b, 0, 0, br2, 0, 0, nullptr, 0, 0, 0, 1 << 30, 0, d_m2b, 0, 512, 2048, 1, 1.f);
  mfma_gemm64<<<dim3(4, 8, 1), 256, 0, stream>>>(
      d_m2b, 0, d_Wr3b, 0, 0, br3, 0, 0, d_xc + 256, 0, 512, 0, 1 << 30, 0, nullptr, 0, 0, 512, 1, 1.f);

  // head MLP
  l2norm_b_kernel<<<BB, 256, 0, stream>>>(d_xc, d_xcb, 512, 512);
  mfma_gemm64<<<dim3(32, 8, 1), 256, 0, stream>>>(
      d_xcb, 0, d_Wf1b, 0, 0, bf1, 0, 0, nullptr, 0, 0, 0, 1 << 30, 0, d_m1b, 0, 2048, 512, 1, 1.f);
  mfma_gemm64<<<dim3(8, 8, 1), 256, 0, stream>>>(
      d_m1b, 0, d_Wf2b, 0, 0, bf2, 0, 0, nullptr, 0, 0, 0, 1 << 30, 0, d_m2b, 0, 512, 2048, 1, 1.f);
  mfma_gemm64<<<dim3(2, 8, 1), 256, 0, stream>>>(
      d_m2b, 0, d_Wf3b, 0, 0, bf3, 0, 0, d_f3, 0, 128, 0, 1 << 30, 0, nullptr, 0, 0, 512, 1, 1.f);
  final_out_kernel<<<BB, 64, 0, stream>>>(d_f3, Wo, bo, (float*)d_out);
}

// Round 8
// 984.419 us; speedup vs baseline: 1.0115x; 1.0115x over previous
//
#include <hip/hip_runtime.h>
#include <hip/hip_bf16.h>
#include <math.h>

#define NUM_NET 5
#define NN 10000
#define NE 160000
#define BB 512
#define FXD 62
#define FXT 954
#define MP 10112  // NN padded to multiple of 128

typedef __bf16 bf16x8 __attribute__((ext_vector_type(8)));
typedef float f32x4 __attribute__((ext_vector_type(4)));
typedef __hip_bfloat16 bf16;

// ---------------- helpers (inputs/outputs are f32 — R7-verified) ----------------
__device__ __forceinline__ float ldf(const void* p, size_t i) {
  return ((const float*)p)[i];
}
__device__ __forceinline__ float lky(float v) { return v > 0.f ? v : 0.2f * v; }
__device__ __forceinline__ float eluf(float v) { return v > 0.f ? v : (__expf(v) - 1.f); }
__device__ __forceinline__ unsigned int packbf(float a, float b) {
  __hip_bfloat162 t;
  t.x = __float2bfloat16(a);
  t.y = __float2bfloat16(b);
  return *(unsigned int*)&t;  // a in low 16, b in high 16
}

// ---------------- mega convert: flattened exact grid (no no-op blocks) ----------------
struct ConvDesc {
  const void* src;
  bf16* dst;
  int M, K, Mp, Kp, mult, add, batch, rowBlocks;
};
struct ConvTable { ConvDesc d[11]; int blk0[12]; };

__global__ void convert_all_kernel(ConvTable tab) {
  int bid = blockIdx.x;
  int di = 0;
#pragma unroll
  for (int d = 1; d < 11; d++) di += (bid >= tab.blk0[d]);
  ConvDesc c = tab.d[di];
  int local = bid - tab.blk0[di];
  int b = local / c.rowBlocks;
  int rb = local - b * c.rowBlocks;
  int wave = threadIdx.x >> 6, lane = threadIdx.x & 63;
  int r = rb * 4 + wave;
  if (r >= c.Mp) return;
  const float* srow = (const float*)c.src + ((size_t)b * c.M + r) * c.K;
  bf16* drow = c.dst + (((size_t)(b * c.mult + c.add)) * c.Mp + r) * c.Kp;
  bool rowok = r < c.M;
  for (int k = lane; k < c.Kp; k += 64) {
    float v = (rowok && k < c.K) ? srow[k] : 0.f;
    drow[k] = __float2bfloat16(v);
  }
}

// ---------------- CSR build (planes = net*2+br) ----------------
__global__ void hist_kernel(const int* __restrict__ ei1, const int* __restrict__ ei2,
                            int* __restrict__ counts) {
  int z = blockIdx.z;
  int br = z & 1, net = z >> 1;
  const int* base = (br ? ei2 : ei1) + (size_t)net * 2 * NE;
  const int* dst = base + NE;
  int* cnt = counts + (size_t)z * NN;
  int i = blockIdx.x * 256 + threadIdx.x;
  if (i < NE) atomicAdd(&cnt[dst[i]], 1);
}

// 4-wide scan: 1024 counts per round
__global__ void scan_kernel(const int* __restrict__ counts, int* __restrict__ offs) {
  int z = blockIdx.x;
  counts += (size_t)z * NN;
  offs += (size_t)z * (NN + 1);
  __shared__ int sdata[256];
  __shared__ int s_carry;
  int t = threadIdx.x;
  if (t == 0) { s_carry = 0; offs[0] = 0; }
  __syncthreads();
  for (int base = 0; base < NN; base += 1024) {
    int loc = base + t * 4;
    int v[4];
#pragma unroll
    for (int j = 0; j < 4; j++) v[j] = (loc + j < NN) ? counts[loc + j] : 0;
    int sum4 = v[0] + v[1] + v[2] + v[3];
    sdata[t] = sum4;
    __syncthreads();
    for (int o = 1; o < 256; o <<= 1) {
      int x = (t >= o) ? sdata[t - o] : 0;
      __syncthreads();
      sdata[t] += x;
      __syncthreads();
    }
    int running = sdata[t] - sum4 + s_carry;  // exclusive prefix + carry
#pragma unroll
    for (int j = 0; j < 4; j++) {
      running += v[j];
      if (loc + j < NN) offs[loc + j + 1] = running;
    }
    int tot = sdata[255];
    __syncthreads();
    if (t == 0) s_carry += tot;
    __syncthreads();
  }
}

__global__ void scatter_kernel(const int* __restrict__ ei1, const int* __restrict__ ei2,
                               const int* __restrict__ offs, int* __restrict__ fill,
                               int* __restrict__ csrc) {
  int z = blockIdx.z;
  int br = z & 1, net = z >> 1;
  const int* base = (br ? ei2 : ei1) + (size_t)net * 2 * NE;
  const int* src = base;
  const int* dst = base + NE;
  const int* offz = offs + (size_t)z * (NN + 1);
  int* fillz = fill + (size_t)z * NN;
  int* out = csrc + (size_t)z * NE;
  int i = blockIdx.x * 256 + threadIdx.x;
  if (i < NE) {
    int d = dst[i];
    int p = offz[d] + atomicAdd(&fillz[d], 1);
    out[p] = src[i];
  }
}

// ---------------- w_al/w_ar precompute -> bf16 [net][64][64] rows 0-9 al, 16-25 ar ----------
__global__ __launch_bounds__(256) void walr_kernel(const void* __restrict__ W1,
                                                   const void* __restrict__ a1s,
                                                   const void* __restrict__ a1d,
                                                   bf16* __restrict__ walrb) {
  int net = blockIdx.x / 10, head = blockIdx.x % 10;
  int t = threadIdx.x, w = t >> 6, k = t & 63;
  __shared__ float ps[8][64];
  float accs = 0.f, accd = 0.f;
  for (int c = w; c < 128; c += 4) {
    float wv = (k < FXD)
        ? ldf(W1, (size_t)net * 1280 * FXD + (size_t)(head * 128 + c) * FXD + k) : 0.f;
    float vs = ldf(a1s, (size_t)net * 1280 + head * 128 + c);
    float vd = ldf(a1d, (size_t)net * 1280 + head * 128 + c);
    accs = fmaf(wv, vs, accs);
    accd = fmaf(wv, vd, accd);
  }
  ps[w][k] = accs;
  ps[4 + w][k] = accd;
  __syncthreads();
  if (w == 0) {
    float s = ps[0][k] + ps[1][k] + ps[2][k] + ps[3][k];
    float dd = ps[4][k] + ps[5][k] + ps[6][k] + ps[7][k];
    walrb[(size_t)net * 4096 + head * 64 + k] = __float2bfloat16(s);
    walrb[(size_t)net * 4096 + (16 + head) * 64 + k] = __float2bfloat16(dd);
  }
}

// ---------------- alpha precompute: wave per dst, per-head softmax -> bf16 alphas ----------
// Row layout (24B): [5 x u32 packed bf16 alpha pairs][u32 dl], dl = d & 15.
// Real edges at CSR position e -> row e; self-loop of dst d -> row NE + d.
__global__ __launch_bounds__(256) void alpha_kernel(
    const float* __restrict__ alrA, const int* __restrict__ offsA,
    const int* __restrict__ srcsA, unsigned int* __restrict__ alphaG, int planeBase) {
  int z = blockIdx.z;
  int plane = planeBase + z;
  const float* alr = alrA + (size_t)plane * MP * 32;
  const int* offs = offsA + (size_t)plane * (NN + 1);
  const int* srcs = srcsA + (size_t)plane * NE;
  unsigned int* ag = alphaG + (size_t)z * (NE + NN) * 6;
  int wave = threadIdx.x >> 6, lane = threadIdx.x & 63;
  int d = blockIdx.x * 4 + wave;
  if (d >= NN) return;
  int e0 = offs[d], ne = offs[d + 1] - e0;
  int total = ne + 1;  // + self loop
  float arh[10];
#pragma unroll
  for (int h = 0; h < 10; h++) arh[h] = alr[(size_t)d * 32 + 16 + h];
  if (total <= 64) {
    int sc = (lane < ne) ? srcs[e0 + lane] : d;
    bool act = lane < total;
    const float* ap = &alr[(size_t)sc * 32];
    float v[10], m[10];
#pragma unroll
    for (int h = 0; h < 10; h++) {
      v[h] = act ? lky(ap[h] + arh[h]) : -1e30f;
      m[h] = v[h];
    }
#pragma unroll
    for (int o = 32; o > 0; o >>= 1)
#pragma unroll
      for (int h = 0; h < 10; h++) m[h] = fmaxf(m[h], __shfl_xor(m[h], o));
    float p[10], s[10];
#pragma unroll
    for (int h = 0; h < 10; h++) {
      p[h] = act ? __expf(v[h] - m[h]) : 0.f;
      s[h] = p[h];
    }
#pragma unroll
    for (int o = 32; o > 0; o >>= 1)
#pragma unroll
      for (int h = 0; h < 10; h++) s[h] += __shfl_xor(s[h], o);
    if (act) {
      float inv[10];
#pragma unroll
      for (int h = 0; h < 10; h++) inv[h] = 1.f / s[h];
      unsigned int wv[6];
#pragma unroll
      for (int hp = 0; hp < 5; hp++)
        wv[hp] = packbf(p[2 * hp] * inv[2 * hp], p[2 * hp + 1] * inv[2 * hp + 1]);
      wv[5] = (unsigned int)(d & 15);
      size_t row = (lane < ne) ? (size_t)(e0 + lane) : (size_t)(NE + d);
      unsigned int* rp = ag + row * 6;
#pragma unroll
      for (int j = 0; j < 6; j++) rp[j] = wv[j];
    }
  } else {
    // rare fallback: degree+1 > 64, two-pass strided
    float m[10], s[10];
#pragma unroll
    for (int h = 0; h < 10; h++) { m[h] = -1e30f; s[h] = 0.f; }
    for (int idx = lane; idx < total; idx += 64) {
      int sc = (idx < ne) ? srcs[e0 + idx] : d;
      const float* ap = &alr[(size_t)sc * 32];
#pragma unroll
      for (int h = 0; h < 10; h++) {
        float v = lky(ap[h] + arh[h]);
        if (v > m[h]) { s[h] = s[h] * __expf(m[h] - v) + 1.f; m[h] = v; }
        else s[h] += __expf(v - m[h]);
      }
    }
#pragma unroll
    for (int o = 32; o > 0; o >>= 1)
#pragma unroll
      for (int h = 0; h < 10; h++) {
        float mo = __shfl_xor(m[h], o), so = __shfl_xor(s[h], o);
        if (so > 0.f) {
          if (mo > m[h]) { s[h] = s[h] * __expf(m[h] - mo) + so; m[h] = mo; }
          else s[h] += so * __expf(mo - m[h]);
        }
      }
    for (int idx = lane; idx < total; idx += 64) {
      int sc = (idx < ne) ? srcs[e0 + idx] : d;
      const float* ap = &alr[(size_t)sc * 32];
      unsigned int wv[6];
#pragma unroll
      for (int hp = 0; hp < 5; hp++) {
        float v0 = lky(ap[2 * hp] + arh[2 * hp]);
        float v1 = lky(ap[2 * hp + 1] + arh[2 * hp + 1]);
        wv[hp] = packbf(__expf(v0 - m[2 * hp]) / s[2 * hp],
                        __expf(v1 - m[2 * hp + 1]) / s[2 * hp + 1]);
      }
      wv[5] = (unsigned int)(d & 15);
      size_t row = (idx < ne) ? (size_t)(e0 + idx) : (size_t)(NE + d);
      unsigned int* rp = ag + row * 6;
#pragma unroll
      for (int j = 0; j < 6; j++) rp[j] = wv[j];
    }
  }
}

// ---------------- xagg: MFMA alpha @ X, prefetched 2-barrier pipeline ----------------
struct Pref {
  uint4 xv;
  unsigned int a0, a1, a2, a3, a4;
  int dl;
  int av;
};

__device__ __forceinline__ void issue_pref(
    Pref& P, int kb, int e, int fblk, int tid, int nreal, int K_len, int e_begin,
    int d0, const int* __restrict__ srcs, const bf16* __restrict__ xp,
    const unsigned int* __restrict__ ag) {
  int ke = kb + e;
  int src;
  if (ke < nreal) {
    src = srcs[e_begin + ke];
  } else {
    int sl = ke - nreal;
    src = d0 + (sl < 16 ? sl : 0);
  }
  P.xv = *(const uint4*)&xp[(size_t)src * 64 + fblk * 8];
  P.av = 0;
  if (tid < 32 && ke < K_len) {
    P.av = 1;
    size_t row = (ke < nreal) ? (size_t)(e_begin + ke) : (size_t)(NE + d0 + (ke - nreal));
    const unsigned int* rp = ag + row * 6;
    P.a0 = rp[0]; P.a1 = rp[1]; P.a2 = rp[2]; P.a3 = rp[3]; P.a4 = rp[4];
    P.dl = (int)rp[5];
  }
}

__global__ __launch_bounds__(256) void xagg_kernel(
    const bf16* __restrict__ xpadA, const unsigned int* __restrict__ alphaG,
    const int* __restrict__ offsA, const int* __restrict__ srcsA,
    bf16* __restrict__ xagg2, int planeBase) {
  int z = blockIdx.z;
  int plane = planeBase + z;
  bf16* xagg = xagg2 + (size_t)z * 10 * MP * 64;
  int d0 = blockIdx.x * 16;
  int tid = threadIdx.x;

  if (d0 >= NN) {  // padding rows: zero-fill output tile (rows NN..MP-1)
    uint4 zz; zz.x = zz.y = zz.z = zz.w = 0u;
#pragma unroll
    for (int k = 0; k < 5; k++) {
      int i = tid + k * 256;  // 10*16*8 = 1280 uint4
      int h = i >> 7, rem = i & 127, row = rem >> 3, seg = rem & 7;
      *(uint4*)&xagg[((size_t)h * MP + d0 + row) * 64 + seg * 8] = zz;
    }
    return;
  }

  const bf16* xp = xpadA + (size_t)plane * MP * 64;
  const int* offs = offsA + (size_t)plane * (NN + 1);
  const int* srcs = srcsA + (size_t)plane * NE;
  const unsigned int* ag = alphaG + (size_t)z * (NE + NN) * 6;

  __shared__ __align__(16) short A_s[10 * 16 * 40];  // 12800 B
  __shared__ __align__(16) short Xt_s[64 * 40];      // 5120 B

  int e_begin = offs[d0];
  int nreal = offs[d0 + 16] - e_begin;
  int K_len = nreal + 16;

  int e = tid & 31, fblk = tid >> 5;
  int lane = tid & 63, wave = tid >> 6;
  int l15 = lane & 15, quad = lane >> 4;
  int hbase = (wave >> 1) * 5;   // waves 0,1 -> heads 0-4; waves 2,3 -> heads 5-9
  int wcol = (wave & 1) * 32;    // 32 feat cols per wave

  Pref Pn;
  issue_pref(Pn, 0, e, fblk, tid, nreal, K_len, e_begin, d0, srcs, xp, ag);

  // prologue: zero A fully
  {
    f32x4 z4 = (f32x4){0.f, 0.f, 0.f, 0.f};
    for (int i = tid; i < 800; i += 256) ((f32x4*)A_s)[i] = z4;
  }
  f32x4 acc[5][2];
#pragma unroll
  for (int i = 0; i < 5; i++)
#pragma unroll
    for (int j = 0; j < 2; j++) acc[i][j] = (f32x4){0.f, 0.f, 0.f, 0.f};
  int prev_dl = -1;
  __syncthreads();  // A zeroed

  for (int kb = 0; kb < K_len; kb += 32) {
    Pref Pc = Pn;
    // ---- W phase: A clear+scatter (tid<32), Xt stage (all) ----
    if (tid < 32) {
      if (prev_dl >= 0) {
#pragma unroll
        for (int h = 0; h < 10; h++) A_s[(h * 16 + prev_dl) * 40 + e] = 0;
      }
      prev_dl = -1;
      if (Pc.av) {
        int dlc = Pc.dl;
        A_s[(0 * 16 + dlc) * 40 + e] = (short)(Pc.a0 & 0xffff);
        A_s[(1 * 16 + dlc) * 40 + e] = (short)(Pc.a0 >> 16);
        A_s[(2 * 16 + dlc) * 40 + e] = (short)(Pc.a1 & 0xffff);
        A_s[(3 * 16 + dlc) * 40 + e] = (short)(Pc.a1 >> 16);
        A_s[(4 * 16 + dlc) * 40 + e] = (short)(Pc.a2 & 0xffff);
        A_s[(5 * 16 + dlc) * 40 + e] = (short)(Pc.a2 >> 16);
        A_s[(6 * 16 + dlc) * 40 + e] = (short)(Pc.a3 & 0xffff);
        A_s[(7 * 16 + dlc) * 40 + e] = (short)(Pc.a3 >> 16);
        A_s[(8 * 16 + dlc) * 40 + e] = (short)(Pc.a4 & 0xffff);
        A_s[(9 * 16 + dlc) * 40 + e] = (short)(Pc.a4 >> 16);
        prev_dl = dlc;
      }
    }
    {
      int fb8 = fblk * 8;
#pragma unroll
      for (int j = 0; j < 4; j++) {
        unsigned int w = ((const unsigned int*)&Pc.xv)[j];
        Xt_s[(fb8 + 2 * j) * 40 + e] = (short)(w & 0xffff);
        Xt_s[(fb8 + 2 * j + 1) * 40 + e] = (short)(w >> 16);
      }
    }
    // prefetch next chunk (flies over the MFMA phase)
    if (kb + 32 < K_len)
      issue_pref(Pn, kb + 32, e, fblk, tid, nreal, K_len, e_begin, d0, srcs, xp, ag);
    __syncthreads();  // A + Xt ready
    // ---- MFMA phase ----
    bf16x8 b0 = *(const bf16x8*)&Xt_s[(wcol + l15) * 40 + quad * 8];
    bf16x8 b1 = *(const bf16x8*)&Xt_s[(wcol + 16 + l15) * 40 + quad * 8];
#pragma unroll
    for (int hh = 0; hh < 5; hh++) {
      bf16x8 af = *(const bf16x8*)&A_s[((hbase + hh) * 16 + l15) * 40 + quad * 8];
      acc[hh][0] = __builtin_amdgcn_mfma_f32_16x16x32_bf16(af, b0, acc[hh][0], 0, 0, 0);
      acc[hh][1] = __builtin_amdgcn_mfma_f32_16x16x32_bf16(af, b1, acc[hh][1], 0, 0, 0);
    }
    __syncthreads();  // MFMA reads done before next W phase
  }

  // ---- epilogue: direct global stores (D map: row=quad*4+r, col=l15) ----
#pragma unroll
  for (int hh = 0; hh < 5; hh++) {
    int h = hbase + hh;
#pragma unroll
    for (int ft = 0; ft < 2; ft++) {
#pragma unroll
      for (int r = 0; r < 4; r++) {
        int drow = d0 + quad * 4 + r;
        xagg[((size_t)h * MP + drow) * 64 + wcol + ft * 16 + l15] =
            __float2bfloat16(acc[hh][ft][r]);
      }
    }
  }
}

// ---------------- fused L1+L2 GEMM + dots, BM=128 row tile ----------------
// R6-proven staging pattern (direct global->LDS each phase, W2 full-K single stage).
// 128 rows per block: same W1/W2 staging bytes + same 4 barriers per h now cover 2x rows.
// LDS: phase1 Ah(128x72)+W1s(128x72)=36.9KB; phase2 Ps(128x136)+W2s(128x136)=69.6KB
// (gfx950 allows >64KB workgroup LDS; 2 blocks/CU). Each wave owns 32 rows x all 128
// cols -> al2/ar2 dots reduce fully in-wave (no s_dot LDS, no cross-wave combine).
// Accumulators acc1[2][8]+acc2[2][8] are plain MFMA accs (m93-style), not
// across-barrier load temps (the R3/R4 spill class) — expect VGPR ~160-220, no scratch.
__global__ __launch_bounds__(256) void fused_l1l2_kernel(
    const bf16* __restrict__ xagg2, const bf16* __restrict__ W1b,
    const void* __restrict__ b1raw, const bf16* __restrict__ W2b,
    const void* __restrict__ a2s, const void* __restrict__ a2d,
    float* __restrict__ al2A, float* __restrict__ ar2A,
    bf16* __restrict__ h2all, int planeBase) {
  int zz = blockIdx.z;
  int plane = planeBase + zz;
  int net = plane >> 1;
  long ow1 = (long)net * 1280 * 64;
  long ob1 = (long)net * 1280;
  long ow2 = (long)net * 128 * 1280;
  long oa2 = (long)net * 128;
  const bf16* xagg = xagg2 + (size_t)zz * 10 * MP * 64;
  float* al2p = al2A + (size_t)plane * NN;
  float* ar2p = ar2A + (size_t)plane * NN;
  bf16* h2 = h2all + (size_t)plane * MP * 128;
  int r0 = blockIdx.y * 128;
  __shared__ __align__(16) char uraw[69632];
  bf16* Ah = (bf16*)uraw;              // 128 x 72  (18432 B)
  bf16* W1s = Ah + 128 * 72;           // 128 x 72  (-> 36864)
  bf16* Ps = (bf16*)uraw;              // 128 x 136 (34816, overlays Ah/W1s)
  bf16* W2s = Ps + 128 * 136;          // 128 x 136 (-> 69632)
  int tid = threadIdx.x, lane = tid & 63, wave = tid >> 6;
  int l15 = lane & 15, quad = lane >> 4;
  int wr = wave * 32;  // wave's 32-row slice of the 128-row tile
  f32x4 acc2[2][8];
#pragma unroll
  for (int i = 0; i < 2; i++)
#pragma unroll
    for (int j = 0; j < 8; j++) acc2[i][j] = (f32x4){0.f, 0.f, 0.f, 0.f};

  for (int h = 0; h < 10; h++) {
    __syncthreads();  // prior stage2 done with Ps/W2s
#pragma unroll
    for (int j = 0; j < 4; j++) {  // Ah: 1024 uint4
      int i = tid + j * 256;
      *(uint4*)&Ah[(i >> 3) * 72 + (i & 7) * 8] =
          *(const uint4*)&xagg[((size_t)h * MP + r0 + (i >> 3)) * 64 + (i & 7) * 8];
    }
#pragma unroll
    for (int j = 0; j < 4; j++) {  // W1s: 1024 uint4
      int i = tid + j * 256;
      *(uint4*)&W1s[(i >> 3) * 72 + (i & 7) * 8] =
          *(const uint4*)&W1b[ow1 + (size_t)(h * 128 + (i >> 3)) * 64 + (i & 7) * 8];
    }
    __syncthreads();
    // stage 1: P = Ah @ W1_h^T. Wave: its 32 rows x all 128 P-cols.
    f32x4 acc1[2][8];
#pragma unroll
    for (int i = 0; i < 2; i++)
#pragma unroll
      for (int j = 0; j < 8; j++) acc1[i][j] = (f32x4){0.f, 0.f, 0.f, 0.f};
#pragma unroll
    for (int kc = 0; kc < 2; kc++) {
      bf16x8 af[2], bfr[8];
#pragma unroll
      for (int mi = 0; mi < 2; mi++)
        af[mi] = *(const bf16x8*)&Ah[(wr + mi * 16 + l15) * 72 + kc * 32 + quad * 8];
#pragma unroll
      for (int ni = 0; ni < 8; ni++)
        bfr[ni] = *(const bf16x8*)&W1s[(ni * 16 + l15) * 72 + kc * 32 + quad * 8];
#pragma unroll
      for (int mi = 0; mi < 2; mi++)
#pragma unroll
        for (int ni = 0; ni < 8; ni++)
          acc1[mi][ni] = __builtin_amdgcn_mfma_f32_16x16x32_bf16(af[mi], bfr[ni], acc1[mi][ni], 0, 0, 0);
    }
    __syncthreads();  // all waves done reading Ah/W1s before Ps overwrite
    // write P (bias + ELU) for own 32 rows; stage W2s (all 128 rows, full K)
#pragma unroll
    for (int ni = 0; ni < 8; ni++) {
      int pcol = ni * 16 + l15;
      float bv = ldf(b1raw, ob1 + h * 128 + pcol);
#pragma unroll
      for (int mi = 0; mi < 2; mi++)
#pragma unroll
        for (int r = 0; r < 4; r++)
          Ps[(wr + mi * 16 + quad * 4 + r) * 136 + pcol] =
              __float2bfloat16(eluf(acc1[mi][ni][r] + bv));
    }
#pragma unroll
    for (int j = 0; j < 8; j++) {  // W2s: 2048 uint4
      int i = tid + j * 256;
      *(uint4*)&W2s[(i >> 4) * 136 + (i & 15) * 8] =
          *(const uint4*)&W2b[ow2 + (size_t)(i >> 4) * 1280 + h * 128 + (i & 15) * 8];
    }
    __syncthreads();
    // stage 2: acc2 += P @ W2_h^T (wave: its 32 rows x all 128 cols)
#pragma unroll
    for (int kc = 0; kc < 4; kc++) {
      bf16x8 pa[2], pb[8];
#pragma unroll
      for (int mi = 0; mi < 2; mi++)
        pa[mi] = *(const bf16x8*)&Ps[(wr + mi * 16 + l15) * 136 + kc * 32 + quad * 8];
#pragma unroll
      for (int ni = 0; ni < 8; ni++)
        pb[ni] = *(const bf16x8*)&W2s[(ni * 16 + l15) * 136 + kc * 32 + quad * 8];
#pragma unroll
      for (int mi = 0; mi < 2; mi++)
#pragma unroll
        for (int ni = 0; ni < 8; ni++)
          acc2[mi][ni] = __builtin_amdgcn_mfma_f32_16x16x32_bf16(pa[mi], pb[ni], acc2[mi][ni], 0, 0, 0);
    }
  }
  // epilogue: h2 write + attention dots (wave owns full rows -> in-wave reduce only)
  float asv[8], adv[8];
#pragma unroll
  for (int ni = 0; ni < 8; ni++) {
    int col = ni * 16 + l15;
    asv[ni] = ldf(a2s, oa2 + col);
    adv[ni] = ldf(a2d, oa2 + col);
  }
#pragma unroll
  for (int mi = 0; mi < 2; mi++) {
#pragma unroll
    for (int r = 0; r < 4; r++) {
      int row = r0 + wr + mi * 16 + quad * 4 + r;
      float psum = 0.f, pdum = 0.f;
#pragma unroll
      for (int ni = 0; ni < 8; ni++) {
        float v = acc2[mi][ni][r];
        h2[(size_t)row * 128 + ni * 16 + l15] = __float2bfloat16(v);
        psum = fmaf(v, asv[ni], psum);
        pdum = fmaf(v, adv[ni], pdum);
      }
#pragma unroll
      for (int o = 1; o < 16; o <<= 1) {
        psum += __shfl_xor(psum, o);
        pdum += __shfl_xor(pdum, o);
      }
      if (l15 == 0 && row < NN) {
        al2p[row] = psum;
        ar2p[row] = pdum;
      }
    }
  }
}

// ---------------- MFMA GEMM 64x64 tile (bias is raw f32 input) ----------------
__global__ __launch_bounds__(256) void mfma_gemm64(
    const bf16* __restrict__ A, long Az, const bf16* __restrict__ B, long Bz, int bdiv,
    const void* __restrict__ bias, long biasoff, long biaszs,
    float* __restrict__ Cf, long Cfz, int ldcf, int accum, int ncols, int brcol,
    bf16* __restrict__ Cb, long Cbz, int ldcb,
    int K, int act, float scale) {
  int z = blockIdx.z;
  int zb = bdiv ? (z >> 1) : z;
  A += (size_t)z * Az;
  B += (size_t)zb * Bz;
  if (Cf) Cf += (size_t)z * Cfz + (size_t)(z & 1) * brcol;
  if (Cb) Cb += (size_t)z * Cbz;
  const bf16* Ag = A + (size_t)blockIdx.y * 64 * K;
  const bf16* Bg = B + (size_t)blockIdx.x * 64 * K;
  __shared__ __align__(16) bf16 Asm[64 * 40];
  __shared__ __align__(16) bf16 Bsm[64 * 40];
  int tid = threadIdx.x;
  int lane = tid & 63, wave = tid >> 6;
  int wr = (wave >> 1) * 32, wc = (wave & 1) * 32;
  int l15 = lane & 15, quad = lane >> 4;
  f32x4 acc[2][2];
#pragma unroll
  for (int i = 0; i < 2; i++)
#pragma unroll
    for (int j = 0; j < 2; j++) acc[i][j] = (f32x4){0.f, 0.f, 0.f, 0.f};
  int isB = tid >> 7;
  int srow = (tid & 127) >> 1, shalf = tid & 1;
  const bf16* G = isB ? Bg : Ag;
  bf16* S = isB ? Bsm : Asm;
  for (int k0 = 0; k0 < K; k0 += 32) {
    const uint4* g = (const uint4*)(G + (size_t)srow * K + k0 + shalf * 16);
    uint4 v0 = g[0], v1 = g[1];
    __syncthreads();
    *(uint4*)&S[srow * 40 + shalf * 16] = v0;
    *(uint4*)&S[srow * 40 + shalf * 16 + 8] = v1;
    __syncthreads();
    bf16x8 af[2], bfr[2];
#pragma unroll
    for (int mi = 0; mi < 2; mi++)
      af[mi] = *(const bf16x8*)&Asm[(wr + mi * 16 + l15) * 40 + quad * 8];
#pragma unroll
    for (int ni = 0; ni < 2; ni++)
      bfr[ni] = *(const bf16x8*)&Bsm[(wc + ni * 16 + l15) * 40 + quad * 8];
#pragma unroll
    for (int mi = 0; mi < 2; mi++)
#pragma unroll
      for (int ni = 0; ni < 2; ni++)
        acc[mi][ni] = __builtin_amdgcn_mfma_f32_16x16x32_bf16(af[mi], bfr[ni], acc[mi][ni], 0, 0, 0);
  }
#pragma unroll
  for (int ni = 0; ni < 2; ni++) {
    int col = blockIdx.x * 64 + wc + ni * 16 + l15;
    if (col >= ncols) continue;
    float bv = bias ? ldf(bias, biasoff + (size_t)zb * biaszs + col) : 0.f;
#pragma unroll
    for (int mi = 0; mi < 2; mi++) {
      int rbase = blockIdx.y * 64 + wr + mi * 16 + quad * 4;
      f32x4 c = acc[mi][ni];
#pragma unroll
      for (int r = 0; r < 4; r++) {
        float v = c[r] + bv;
        if (act == 1) v = fmaxf(v, 0.f);
        else if (act == 2) v = eluf(v);
        v *= scale;
        if (Cf) {
          size_t ci = (size_t)(rbase + r) * ldcf + col;
          if (accum == 1) Cf[ci] += v;
          else if (accum == 2) atomicAdd(&Cf[ci], v);
          else Cf[ci] = v;
        }
        if (Cb) Cb[(size_t)(rbase + r) * ldcb + col] = __float2bfloat16(v);
      }
    }
  }
}

// ---------------- GAT layer-2 aggregation: wave per dst, LDS (src,alpha) pairs ------------
__global__ __launch_bounds__(256) void gat_agg1_kernel(
    const bf16* __restrict__ h2all, const float* __restrict__ alA, const float* __restrict__ arA,
    const int* __restrict__ offsA, const int* __restrict__ srcsA,
    const void* __restrict__ b2, bf16* __restrict__ out2all) {
  int z = blockIdx.z;
  int net = z >> 1;
  const bf16* h = h2all + (size_t)z * MP * 128;
  const float* al = alA + (size_t)z * NN;
  const float* ar = arA + (size_t)z * NN;
  const int* offs = offsA + (size_t)z * (NN + 1);
  const int* srcs = srcsA + (size_t)z * NE;
  __shared__ float2 s_pair[4][64];
  int wave = threadIdx.x >> 6, lane = threadIdx.x & 63;
  int d = blockIdx.x * 4 + wave;
  if (d >= NN) return;
  int e0 = offs[d], ne = offs[d + 1] - e0;
  int total = ne + 1;
  float ard = ar[d];
  float m, s, vcache = -1e30f;
  if (total <= 64) {
    int sc = (lane < ne) ? srcs[e0 + lane] : d;
    bool act = lane < total;
    vcache = act ? lky(al[sc] + ard) : -1e30f;
    m = vcache;
    s = act ? 1.f : 0.f;
#pragma unroll
    for (int o = 32; o > 0; o >>= 1) {
      float mo = __shfl_xor(m, o), so = __shfl_xor(s, o);
      if (so > 0.f) {
        if (mo > m) { s = s * __expf(m - mo) + so; m = mo; }
        else s += so * __expf(mo - m);
      }
    }
  } else {
    m = -1e30f; s = 0.f;
    for (int idx = lane; idx < total; idx += 64) {
      int sc = (idx < ne) ? srcs[e0 + idx] : d;
      float v = lky(al[sc] + ard);
      if (v > m) { s = s * __expf(m - v) + 1.f; m = v; }
      else s += __expf(v - m);
    }
#pragma unroll
    for (int o = 32; o > 0; o >>= 1) {
      float mo = __shfl_xor(m, o), so = __shfl_xor(s, o);
      if (so > 0.f) {
        if (mo > m) { s = s * __expf(m - mo) + so; m = mo; }
        else s += so * __expf(mo - m);
      }
    }
  }
  float inv_s = 1.f / s;
  float acc0 = 0.f, acc1v = 0.f;
  for (int c0 = 0; c0 < total; c0 += 64) {
    int idx = c0 + lane;
    int cnt = min(64, total - c0);
    if (idx < total) {
      int sc = (idx < ne) ? srcs[e0 + idx] : d;
      float v = (total <= 64) ? vcache : lky(al[sc] + ard);
      float a = __expf(v - m) * inv_s;
      s_pair[wave][lane] = make_float2(__int_as_float(sc), a);
    }
    // wave-private LDS: same-wave program order + compiler lgkmcnt waits ensure RAW
    int i = 0;
    for (; i + 2 <= cnt; i += 2) {
      float2 pA = s_pair[wave][i];
      float2 pB = s_pair[wave][i + 1];
      __hip_bfloat162 vA =
          ((const __hip_bfloat162*)(h + (size_t)__float_as_int(pA.x) * 128))[lane];
      __hip_bfloat162 vB =
          ((const __hip_bfloat162*)(h + (size_t)__float_as_int(pB.x) * 128))[lane];
      acc0 = fmaf(__bfloat162float(vA.x), pA.y, acc0);
      acc1v = fmaf(__bfloat162float(vA.y), pA.y, acc1v);
      acc0 = fmaf(__bfloat162float(vB.x), pB.y, acc0);
      acc1v = fmaf(__bfloat162float(vB.y), pB.y, acc1v);
    }
    if (i < cnt) {
      float2 pA = s_pair[wave][i];
      __hip_bfloat162 vA =
          ((const __hip_bfloat162*)(h + (size_t)__float_as_int(pA.x) * 128))[lane];
      acc0 = fmaf(__bfloat162float(vA.x), pA.y, acc0);
      acc1v = fmaf(__bfloat162float(vA.y), pA.y, acc1v);
    }
  }
  float b0 = ldf(b2, (size_t)net * 128 + 2 * lane);
  float b1v = ldf(b2, (size_t)net * 128 + 2 * lane + 1);
  __hip_bfloat162 o;
  o.x = __float2bfloat16(eluf(acc0 + b0));
  o.y = __float2bfloat16(eluf(acc1v + b1v));
  ((__hip_bfloat162*)(out2all + ((size_t)z * NN + d) * 128))[lane] = o;
}

// ---------------- global max pool (bf16 in/out), z = plane ----------------
__global__ __launch_bounds__(256) void pool_max_kernel(const bf16* __restrict__ out2all,
                                                       bf16* __restrict__ gall) {
  int z = blockIdx.z;
  const bf16* h = out2all + (size_t)z * NN * 128;
  bf16* g = gall + (size_t)z * BB * 128;
  int wave = threadIdx.x >> 6, lane = threadIdx.x & 63;
  int b = blockIdx.x * 4 + wave;
  if (b >= BB) return;
  int n0 = (b * NN + BB - 1) / BB;
  int n1 = ((b + 1) * NN + BB - 1) / BB;
  if (n1 > NN) n1 = NN;
  float mx = -1e30f, my = -1e30f;
  for (int n = n0; n < n1; n++) {
    __hip_bfloat162 v = ((const __hip_bfloat162*)(h + (size_t)n * 128))[lane];
    mx = fmaxf(mx, __bfloat162float(v.x));
    my = fmaxf(my, __bfloat162float(v.y));
  }
  __hip_bfloat162 o;
  o.x = __float2bfloat16(mx);
  o.y = __float2bfloat16(my);
  ((__hip_bfloat162*)(g + (size_t)b * 128))[lane] = o;
}

// ---------------- l2 normalize rows (f32 in) -> padded bf16 ----------------
__global__ __launch_bounds__(256) void l2norm_b_kernel(const float* __restrict__ x,
                                                       bf16* __restrict__ y, int Din, int Kp) {
  int r = blockIdx.x, t = threadIdx.x;
  __shared__ float red[256];
  float s = 0.f;
  for (int i = t; i < Din; i += 256) {
    float v = x[(size_t)r * Din + i];
    s += v * v;
  }
  red[t] = s;
  __syncthreads();
  for (int o = 128; o > 0; o >>= 1) { if (t < o) red[t] += red[t + o]; __syncthreads(); }
  float inv = 1.f / fmaxf(sqrtf(red[0]), 1e-12f);
  for (int i = t; i < Kp; i += 256) {
    float v = (i < Din) ? x[(size_t)r * Din + i] : 0.f;
    y[(size_t)r * Kp + i] = __float2bfloat16(v * inv);
  }
}

// ---------------- final 512x2 output (f32 out) ----------------
__global__ void final_out_kernel(const float* __restrict__ f3, const void* __restrict__ Wo,
                                 const void* __restrict__ bo, float* __restrict__ out) {
  int r = blockIdx.x;
  int lane = threadIdx.x;
  float x0 = f3[(size_t)r * 128 + lane], x1v = f3[(size_t)r * 128 + 64 + lane];
  float s0 = x0 * ldf(Wo, lane) + x1v * ldf(Wo, 64 + lane);
  float s1 = x0 * ldf(Wo, 128 + lane) + x1v * ldf(Wo, 192 + lane);
#pragma unroll
  for (int o = 32; o > 0; o >>= 1) { s0 += __shfl_down(s0, o); s1 += __shfl_down(s1, o); }
  if (lane == 0) {
    out[r * 2] = s0 + ldf(bo, 0);
    out[r * 2 + 1] = s1 + ldf(bo, 1);
  }
}

// ---------------- host ----------------

extern "C" void kernel_launch(void* const* d_in, const int* in_sizes, int n_in,
                              void* d_out, int out_size, void* d_ws, size_t ws_size,
                              hipStream_t stream) {
  const void* x1 = d_in[0];
  const int* ei1 = (const int*)d_in[1];
  const void* x2 = d_in[3];
  const int* ei2 = (const int*)d_in[4];
  const void* cell = d_in[6];
  const void* W1 = d_in[7];
  const void* a1s = d_in[8];
  const void* a1d = d_in[9];
  const void* b1 = d_in[10];
  const void* W2 = d_in[11];
  const void* a2s = d_in[12];
  const void* a2d = d_in[13];
  const void* b2 = d_in[14];
  const void* Wg = d_in[15];
  const void* bg = d_in[16];
  const void* Wr1 = d_in[17]; const void* br1 = d_in[18];
  const void* Wr2 = d_in[19]; const void* br2 = d_in[20];
  const void* Wr3 = d_in[21]; const void* br3 = d_in[22];
  const void* Wf1 = d_in[23]; const void* bf1 = d_in[24];
  const void* Wf2 = d_in[25]; const void* bf2 = d_in[26];
  const void* Wf3 = d_in[27]; const void* bf3 = d_in[28];
  const void* Wo = d_in[29]; const void* bo = d_in[30];

  char* base = (char*)d_ws;
  size_t off = 0;
  auto alloc = [&](size_t bytes) -> void* {
    void* p = base + off;
    off = (off + bytes + 255) & ~(size_t)255;
    return p;
  };
  bf16* d_xpad = (bf16*)alloc((size_t)10 * MP * 64 * 2);
  bf16* d_W1b = (bf16*)alloc((size_t)5 * 1280 * 64 * 2);
  bf16* d_W2b = (bf16*)alloc((size_t)5 * 128 * 1280 * 2);
  bf16* d_Wgb = (bf16*)alloc((size_t)5 * 128 * 128 * 2);
  bf16* d_Wr1b = (bf16*)alloc((size_t)2048 * 960 * 2);
  bf16* d_Wr2b = (bf16*)alloc((size_t)512 * 2048 * 2);
  bf16* d_Wr3b = (bf16*)alloc((size_t)256 * 512 * 2);
  bf16* d_Wf1b = (bf16*)alloc((size_t)2048 * 512 * 2);
  bf16* d_Wf2b = (bf16*)alloc((size_t)512 * 2048 * 2);
  bf16* d_Wf3b = (bf16*)alloc((size_t)128 * 512 * 2);
  int* d_offs = (int*)alloc((size_t)10 * (NN + 1) * 4);
  int* d_srcs = (int*)alloc((size_t)10 * NE * 4);
  int* d_cnt = (int*)alloc((size_t)10 * NN * 4);
  bf16* d_walrb = (bf16*)alloc((size_t)5 * 64 * 64 * 2);
  float* d_alr = (float*)alloc((size_t)10 * MP * 32 * 4);
  float* d_al2 = (float*)alloc((size_t)20 * NN * 4);  // al2 [10][NN] then ar2 [10][NN]
  float* d_ar2 = d_al2 + (size_t)10 * NN;
  bf16* d_h2all = (bf16*)alloc((size_t)10 * MP * 128 * 2);
  // alpha rows for up to 10 planes: [(NE+NN) rows][24B]
  unsigned int* d_alphaG = (unsigned int*)alloc((size_t)10 * (NE + NN) * 24);
  // uni region: xagg2 (G planes) overlaid with tail buffers.
  char* uni = base + off;
  size_t avail = (ws_size > off) ? (ws_size - off) : 0;
  size_t need10 = (size_t)10 * 10 * MP * 64 * 2;  // 129,433,600
  int G = (avail >= need10 + 65536) ? 10 : 5;
  bf16* d_xagg2 = (bf16*)uni;                // G x 10 x MP x 64 x 2
  bf16* d_out2all = (bf16*)uni;              // 10 x NN x 128 x 2 = 25,600,000 B
  bf16* d_gall = (bf16*)(uni + 25600000);    // 1,310,720 B
  float* d_xc = (float*)(uni + 26910720);    // 1,048,576 B
  bf16* d_xcb = (bf16*)(uni + 27959296);     // 524,288 B
  bf16* d_cnb = (bf16*)(uni + 28483584);     // 983,040 B
  bf16* d_m1b = (bf16*)(uni + 29466624);     // 2,097,152 B
  bf16* d_m2b = (bf16*)(uni + 31563776);     // 524,288 B
  float* d_f3 = (float*)(uni + 32088064);    // 262,144 B

  ConvTable tab;
  tab.d[0] = {x1, d_xpad, NN, FXD, MP, 64, 2, 0, 5, (MP + 3) / 4};
  tab.d[1] = {x2, d_xpad, NN, FXD, MP, 64, 2, 1, 5, (MP + 3) / 4};
  tab.d[2] = {W1, d_W1b, 1280, FXD, 1280, 64, 1, 0, 5, 320};
  tab.d[3] = {W2, d_W2b, 128, 1280, 128, 1280, 1, 0, 5, 32};
  tab.d[4] = {Wg, d_Wgb, 128, 128, 128, 128, 1, 0, 5, 32};
  tab.d[5] = {Wr1, d_Wr1b, 2048, FXT, 2048, 960, 1, 0, 1, 512};
  tab.d[6] = {Wr2, d_Wr2b, 512, 2048, 512, 2048, 1, 0, 1, 128};
  tab.d[7] = {Wr3, d_Wr3b, 256, 512, 256, 512, 1, 0, 1, 64};
  tab.d[8] = {Wf1, d_Wf1b, 2048, 512, 2048, 512, 1, 0, 1, 512};
  tab.d[9] = {Wf2, d_Wf2b, 512, 2048, 512, 2048, 1, 0, 1, 128};
  tab.d[10] = {Wf3, d_Wf3b, 128, 512, 128, 512, 1, 0, 1, 32};
  {
    int cum = 0;
    tab.blk0[0] = 0;
    for (int i = 0; i < 11; i++) {
      cum += tab.d[i].rowBlocks * tab.d[i].batch;
      tab.blk0[i + 1] = cum;
    }
    convert_all_kernel<<<dim3(cum), 256, 0, stream>>>(tab);
  }

  // CSR for all 10 planes
  hipMemsetAsync(d_cnt, 0, (size_t)10 * NN * 4, stream);
  hist_kernel<<<dim3((NE + 255) / 256, 1, 10), 256, 0, stream>>>(ei1, ei2, d_cnt);
  scan_kernel<<<10, 256, 0, stream>>>(d_cnt, d_offs);
  hipMemsetAsync(d_cnt, 0, (size_t)10 * NN * 4, stream);
  scatter_kernel<<<dim3((NE + 255) / 256, 1, 10), 256, 0, stream>>>(ei1, ei2, d_offs, d_cnt, d_srcs);

  // layer-1 attention logits: alr = xpad @ walrb^T (cols 0-9 al, 16-25 ar; others unused)
  walr_kernel<<<50, 256, 0, stream>>>(W1, a1s, a1d, d_walrb);
  mfma_gemm64<<<dim3(1, MP / 64, 10), 256, 0, stream>>>(
      d_xpad, (long)MP * 64, d_walrb, 4096, 1, nullptr, 0, 0,
      d_alr, (long)MP * 32, 32, 0, 32, 0, nullptr, 0, 0, 64, 0, 1.f);

  for (int pb = 0; pb < 10; pb += G) {
    alpha_kernel<<<dim3(NN / 4, 1, G), 256, 0, stream>>>(d_alr, d_offs, d_srcs, d_alphaG, pb);
    xagg_kernel<<<dim3(MP / 16, 1, G), 256, 0, stream>>>(d_xpad, d_alphaG, d_offs, d_srcs, d_xagg2, pb);
    fused_l1l2_kernel<<<dim3(1, MP / 128, G), 256, 0, stream>>>(
        d_xagg2, d_W1b, b1, d_W2b, a2s, a2d, d_al2, d_ar2, d_h2all, pb);
  }

  // batched tail over all 10 planes
  hipMemsetAsync(d_xc, 0, (size_t)BB * 512 * 4, stream);
  gat_agg1_kernel<<<dim3(2500, 1, 10), 256, 0, stream>>>(
      d_h2all, d_al2, d_ar2, d_offs, d_srcs, b2, d_out2all);
  pool_max_kernel<<<dim3(BB / 4, 1, 10), 256, 0, stream>>>(d_out2all, d_gall);
  // xc[:, (z&1)*128 : +128] += relu(g_z @ Wg_{z>>1}^T + bg_{z>>1}) * 0.2, one dispatch
  mfma_gemm64<<<dim3(2, BB / 64, 10), 256, 0, stream>>>(
      d_gall, (long)BB * 128, d_Wgb, 128 * 128, 1,
      bg, 0, 128,
      d_xc, 0, 512, 2, 128, 128, nullptr, 0, 0, 128, 1, 0.2f);

  // cell reduction MLP -> xc[:,256:512]
  l2norm_b_kernel<<<BB, 256, 0, stream>>>((const float*)cell, d_cnb, FXT, 960);
  mfma_gemm64<<<dim3(32, 8, 1), 256, 0, stream>>>(
      d_cnb, 0, d_Wr1b, 0, 0, br1, 0, 0, nullptr, 0, 0, 0, 1 << 30, 0, d_m1b, 0, 2048, 960, 1, 1.f);
  mfma_gemm64<<<dim3(8, 8, 1), 256, 0, stream>>>(
      d_m1b, 0, d_Wr2b, 0, 0, br2, 0, 0, nullptr, 0, 0, 0, 1 << 30, 0, d_m2b, 0, 512, 2048, 1, 1.f);
  mfma_gemm64<<<dim3(4, 8, 1), 256, 0, stream>>>(
      d_m2b, 0, d_Wr3b, 0, 0, br3, 0, 0, d_xc + 256, 0, 512, 0, 1 << 30, 0, nullptr, 0, 0, 512, 1, 1.f);

  // head MLP
  l2norm_b_kernel<<<BB, 256, 0, stream>>>(d_xc, d_xcb, 512, 512);
  mfma_gemm64<<<dim3(32, 8, 1), 256, 0, stream>>>(
      d_xcb, 0, d_Wf1b, 0, 0, bf1, 0, 0, nullptr, 0, 0, 0, 1 << 30, 0, d_m1b, 0, 2048, 512, 1, 1.f);
  mfma_gemm64<<<dim3(8, 8, 1), 256, 0, stream>>>(
      d_m1b, 0, d_Wf2b, 0, 0, bf2, 0, 0, nullptr, 0, 0, 0, 1 << 30, 0, d_m2b, 0, 512, 2048, 1, 1.f);
  mfma_gemm64<<<dim3(2, 8, 1), 256, 0, stream>>>(
      d_m2b, 0, d_Wf3b, 0, 0, bf3, 0, 0, d_f3, 0, 128, 0, 1 << 30, 0, nullptr, 0, 0, 512, 1, 1.f);
  final_out_kernel<<<BB, 64, 0, stream>>>(d_f3, Wo, bo, (float*)d_out);
}

// Round 9
// 941.203 us; speedup vs baseline: 1.0579x; 1.0459x over previous
//
#include <hip/hip_runtime.h>
#include <hip/hip_bf16.h>
#include <math.h>

#define NUM_NET 5
#define NN 10000
#define NE 160000
#define BB 512
#define FXD 62
#define FXT 954
#define MP 10112  // NN padded to multiple of 128

typedef __bf16 bf16x8 __attribute__((ext_vector_type(8)));
typedef float f32x4 __attribute__((ext_vector_type(4)));
typedef __hip_bfloat16 bf16;

// ---------------- helpers (inputs/outputs are f32 — R7-verified) ----------------
__device__ __forceinline__ float ldf(const void* p, size_t i) {
  return ((const float*)p)[i];
}
__device__ __forceinline__ float lky(float v) { return v > 0.f ? v : 0.2f * v; }
__device__ __forceinline__ float eluf(float v) { return v > 0.f ? v : (__expf(v) - 1.f); }
__device__ __forceinline__ unsigned int packbf(float a, float b) {
  __hip_bfloat162 t;
  t.x = __float2bfloat16(a);
  t.y = __float2bfloat16(b);
  return *(unsigned int*)&t;  // a in low 16, b in high 16
}

// ---------------- mega convert: flattened exact grid (no no-op blocks) ----------------
struct ConvDesc {
  const void* src;
  bf16* dst;
  int M, K, Mp, Kp, mult, add, batch, rowBlocks;
};
struct ConvTable { ConvDesc d[11]; int blk0[12]; };

__global__ void convert_all_kernel(ConvTable tab) {
  int bid = blockIdx.x;
  int di = 0;
#pragma unroll
  for (int d = 1; d < 11; d++) di += (bid >= tab.blk0[d]);
  ConvDesc c = tab.d[di];
  int local = bid - tab.blk0[di];
  int b = local / c.rowBlocks;
  int rb = local - b * c.rowBlocks;
  int wave = threadIdx.x >> 6, lane = threadIdx.x & 63;
  int r = rb * 4 + wave;
  if (r >= c.Mp) return;
  const float* srow = (const float*)c.src + ((size_t)b * c.M + r) * c.K;
  bf16* drow = c.dst + (((size_t)(b * c.mult + c.add)) * c.Mp + r) * c.Kp;
  bool rowok = r < c.M;
  for (int k = lane; k < c.Kp; k += 64) {
    float v = (rowok && k < c.K) ? srow[k] : 0.f;
    drow[k] = __float2bfloat16(v);
  }
}

// ---------------- CSR build (planes = net*2+br) ----------------
__global__ void hist_kernel(const int* __restrict__ ei1, const int* __restrict__ ei2,
                            int* __restrict__ counts) {
  int z = blockIdx.z;
  int br = z & 1, net = z >> 1;
  const int* base = (br ? ei2 : ei1) + (size_t)net * 2 * NE;
  const int* dst = base + NE;
  int* cnt = counts + (size_t)z * NN;
  int i = blockIdx.x * 256 + threadIdx.x;
  if (i < NE) atomicAdd(&cnt[dst[i]], 1);
}

// 4-wide scan: 1024 counts per round
__global__ void scan_kernel(const int* __restrict__ counts, int* __restrict__ offs) {
  int z = blockIdx.x;
  counts += (size_t)z * NN;
  offs += (size_t)z * (NN + 1);
  __shared__ int sdata[256];
  __shared__ int s_carry;
  int t = threadIdx.x;
  if (t == 0) { s_carry = 0; offs[0] = 0; }
  __syncthreads();
  for (int base = 0; base < NN; base += 1024) {
    int loc = base + t * 4;
    int v[4];
#pragma unroll
    for (int j = 0; j < 4; j++) v[j] = (loc + j < NN) ? counts[loc + j] : 0;
    int sum4 = v[0] + v[1] + v[2] + v[3];
    sdata[t] = sum4;
    __syncthreads();
    for (int o = 1; o < 256; o <<= 1) {
      int x = (t >= o) ? sdata[t - o] : 0;
      __syncthreads();
      sdata[t] += x;
      __syncthreads();
    }
    int running = sdata[t] - sum4 + s_carry;  // exclusive prefix + carry
#pragma unroll
    for (int j = 0; j < 4; j++) {
      running += v[j];
      if (loc + j < NN) offs[loc + j + 1] = running;
    }
    int tot = sdata[255];
    __syncthreads();
    if (t == 0) s_carry += tot;
    __syncthreads();
  }
}

__global__ void scatter_kernel(const int* __restrict__ ei1, const int* __restrict__ ei2,
                               const int* __restrict__ offs, int* __restrict__ fill,
                               int* __restrict__ csrc) {
  int z = blockIdx.z;
  int br = z & 1, net = z >> 1;
  const int* base = (br ? ei2 : ei1) + (size_t)net * 2 * NE;
  const int* src = base;
  const int* dst = base + NE;
  const int* offz = offs + (size_t)z * (NN + 1);
  int* fillz = fill + (size_t)z * NN;
  int* out = csrc + (size_t)z * NE;
  int i = blockIdx.x * 256 + threadIdx.x;
  if (i < NE) {
    int d = dst[i];
    int p = offz[d] + atomicAdd(&fillz[d], 1);
    out[p] = src[i];
  }
}

// ---------------- w_al/w_ar precompute -> bf16 [net][64][64] rows 0-9 al, 16-25 ar ----------
__global__ __launch_bounds__(256) void walr_kernel(const void* __restrict__ W1,
                                                   const void* __restrict__ a1s,
                                                   const void* __restrict__ a1d,
                                                   bf16* __restrict__ walrb) {
  int net = blockIdx.x / 10, head = blockIdx.x % 10;
  int t = threadIdx.x, w = t >> 6, k = t & 63;
  __shared__ float ps[8][64];
  float accs = 0.f, accd = 0.f;
  for (int c = w; c < 128; c += 4) {
    float wv = (k < FXD)
        ? ldf(W1, (size_t)net * 1280 * FXD + (size_t)(head * 128 + c) * FXD + k) : 0.f;
    float vs = ldf(a1s, (size_t)net * 1280 + head * 128 + c);
    float vd = ldf(a1d, (size_t)net * 1280 + head * 128 + c);
    accs = fmaf(wv, vs, accs);
    accd = fmaf(wv, vd, accd);
  }
  ps[w][k] = accs;
  ps[4 + w][k] = accd;
  __syncthreads();
  if (w == 0) {
    float s = ps[0][k] + ps[1][k] + ps[2][k] + ps[3][k];
    float dd = ps[4][k] + ps[5][k] + ps[6][k] + ps[7][k];
    walrb[(size_t)net * 4096 + head * 64 + k] = __float2bfloat16(s);
    walrb[(size_t)net * 4096 + (16 + head) * 64 + k] = __float2bfloat16(dd);
  }
}

// ---------------- alpha precompute: wave per dst, per-head softmax -> bf16 alphas ----------
// Row layout (24B): [5 x u32 packed bf16 alpha pairs][u32 dl], dl = d & 15.
// Real edges at CSR position e -> row e; self-loop of dst d -> row NE + d.
__global__ __launch_bounds__(256) void alpha_kernel(
    const float* __restrict__ alrA, const int* __restrict__ offsA,
    const int* __restrict__ srcsA, unsigned int* __restrict__ alphaG, int planeBase) {
  int z = blockIdx.z;
  int plane = planeBase + z;
  const float* alr = alrA + (size_t)plane * MP * 32;
  const int* offs = offsA + (size_t)plane * (NN + 1);
  const int* srcs = srcsA + (size_t)plane * NE;
  unsigned int* ag = alphaG + (size_t)z * (NE + NN) * 6;
  int wave = threadIdx.x >> 6, lane = threadIdx.x & 63;
  int d = blockIdx.x * 4 + wave;
  if (d >= NN) return;
  int e0 = offs[d], ne = offs[d + 1] - e0;
  int total = ne + 1;  // + self loop
  float arh[10];
#pragma unroll
  for (int h = 0; h < 10; h++) arh[h] = alr[(size_t)d * 32 + 16 + h];
  if (total <= 64) {
    int sc = (lane < ne) ? srcs[e0 + lane] : d;
    bool act = lane < total;
    const float* ap = &alr[(size_t)sc * 32];
    float v[10], m[10];
#pragma unroll
    for (int h = 0; h < 10; h++) {
      v[h] = act ? lky(ap[h] + arh[h]) : -1e30f;
      m[h] = v[h];
    }
#pragma unroll
    for (int o = 32; o > 0; o >>= 1)
#pragma unroll
      for (int h = 0; h < 10; h++) m[h] = fmaxf(m[h], __shfl_xor(m[h], o));
    float p[10], s[10];
#pragma unroll
    for (int h = 0; h < 10; h++) {
      p[h] = act ? __expf(v[h] - m[h]) : 0.f;
      s[h] = p[h];
    }
#pragma unroll
    for (int o = 32; o > 0; o >>= 1)
#pragma unroll
      for (int h = 0; h < 10; h++) s[h] += __shfl_xor(s[h], o);
    if (act) {
      float inv[10];
#pragma unroll
      for (int h = 0; h < 10; h++) inv[h] = 1.f / s[h];
      unsigned int wv[6];
#pragma unroll
      for (int hp = 0; hp < 5; hp++)
        wv[hp] = packbf(p[2 * hp] * inv[2 * hp], p[2 * hp + 1] * inv[2 * hp + 1]);
      wv[5] = (unsigned int)(d & 15);
      size_t row = (lane < ne) ? (size_t)(e0 + lane) : (size_t)(NE + d);
      unsigned int* rp = ag + row * 6;
#pragma unroll
      for (int j = 0; j < 6; j++) rp[j] = wv[j];
    }
  } else {
    // rare fallback: degree+1 > 64, two-pass strided
    float m[10], s[10];
#pragma unroll
    for (int h = 0; h < 10; h++) { m[h] = -1e30f; s[h] = 0.f; }
    for (int idx = lane; idx < total; idx += 64) {
      int sc = (idx < ne) ? srcs[e0 + idx] : d;
      const float* ap = &alr[(size_t)sc * 32];
#pragma unroll
      for (int h = 0; h < 10; h++) {
        float v = lky(ap[h] + arh[h]);
        if (v > m[h]) { s[h] = s[h] * __expf(m[h] - v) + 1.f; m[h] = v; }
        else s[h] += __expf(v - m[h]);
      }
    }
#pragma unroll
    for (int o = 32; o > 0; o >>= 1)
#pragma unroll
      for (int h = 0; h < 10; h++) {
        float mo = __shfl_xor(m[h], o), so = __shfl_xor(s[h], o);
        if (so > 0.f) {
          if (mo > m[h]) { s[h] = s[h] * __expf(m[h] - mo) + so; m[h] = mo; }
          else s[h] += so * __expf(mo - m[h]);
        }
      }
    for (int idx = lane; idx < total; idx += 64) {
      int sc = (idx < ne) ? srcs[e0 + idx] : d;
      const float* ap = &alr[(size_t)sc * 32];
      unsigned int wv[6];
#pragma unroll
      for (int hp = 0; hp < 5; hp++) {
        float v0 = lky(ap[2 * hp] + arh[2 * hp]);
        float v1 = lky(ap[2 * hp + 1] + arh[2 * hp + 1]);
        wv[hp] = packbf(__expf(v0 - m[2 * hp]) / s[2 * hp],
                        __expf(v1 - m[2 * hp + 1]) / s[2 * hp + 1]);
      }
      wv[5] = (unsigned int)(d & 15);
      size_t row = (idx < ne) ? (size_t)(e0 + idx) : (size_t)(NE + d);
      unsigned int* rp = ag + row * 6;
#pragma unroll
      for (int j = 0; j < 6; j++) rp[j] = wv[j];
    }
  }
}

// ---------------- xagg: MFMA alpha @ X, prefetched 2-barrier pipeline ----------------
struct Pref {
  uint4 xv;
  unsigned int a0, a1, a2, a3, a4;
  int dl;
  int av;
};

__device__ __forceinline__ void issue_pref(
    Pref& P, int kb, int e, int fblk, int tid, int nreal, int K_len, int e_begin,
    int d0, const int* __restrict__ srcs, const bf16* __restrict__ xp,
    const unsigned int* __restrict__ ag) {
  int ke = kb + e;
  int src;
  if (ke < nreal) {
    src = srcs[e_begin + ke];
  } else {
    int sl = ke - nreal;
    src = d0 + (sl < 16 ? sl : 0);
  }
  P.xv = *(const uint4*)&xp[(size_t)src * 64 + fblk * 8];
  P.av = 0;
  if (tid < 32 && ke < K_len) {
    P.av = 1;
    size_t row = (ke < nreal) ? (size_t)(e_begin + ke) : (size_t)(NE + d0 + (ke - nreal));
    const unsigned int* rp = ag + row * 6;
    P.a0 = rp[0]; P.a1 = rp[1]; P.a2 = rp[2]; P.a3 = rp[3]; P.a4 = rp[4];
    P.dl = (int)rp[5];
  }
}

__global__ __launch_bounds__(256) void xagg_kernel(
    const bf16* __restrict__ xpadA, const unsigned int* __restrict__ alphaG,
    const int* __restrict__ offsA, const int* __restrict__ srcsA,
    bf16* __restrict__ xagg2, int planeBase) {
  int z = blockIdx.z;
  int plane = planeBase + z;
  bf16* xagg = xagg2 + (size_t)z * 10 * MP * 64;
  int d0 = blockIdx.x * 16;
  int tid = threadIdx.x;

  if (d0 >= NN) {  // padding rows: zero-fill output tile (rows NN..MP-1)
    uint4 zz; zz.x = zz.y = zz.z = zz.w = 0u;
#pragma unroll
    for (int k = 0; k < 5; k++) {
      int i = tid + k * 256;  // 10*16*8 = 1280 uint4
      int h = i >> 7, rem = i & 127, row = rem >> 3, seg = rem & 7;
      *(uint4*)&xagg[((size_t)h * MP + d0 + row) * 64 + seg * 8] = zz;
    }
    return;
  }

  const bf16* xp = xpadA + (size_t)plane * MP * 64;
  const int* offs = offsA + (size_t)plane * (NN + 1);
  const int* srcs = srcsA + (size_t)plane * NE;
  const unsigned int* ag = alphaG + (size_t)z * (NE + NN) * 6;

  __shared__ __align__(16) short A_s[10 * 16 * 40];  // 12800 B
  __shared__ __align__(16) short Xt_s[64 * 40];      // 5120 B

  int e_begin = offs[d0];
  int nreal = offs[d0 + 16] - e_begin;
  int K_len = nreal + 16;

  int e = tid & 31, fblk = tid >> 5;
  int lane = tid & 63, wave = tid >> 6;
  int l15 = lane & 15, quad = lane >> 4;
  int hbase = (wave >> 1) * 5;   // waves 0,1 -> heads 0-4; waves 2,3 -> heads 5-9
  int wcol = (wave & 1) * 32;    // 32 feat cols per wave

  Pref Pn;
  issue_pref(Pn, 0, e, fblk, tid, nreal, K_len, e_begin, d0, srcs, xp, ag);

  // prologue: zero A fully
  {
    f32x4 z4 = (f32x4){0.f, 0.f, 0.f, 0.f};
    for (int i = tid; i < 800; i += 256) ((f32x4*)A_s)[i] = z4;
  }
  f32x4 acc[5][2];
#pragma unroll
  for (int i = 0; i < 5; i++)
#pragma unroll
    for (int j = 0; j < 2; j++) acc[i][j] = (f32x4){0.f, 0.f, 0.f, 0.f};
  int prev_dl = -1;
  __syncthreads();  // A zeroed

  for (int kb = 0; kb < K_len; kb += 32) {
    Pref Pc = Pn;
    // ---- W phase: A clear+scatter (tid<32), Xt stage (all) ----
    if (tid < 32) {
      if (prev_dl >= 0) {
#pragma unroll
        for (int h = 0; h < 10; h++) A_s[(h * 16 + prev_dl) * 40 + e] = 0;
      }
      prev_dl = -1;
      if (Pc.av) {
        int dlc = Pc.dl;
        A_s[(0 * 16 + dlc) * 40 + e] = (short)(Pc.a0 & 0xffff);
        A_s[(1 * 16 + dlc) * 40 + e] = (short)(Pc.a0 >> 16);
        A_s[(2 * 16 + dlc) * 40 + e] = (short)(Pc.a1 & 0xffff);
        A_s[(3 * 16 + dlc) * 40 + e] = (short)(Pc.a1 >> 16);
        A_s[(4 * 16 + dlc) * 40 + e] = (short)(Pc.a2 & 0xffff);
        A_s[(5 * 16 + dlc) * 40 + e] = (short)(Pc.a2 >> 16);
        A_s[(6 * 16 + dlc) * 40 + e] = (short)(Pc.a3 & 0xffff);
        A_s[(7 * 16 + dlc) * 40 + e] = (short)(Pc.a3 >> 16);
        A_s[(8 * 16 + dlc) * 40 + e] = (short)(Pc.a4 & 0xffff);
        A_s[(9 * 16 + dlc) * 40 + e] = (short)(Pc.a4 >> 16);
        prev_dl = dlc;
      }
    }
    {
      int fb8 = fblk * 8;
#pragma unroll
      for (int j = 0; j < 4; j++) {
        unsigned int w = ((const unsigned int*)&Pc.xv)[j];
        Xt_s[(fb8 + 2 * j) * 40 + e] = (short)(w & 0xffff);
        Xt_s[(fb8 + 2 * j + 1) * 40 + e] = (short)(w >> 16);
      }
    }
    // prefetch next chunk (flies over the MFMA phase)
    if (kb + 32 < K_len)
      issue_pref(Pn, kb + 32, e, fblk, tid, nreal, K_len, e_begin, d0, srcs, xp, ag);
    __syncthreads();  // A + Xt ready
    // ---- MFMA phase ----
    bf16x8 b0 = *(const bf16x8*)&Xt_s[(wcol + l15) * 40 + quad * 8];
    bf16x8 b1 = *(const bf16x8*)&Xt_s[(wcol + 16 + l15) * 40 + quad * 8];
#pragma unroll
    for (int hh = 0; hh < 5; hh++) {
      bf16x8 af = *(const bf16x8*)&A_s[((hbase + hh) * 16 + l15) * 40 + quad * 8];
      acc[hh][0] = __builtin_amdgcn_mfma_f32_16x16x32_bf16(af, b0, acc[hh][0], 0, 0, 0);
      acc[hh][1] = __builtin_amdgcn_mfma_f32_16x16x32_bf16(af, b1, acc[hh][1], 0, 0, 0);
    }
    __syncthreads();  // MFMA reads done before next W phase
  }

  // ---- epilogue: direct global stores (D map: row=quad*4+r, col=l15) ----
#pragma unroll
  for (int hh = 0; hh < 5; hh++) {
    int h = hbase + hh;
#pragma unroll
    for (int ft = 0; ft < 2; ft++) {
#pragma unroll
      for (int r = 0; r < 4; r++) {
        int drow = d0 + quad * 4 + r;
        xagg[((size_t)h * MP + drow) * 64 + wcol + ft * 16 + l15] =
            __float2bfloat16(acc[hh][ft][r]);
      }
    }
  }
}

// ---------------- fused L1+L2 GEMM + dots, col-merged (full 128 h2 cols per block) --------
// R6-exact version: direct global->LDS staging, single full-K W2 stage, 4 barriers/h.
// LDS overlay: phase1 Ah(64x72)+W1s(128x72)=27.6KB; phase2 Ps(64x136)+W2s(128x136)=52.2KB.
// Verified 170us @ G=10 (R6). Split-k (R7), reg-prefetch (R3/R4), BM=128 (R8) all lost.
__global__ __launch_bounds__(256) void fused_l1l2_kernel(
    const bf16* __restrict__ xagg2, const bf16* __restrict__ W1b,
    const void* __restrict__ b1raw, const bf16* __restrict__ W2b,
    const void* __restrict__ a2s, const void* __restrict__ a2d,
    float* __restrict__ al2A, float* __restrict__ ar2A,
    bf16* __restrict__ h2all, int planeBase) {
  int zz = blockIdx.z;
  int plane = planeBase + zz;
  int net = plane >> 1;
  long ow1 = (long)net * 1280 * 64;
  long ob1 = (long)net * 1280;
  long ow2 = (long)net * 128 * 1280;
  long oa2 = (long)net * 128;
  const bf16* xagg = xagg2 + (size_t)zz * 10 * MP * 64;
  float* al2p = al2A + (size_t)plane * NN;
  float* ar2p = ar2A + (size_t)plane * NN;
  bf16* h2 = h2all + (size_t)plane * MP * 128;
  int r0 = blockIdx.y * 64;
  __shared__ __align__(16) char uraw[52224];
  bf16* Ah = (bf16*)uraw;             // 64 x 72
  bf16* W1s = Ah + 64 * 72;           // 128 x 72
  bf16* Ps = (bf16*)uraw;             // 64 x 136 (overlays Ah/W1s)
  bf16* W2s = Ps + 64 * 136;          // 128 x 136
  __shared__ float s_dot[2][2][32][2];  // [rowHalf][colHalf][rowLocal][al/ar]
  int tid = threadIdx.x, lane = tid & 63, wave = tid >> 6;
  int l15 = lane & 15, quad = lane >> 4;
  int rowHalf = wave >> 1, colHalf = wave & 1;
  int wr = rowHalf * 32, wc = colHalf * 64;
  f32x4 acc2[2][4];
#pragma unroll
  for (int i = 0; i < 2; i++)
#pragma unroll
    for (int j = 0; j < 4; j++) acc2[i][j] = (f32x4){0.f, 0.f, 0.f, 0.f};

  for (int h = 0; h < 10; h++) {
    __syncthreads();  // prior stage2 done with Ps/W2s
    for (int i = tid; i < 512; i += 256) {
      int r = i >> 3, seg = i & 7;
      *(uint4*)&Ah[r * 72 + seg * 8] =
          *(const uint4*)&xagg[((size_t)h * MP + r0 + r) * 64 + seg * 8];
    }
    for (int i = tid; i < 1024; i += 256) {
      int r = i >> 3, seg = i & 7;
      *(uint4*)&W1s[r * 72 + seg * 8] =
          *(const uint4*)&W1b[ow1 + (size_t)(h * 128 + r) * 64 + seg * 8];
    }
    __syncthreads();
    // stage 1: P = xagg_h @ W1_h^T (each wave -> 32 of 128 P-cols, all 64 rows)
    f32x4 acc1[4][2];
#pragma unroll
    for (int i = 0; i < 4; i++)
#pragma unroll
      for (int j = 0; j < 2; j++) acc1[i][j] = (f32x4){0.f, 0.f, 0.f, 0.f};
#pragma unroll
    for (int kc = 0; kc < 2; kc++) {
      bf16x8 af[4], bfr[2];
#pragma unroll
      for (int mi = 0; mi < 4; mi++)
        af[mi] = *(const bf16x8*)&Ah[(mi * 16 + l15) * 72 + kc * 32 + quad * 8];
#pragma unroll
      for (int ni = 0; ni < 2; ni++)
        bfr[ni] = *(const bf16x8*)&W1s[(wave * 32 + ni * 16 + l15) * 72 + kc * 32 + quad * 8];
#pragma unroll
      for (int mi = 0; mi < 4; mi++)
#pragma unroll
        for (int ni = 0; ni < 2; ni++)
          acc1[mi][ni] = __builtin_amdgcn_mfma_f32_16x16x32_bf16(af[mi], bfr[ni], acc1[mi][ni], 0, 0, 0);
    }
    __syncthreads();  // all waves done reading Ah/W1s before Ps overwrite
    // write P (bias + ELU) and stage W2s (all 128 rows)
#pragma unroll
    for (int ni = 0; ni < 2; ni++) {
      int pcol = wave * 32 + ni * 16 + l15;
      float bv = ldf(b1raw, ob1 + h * 128 + pcol);
#pragma unroll
      for (int mi = 0; mi < 4; mi++)
#pragma unroll
        for (int r = 0; r < 4; r++)
          Ps[(mi * 16 + quad * 4 + r) * 136 + pcol] =
              __float2bfloat16(eluf(acc1[mi][ni][r] + bv));
    }
    for (int i = tid; i < 2048; i += 256) {
      int r = i >> 4, seg = i & 15;
      *(uint4*)&W2s[r * 136 + seg * 8] =
          *(const uint4*)&W2b[ow2 + (size_t)r * 1280 + h * 128 + seg * 8];
    }
    __syncthreads();
    // stage 2: acc2 += P @ W2_h^T  (wave: 32 rows x 64 cols)
#pragma unroll
    for (int kc = 0; kc < 4; kc++) {
      bf16x8 pa[2], pb[4];
#pragma unroll
      for (int mi = 0; mi < 2; mi++)
        pa[mi] = *(const bf16x8*)&Ps[(wr + mi * 16 + l15) * 136 + kc * 32 + quad * 8];
#pragma unroll
      for (int ni = 0; ni < 4; ni++)
        pb[ni] = *(const bf16x8*)&W2s[(wc + ni * 16 + l15) * 136 + kc * 32 + quad * 8];
#pragma unroll
      for (int mi = 0; mi < 2; mi++)
#pragma unroll
        for (int ni = 0; ni < 4; ni++)
          acc2[mi][ni] = __builtin_amdgcn_mfma_f32_16x16x32_bf16(pa[mi], pb[ni], acc2[mi][ni], 0, 0, 0);
    }
  }
  // epilogue: h2 write + attention dots (combined across col-halves in LDS)
  float asv[4], adv[4];
#pragma unroll
  for (int ni = 0; ni < 4; ni++) {
    int col = wc + ni * 16 + l15;
    asv[ni] = ldf(a2s, oa2 + col);
    adv[ni] = ldf(a2d, oa2 + col);
  }
#pragma unroll
  for (int mi = 0; mi < 2; mi++) {
#pragma unroll
    for (int r = 0; r < 4; r++) {
      int rl = mi * 16 + quad * 4 + r;  // row-local within this wave's 32
      int row = r0 + wr + rl;
      float psum = 0.f, pdum = 0.f;
#pragma unroll
      for (int ni = 0; ni < 4; ni++) {
        float v = acc2[mi][ni][r];
        h2[(size_t)row * 128 + wc + ni * 16 + l15] = __float2bfloat16(v);
        psum = fmaf(v, asv[ni], psum);
        pdum = fmaf(v, adv[ni], pdum);
      }
#pragma unroll
      for (int o = 1; o < 16; o <<= 1) {
        psum += __shfl_xor(psum, o);
        pdum += __shfl_xor(pdum, o);
      }
      if (l15 == 0) {
        s_dot[rowHalf][colHalf][rl][0] = psum;
        s_dot[rowHalf][colHalf][rl][1] = pdum;
      }
    }
  }
  __syncthreads();
  if (tid < 64) {
    int row = r0 + tid;
    if (row < NN) {
      int rh = tid >> 5, rl = tid & 31;
      al2p[row] = s_dot[rh][0][rl][0] + s_dot[rh][1][rl][0];
      ar2p[row] = s_dot[rh][0][rl][1] + s_dot[rh][1][rl][1];
    }
  }
}

// ---------------- MFMA GEMM 64x64 tile (bias is raw f32 input) ----------------
__global__ __launch_bounds__(256) void mfma_gemm64(
    const bf16* __restrict__ A, long Az, const bf16* __restrict__ B, long Bz, int bdiv,
    const void* __restrict__ bias, long biasoff, long biaszs,
    float* __restrict__ Cf, long Cfz, int ldcf, int accum, int ncols, int brcol,
    bf16* __restrict__ Cb, long Cbz, int ldcb,
    int K, int act, float scale) {
  int z = blockIdx.z;
  int zb = bdiv ? (z >> 1) : z;
  A += (size_t)z * Az;
  B += (size_t)zb * Bz;
  if (Cf) Cf += (size_t)z * Cfz + (size_t)(z & 1) * brcol;
  if (Cb) Cb += (size_t)z * Cbz;
  const bf16* Ag = A + (size_t)blockIdx.y * 64 * K;
  const bf16* Bg = B + (size_t)blockIdx.x * 64 * K;
  __shared__ __align__(16) bf16 Asm[64 * 40];
  __shared__ __align__(16) bf16 Bsm[64 * 40];
  int tid = threadIdx.x;
  int lane = tid & 63, wave = tid >> 6;
  int wr = (wave >> 1) * 32, wc = (wave & 1) * 32;
  int l15 = lane & 15, quad = lane >> 4;
  f32x4 acc[2][2];
#pragma unroll
  for (int i = 0; i < 2; i++)
#pragma unroll
    for (int j = 0; j < 2; j++) acc[i][j] = (f32x4){0.f, 0.f, 0.f, 0.f};
  int isB = tid >> 7;
  int srow = (tid & 127) >> 1, shalf = tid & 1;
  const bf16* G = isB ? Bg : Ag;
  bf16* S = isB ? Bsm : Asm;
  for (int k0 = 0; k0 < K; k0 += 32) {
    const uint4* g = (const uint4*)(G + (size_t)srow * K + k0 + shalf * 16);
    uint4 v0 = g[0], v1 = g[1];
    __syncthreads();
    *(uint4*)&S[srow * 40 + shalf * 16] = v0;
    *(uint4*)&S[srow * 40 + shalf * 16 + 8] = v1;
    __syncthreads();
    bf16x8 af[2], bfr[2];
#pragma unroll
    for (int mi = 0; mi < 2; mi++)
      af[mi] = *(const bf16x8*)&Asm[(wr + mi * 16 + l15) * 40 + quad * 8];
#pragma unroll
    for (int ni = 0; ni < 2; ni++)
      bfr[ni] = *(const bf16x8*)&Bsm[(wc + ni * 16 + l15) * 40 + quad * 8];
#pragma unroll
    for (int mi = 0; mi < 2; mi++)
#pragma unroll
      for (int ni = 0; ni < 2; ni++)
        acc[mi][ni] = __builtin_amdgcn_mfma_f32_16x16x32_bf16(af[mi], bfr[ni], acc[mi][ni], 0, 0, 0);
  }
#pragma unroll
  for (int ni = 0; ni < 2; ni++) {
    int col = blockIdx.x * 64 + wc + ni * 16 + l15;
    if (col >= ncols) continue;
    float bv = bias ? ldf(bias, biasoff + (size_t)zb * biaszs + col) : 0.f;
#pragma unroll
    for (int mi = 0; mi < 2; mi++) {
      int rbase = blockIdx.y * 64 + wr + mi * 16 + quad * 4;
      f32x4 c = acc[mi][ni];
#pragma unroll
      for (int r = 0; r < 4; r++) {
        float v = c[r] + bv;
        if (act == 1) v = fmaxf(v, 0.f);
        else if (act == 2) v = eluf(v);
        v *= scale;
        if (Cf) {
          size_t ci = (size_t)(rbase + r) * ldcf + col;
          if (accum == 1) Cf[ci] += v;
          else if (accum == 2) atomicAdd(&Cf[ci], v);
          else Cf[ci] = v;
        }
        if (Cb) Cb[(size_t)(rbase + r) * ldcb + col] = __float2bfloat16(v);
      }
    }
  }
}

// ---------------- GAT layer-2 aggregation: MFMA alpha @ h2 (xagg skeleton, 1 head) -------
// 16 dsts/block (NN/16 = 625 exact), 32-edge chunks + 16 self-edges, inline 1-head
// softmax (16 par-lanes per dst + shfl_xor merge), sparse A[16][40], Xt[128][40],
// 2 MFMA/chunk/wave (4 waves x 32 feat cols). Bias+ELU epilogue, direct stores.
struct Pref2 {
  uint4 xv0, xv1;
  float alv;
  int dl;
  int av;
};

__device__ __forceinline__ void issue_pref2(
    Pref2& P, int kb, int e, int fblk, int tid, int nreal, int K_len, int e_begin,
    int d0, const int* __restrict__ srcs, const bf16* __restrict__ h,
    const float* __restrict__ al, const int* s_offs) {
  int ke = kb + e;
  int src, dl;
  if (ke < nreal) {
    int eg = e_begin + ke;
    src = srcs[eg];
    dl = 0;
#pragma unroll
    for (int jj = 1; jj < 16; jj++) dl += (eg >= s_offs[jj]);
  } else {
    int sl = ke - nreal;
    dl = sl;
    src = d0 + (sl < 16 ? sl : 0);
  }
  P.xv0 = *(const uint4*)&h[(size_t)src * 128 + fblk * 16];
  P.xv1 = *(const uint4*)&h[(size_t)src * 128 + fblk * 16 + 8];
  P.av = 0;
  if (tid < 32 && ke < K_len) {
    P.av = 1;
    P.alv = al[src];
    P.dl = dl;
  }
}

__global__ __launch_bounds__(256) void gat_agg2_kernel(
    const bf16* __restrict__ h2all, const float* __restrict__ alA, const float* __restrict__ arA,
    const int* __restrict__ offsA, const int* __restrict__ srcsA,
    const void* __restrict__ b2, bf16* __restrict__ out2all) {
  int z = blockIdx.z;
  int net = z >> 1;
  const bf16* h = h2all + (size_t)z * MP * 128;
  const float* al = alA + (size_t)z * NN;
  const float* ar = arA + (size_t)z * NN;
  const int* offs = offsA + (size_t)z * (NN + 1);
  const int* srcs = srcsA + (size_t)z * NE;
  int d0 = blockIdx.x * 16;
  int tid = threadIdx.x;

  __shared__ __align__(16) short A_s[16 * 40];     // 1280 B
  __shared__ __align__(16) short Xt_s[128 * 40];   // 10240 B
  __shared__ int s_offs[17];
  __shared__ float s_m[16], s_sinv[16], s_ar[16];

  if (tid < 17) s_offs[tid] = offs[d0 + tid];
  __syncthreads();
  int e_begin = s_offs[0];
  int nreal = s_offs[16] - e_begin;
  int K_len = nreal + 16;

  // ---- phase 1: per-dst 1-head online softmax (16 par-lanes per dst) ----
  {
    int dl = tid >> 4, par = tid & 15;
    int d = d0 + dl;
    float ard = ar[d];
    float m, s;
    if (par == 0) { m = lky(al[d] + ard); s = 1.f; }  // self-loop seed
    else { m = -1e30f; s = 0.f; }
    int ee = s_offs[dl + 1];
    for (int e2 = s_offs[dl] + par; e2 < ee; e2 += 16) {
      float v = lky(al[srcs[e2]] + ard);
      if (v > m) { s = s * __expf(m - v) + 1.f; m = v; }
      else s += __expf(v - m);
    }
#pragma unroll
    for (int o = 8; o >= 1; o >>= 1) {
      float mo = __shfl_xor(m, o), so = __shfl_xor(s, o);
      if (so > 0.f) {
        if (mo > m) { s = s * __expf(m - mo) + so; m = mo; }
        else s += so * __expf(mo - m);
      }
    }
    if (par == 0) { s_m[dl] = m; s_sinv[dl] = 1.f / s; s_ar[dl] = ard; }
  }

  int e = tid & 31, fblk = tid >> 5;  // 8 fblks x 16 feats
  int lane = tid & 63, wave = tid >> 6;
  int l15 = lane & 15, quad = lane >> 4;
  int wcol = wave * 32;

  Pref2 Pn;
  issue_pref2(Pn, 0, e, fblk, tid, nreal, K_len, e_begin, d0, srcs, h, al, s_offs);

  if (tid < 80) {  // zero A_s (1280 B = 80 uint4)
    uint4 zz; zz.x = zz.y = zz.z = zz.w = 0u;
    ((uint4*)A_s)[tid] = zz;
  }
  f32x4 acc[2];
  acc[0] = (f32x4){0.f, 0.f, 0.f, 0.f};
  acc[1] = (f32x4){0.f, 0.f, 0.f, 0.f};
  int prev_dl = -1;
  __syncthreads();  // phase-1 results + A zero visible

  for (int kb = 0; kb < K_len; kb += 32) {
    Pref2 Pc = Pn;
    // ---- W phase: alpha scatter (tid<32) + Xt stage (all) ----
    if (tid < 32) {
      if (prev_dl >= 0) A_s[prev_dl * 40 + e] = 0;
      prev_dl = -1;
      if (Pc.av) {
        float v = lky(Pc.alv + s_ar[Pc.dl]);
        float a = __expf(v - s_m[Pc.dl]) * s_sinv[Pc.dl];
        A_s[Pc.dl * 40 + e] = (short)(packbf(a, 0.f) & 0xffff);
        prev_dl = Pc.dl;
      }
    }
    {
      int fb = fblk * 16;
#pragma unroll
      for (int j = 0; j < 4; j++) {
        unsigned int w0 = ((const unsigned int*)&Pc.xv0)[j];
        Xt_s[(fb + 2 * j) * 40 + e] = (short)(w0 & 0xffff);
        Xt_s[(fb + 2 * j + 1) * 40 + e] = (short)(w0 >> 16);
        unsigned int w1 = ((const unsigned int*)&Pc.xv1)[j];
        Xt_s[(fb + 8 + 2 * j) * 40 + e] = (short)(w1 & 0xffff);
        Xt_s[(fb + 8 + 2 * j + 1) * 40 + e] = (short)(w1 >> 16);
      }
    }
    if (kb + 32 < K_len)
      issue_pref2(Pn, kb + 32, e, fblk, tid, nreal, K_len, e_begin, d0, srcs, h, al, s_offs);
    __syncthreads();  // A + Xt ready
    // ---- MFMA phase ----
    bf16x8 af = *(const bf16x8*)&A_s[l15 * 40 + quad * 8];
    bf16x8 b0 = *(const bf16x8*)&Xt_s[(wcol + l15) * 40 + quad * 8];
    bf16x8 b1 = *(const bf16x8*)&Xt_s[(wcol + 16 + l15) * 40 + quad * 8];
    acc[0] = __builtin_amdgcn_mfma_f32_16x16x32_bf16(af, b0, acc[0], 0, 0, 0);
    acc[1] = __builtin_amdgcn_mfma_f32_16x16x32_bf16(af, b1, acc[1], 0, 0, 0);
    __syncthreads();  // MFMA reads done before next W phase
  }

  // ---- epilogue: bias + ELU, direct stores (row=d0+quad*4+r, col=wcol+ft*16+l15) ----
#pragma unroll
  for (int ft = 0; ft < 2; ft++) {
    int col = wcol + ft * 16 + l15;
    float bv = ldf(b2, (size_t)net * 128 + col);
#pragma unroll
    for (int r = 0; r < 4; r++) {
      int row = d0 + quad * 4 + r;
      out2all[((size_t)z * NN + row) * 128 + col] =
          __float2bfloat16(eluf(acc[ft][r] + bv));
    }
  }
}

// ---------------- global max pool (bf16 in/out), z = plane ----------------
__global__ __launch_bounds__(256) void pool_max_kernel(const bf16* __restrict__ out2all,
                                                       bf16* __restrict__ gall) {
  int z = blockIdx.z;
  const bf16* h = out2all + (size_t)z * NN * 128;
  bf16* g = gall + (size_t)z * BB * 128;
  int wave = threadIdx.x >> 6, lane = threadIdx.x & 63;
  int b = blockIdx.x * 4 + wave;
  if (b >= BB) return;
  int n0 = (b * NN + BB - 1) / BB;
  int n1 = ((b + 1) * NN + BB - 1) / BB;
  if (n1 > NN) n1 = NN;
  float mx = -1e30f, my = -1e30f;
  for (int n = n0; n < n1; n++) {
    __hip_bfloat162 v = ((const __hip_bfloat162*)(h + (size_t)n * 128))[lane];
    mx = fmaxf(mx, __bfloat162float(v.x));
    my = fmaxf(my, __bfloat162float(v.y));
  }
  __hip_bfloat162 o;
  o.x = __float2bfloat16(mx);
  o.y = __float2bfloat16(my);
  ((__hip_bfloat162*)(g + (size_t)b * 128))[lane] = o;
}

// ---------------- l2 normalize rows (f32 in) -> padded bf16 ----------------
__global__ __launch_bounds__(256) void l2norm_b_kernel(const float* __restrict__ x,
                                                       bf16* __restrict__ y, int Din, int Kp) {
  int r = blockIdx.x, t = threadIdx.x;
  __shared__ float red[256];
  float s = 0.f;
  for (int i = t; i < Din; i += 256) {
    float v = x[(size_t)r * Din + i];
    s += v * v;
  }
  red[t] = s;
  __syncthreads();
  for (int o = 128; o > 0; o >>= 1) { if (t < o) red[t] += red[t + o]; __syncthreads(); }
  float inv = 1.f / fmaxf(sqrtf(red[0]), 1e-12f);
  for (int i = t; i < Kp; i += 256) {
    float v = (i < Din) ? x[(size_t)r * Din + i] : 0.f;
    y[(size_t)r * Kp + i] = __float2bfloat16(v * inv);
  }
}

// ---------------- final 512x2 output (f32 out) ----------------
__global__ void final_out_kernel(const float* __restrict__ f3, const void* __restrict__ Wo,
                                 const void* __restrict__ bo, float* __restrict__ out) {
  int r = blockIdx.x;
  int lane = threadIdx.x;
  float x0 = f3[(size_t)r * 128 + lane], x1v = f3[(size_t)r * 128 + 64 + lane];
  float s0 = x0 * ldf(Wo, lane) + x1v * ldf(Wo, 64 + lane);
  float s1 = x0 * ldf(Wo, 128 + lane) + x1v * ldf(Wo, 192 + lane);
#pragma unroll
  for (int o = 32; o > 0; o >>= 1) { s0 += __shfl_down(s0, o); s1 += __shfl_down(s1, o); }
  if (lane == 0) {
    out[r * 2] = s0 + ldf(bo, 0);
    out[r * 2 + 1] = s1 + ldf(bo, 1);
  }
}

// ---------------- host ----------------

extern "C" void kernel_launch(void* const* d_in, const int* in_sizes, int n_in,
                              void* d_out, int out_size, void* d_ws, size_t ws_size,
                              hipStream_t stream) {
  const void* x1 = d_in[0];
  const int* ei1 = (const int*)d_in[1];
  const void* x2 = d_in[3];
  const int* ei2 = (const int*)d_in[4];
  const void* cell = d_in[6];
  const void* W1 = d_in[7];
  const void* a1s = d_in[8];
  const void* a1d = d_in[9];
  const void* b1 = d_in[10];
  const void* W2 = d_in[11];
  const void* a2s = d_in[12];
  const void* a2d = d_in[13];
  const void* b2 = d_in[14];
  const void* Wg = d_in[15];
  const void* bg = d_in[16];
  const void* Wr1 = d_in[17]; const void* br1 = d_in[18];
  const void* Wr2 = d_in[19]; const void* br2 = d_in[20];
  const void* Wr3 = d_in[21]; const void* br3 = d_in[22];
  const void* Wf1 = d_in[23]; const void* bf1 = d_in[24];
  const void* Wf2 = d_in[25]; const void* bf2 = d_in[26];
  const void* Wf3 = d_in[27]; const void* bf3 = d_in[28];
  const void* Wo = d_in[29]; const void* bo = d_in[30];

  char* base = (char*)d_ws;
  size_t off = 0;
  auto alloc = [&](size_t bytes) -> void* {
    void* p = base + off;
    off = (off + bytes + 255) & ~(size_t)255;
    return p;
  };
  bf16* d_xpad = (bf16*)alloc((size_t)10 * MP * 64 * 2);
  bf16* d_W1b = (bf16*)alloc((size_t)5 * 1280 * 64 * 2);
  bf16* d_W2b = (bf16*)alloc((size_t)5 * 128 * 1280 * 2);
  bf16* d_Wgb = (bf16*)alloc((size_t)5 * 128 * 128 * 2);
  bf16* d_Wr1b = (bf16*)alloc((size_t)2048 * 960 * 2);
  bf16* d_Wr2b = (bf16*)alloc((size_t)512 * 2048 * 2);
  bf16* d_Wr3b = (bf16*)alloc((size_t)256 * 512 * 2);
  bf16* d_Wf1b = (bf16*)alloc((size_t)2048 * 512 * 2);
  bf16* d_Wf2b = (bf16*)alloc((size_t)512 * 2048 * 2);
  bf16* d_Wf3b = (bf16*)alloc((size_t)128 * 512 * 2);
  int* d_offs = (int*)alloc((size_t)10 * (NN + 1) * 4);
  int* d_srcs = (int*)alloc((size_t)10 * NE * 4);
  int* d_cnt = (int*)alloc((size_t)10 * NN * 4);
  bf16* d_walrb = (bf16*)alloc((size_t)5 * 64 * 64 * 2);
  float* d_alr = (float*)alloc((size_t)10 * MP * 32 * 4);
  float* d_al2 = (float*)alloc((size_t)20 * NN * 4);  // al2 [10][NN] then ar2 [10][NN]
  float* d_ar2 = d_al2 + (size_t)10 * NN;
  bf16* d_h2all = (bf16*)alloc((size_t)10 * MP * 128 * 2);
  // alpha rows for up to 10 planes: [(NE+NN) rows][24B]
  unsigned int* d_alphaG = (unsigned int*)alloc((size_t)10 * (NE + NN) * 24);
  // uni region: xagg2 (G planes) overlaid with tail buffers.
  char* uni = base + off;
  size_t avail = (ws_size > off) ? (ws_size - off) : 0;
  size_t need10 = (size_t)10 * 10 * MP * 64 * 2;  // 129,433,600
  int G = (avail >= need10 + 65536) ? 10 : 5;
  bf16* d_xagg2 = (bf16*)uni;                // G x 10 x MP x 64 x 2
  bf16* d_out2all = (bf16*)uni;              // 10 x NN x 128 x 2 = 25,600,000 B
  bf16* d_gall = (bf16*)(uni + 25600000);    // 1,310,720 B
  float* d_xc = (float*)(uni + 26910720);    // 1,048,576 B
  bf16* d_xcb = (bf16*)(uni + 27959296);     // 524,288 B
  bf16* d_cnb = (bf16*)(uni + 28483584);     // 983,040 B
  bf16* d_m1b = (bf16*)(uni + 29466624);     // 2,097,152 B
  bf16* d_m2b = (bf16*)(uni + 31563776);     // 524,288 B
  float* d_f3 = (float*)(uni + 32088064);    // 262,144 B

  ConvTable tab;
  tab.d[0] = {x1, d_xpad, NN, FXD, MP, 64, 2, 0, 5, (MP + 3) / 4};
  tab.d[1] = {x2, d_xpad, NN, FXD, MP, 64, 2, 1, 5, (MP + 3) / 4};
  tab.d[2] = {W1, d_W1b, 1280, FXD, 1280, 64, 1, 0, 5, 320};
  tab.d[3] = {W2, d_W2b, 128, 1280, 128, 1280, 1, 0, 5, 32};
  tab.d[4] = {Wg, d_Wgb, 128, 128, 128, 128, 1, 0, 5, 32};
  tab.d[5] = {Wr1, d_Wr1b, 2048, FXT, 2048, 960, 1, 0, 1, 512};
  tab.d[6] = {Wr2, d_Wr2b, 512, 2048, 512, 2048, 1, 0, 1, 128};
  tab.d[7] = {Wr3, d_Wr3b, 256, 512, 256, 512, 1, 0, 1, 64};
  tab.d[8] = {Wf1, d_Wf1b, 2048, 512, 2048, 512, 1, 0, 1, 512};
  tab.d[9] = {Wf2, d_Wf2b, 512, 2048, 512, 2048, 1, 0, 1, 128};
  tab.d[10] = {Wf3, d_Wf3b, 128, 512, 128, 512, 1, 0, 1, 32};
  {
    int cum = 0;
    tab.blk0[0] = 0;
    for (int i = 0; i < 11; i++) {
      cum += tab.d[i].rowBlocks * tab.d[i].batch;
      tab.blk0[i + 1] = cum;
    }
    convert_all_kernel<<<dim3(cum), 256, 0, stream>>>(tab);
  }

  // CSR for all 10 planes
  hipMemsetAsync(d_cnt, 0, (size_t)10 * NN * 4, stream);
  hist_kernel<<<dim3((NE + 255) / 256, 1, 10), 256, 0, stream>>>(ei1, ei2, d_cnt);
  scan_kernel<<<10, 256, 0, stream>>>(d_cnt, d_offs);
  hipMemsetAsync(d_cnt, 0, (size_t)10 * NN * 4, stream);
  scatter_kernel<<<dim3((NE + 255) / 256, 1, 10), 256, 0, stream>>>(ei1, ei2, d_offs, d_cnt, d_srcs);

  // layer-1 attention logits: alr = xpad @ walrb^T (cols 0-9 al, 16-25 ar; others unused)
  walr_kernel<<<50, 256, 0, stream>>>(W1, a1s, a1d, d_walrb);
  mfma_gemm64<<<dim3(1, MP / 64, 10), 256, 0, stream>>>(
      d_xpad, (long)MP * 64, d_walrb, 4096, 1, nullptr, 0, 0,
      d_alr, (long)MP * 32, 32, 0, 32, 0, nullptr, 0, 0, 64, 0, 1.f);

  for (int pb = 0; pb < 10; pb += G) {
    alpha_kernel<<<dim3(NN / 4, 1, G), 256, 0, stream>>>(d_alr, d_offs, d_srcs, d_alphaG, pb);
    xagg_kernel<<<dim3(MP / 16, 1, G), 256, 0, stream>>>(d_xpad, d_alphaG, d_offs, d_srcs, d_xagg2, pb);
    fused_l1l2_kernel<<<dim3(1, MP / 64, G), 256, 0, stream>>>(
        d_xagg2, d_W1b, b1, d_W2b, a2s, a2d, d_al2, d_ar2, d_h2all, pb);
  }

  // batched tail over all 10 planes
  hipMemsetAsync(d_xc, 0, (size_t)BB * 512 * 4, stream);
  gat_agg2_kernel<<<dim3(NN / 16, 1, 10), 256, 0, stream>>>(
      d_h2all, d_al2, d_ar2, d_offs, d_srcs, b2, d_out2all);
  pool_max_kernel<<<dim3(BB / 4, 1, 10), 256, 0, stream>>>(d_out2all, d_gall);
  // xc[:, (z&1)*128 : +128] += relu(g_z @ Wg_{z>>1}^T + bg_{z>>1}) * 0.2, one dispatch
  mfma_gemm64<<<dim3(2, BB / 64, 10), 256, 0, stream>>>(
      d_gall, (long)BB * 128, d_Wgb, 128 * 128, 1,
      bg, 0, 128,
      d_xc, 0, 512, 2, 128, 128, nullptr, 0, 0, 128, 1, 0.2f);

  // cell reduction MLP -> xc[:,256:512]
  l2norm_b_kernel<<<BB, 256, 0, stream>>>((const float*)cell, d_cnb, FXT, 960);
  mfma_gemm64<<<dim3(32, 8, 1), 256, 0, stream>>>(
      d_cnb, 0, d_Wr1b, 0, 0, br1, 0, 0, nullptr, 0, 0, 0, 1 << 30, 0, d_m1b, 0, 2048, 960, 1, 1.f);
  mfma_gemm64<<<dim3(8, 8, 1), 256, 0, stream>>>(
      d_m1b, 0, d_Wr2b, 0, 0, br2, 0, 0, nullptr, 0, 0, 0, 1 << 30, 0, d_m2b, 0, 512, 2048, 1, 1.f);
  mfma_gemm64<<<dim3(4, 8, 1), 256, 0, stream>>>(
      d_m2b, 0, d_Wr3b, 0, 0, br3, 0, 0, d_xc + 256, 0, 512, 0, 1 << 30, 0, nullptr, 0, 0, 512, 1, 1.f);

  // head MLP
  l2norm_b_kernel<<<BB, 256, 0, stream>>>(d_xc, d_xcb, 512, 512);
  mfma_gemm64<<<dim3(32, 8, 1), 256, 0, stream>>>(
      d_xcb, 0, d_Wf1b, 0, 0, bf1, 0, 0, nullptr, 0, 0, 0, 1 << 30, 0, d_m1b, 0, 2048, 512, 1, 1.f);
  mfma_gemm64<<<dim3(8, 8, 1), 256, 0, stream>>>(
      d_m1b, 0, d_Wf2b, 0, 0, bf2, 0, 0, nullptr, 0, 0, 0, 1 << 30, 0, d_m2b, 0, 512, 2048, 1, 1.f);
  mfma_gemm64<<<dim3(2, 8, 1), 256, 0, stream>>>(
      d_m2b, 0, d_Wf3b, 0, 0, bf3, 0, 0, d_f3, 0, 128, 0, 1 << 30, 0, nullptr, 0, 0, 512, 1, 1.f);
  final_out_kernel<<<BB, 64, 0, stream>>>(d_f3, Wo, bo, (float*)d_out);
}

// Round 10
// 921.708 us; speedup vs baseline: 1.0803x; 1.0212x over previous
//
#include <hip/hip_runtime.h>
#include <hip/hip_bf16.h>
#include <math.h>

#define NUM_NET 5
#define NN 10000
#define NE 160000
#define BB 512
#define FXD 62
#define FXT 954
#define MP 10112  // NN padded to multiple of 128

typedef __bf16 bf16x8 __attribute__((ext_vector_type(8)));
typedef float f32x4 __attribute__((ext_vector_type(4)));
typedef __hip_bfloat16 bf16;

// ---------------- helpers (inputs/outputs are f32 — R7-verified) ----------------
__device__ __forceinline__ float ldf(const void* p, size_t i) {
  return ((const float*)p)[i];
}
__device__ __forceinline__ float lky(float v) { return v > 0.f ? v : 0.2f * v; }
__device__ __forceinline__ float eluf(float v) { return v > 0.f ? v : (__expf(v) - 1.f); }
__device__ __forceinline__ unsigned int packbf(float a, float b) {
  __hip_bfloat162 t;
  t.x = __float2bfloat16(a);
  t.y = __float2bfloat16(b);
  return *(unsigned int*)&t;  // a in low 16, b in high 16
}

// ---------------- mega convert: flattened exact grid (no no-op blocks) ----------------
struct ConvDesc {
  const void* src;
  bf16* dst;
  int M, K, Mp, Kp, mult, add, batch, rowBlocks;
};
struct ConvTable { ConvDesc d[11]; int blk0[12]; };

__global__ void convert_all_kernel(ConvTable tab) {
  int bid = blockIdx.x;
  int di = 0;
#pragma unroll
  for (int d = 1; d < 11; d++) di += (bid >= tab.blk0[d]);
  ConvDesc c = tab.d[di];
  int local = bid - tab.blk0[di];
  int b = local / c.rowBlocks;
  int rb = local - b * c.rowBlocks;
  int wave = threadIdx.x >> 6, lane = threadIdx.x & 63;
  int r = rb * 4 + wave;
  if (r >= c.Mp) return;
  const float* srow = (const float*)c.src + ((size_t)b * c.M + r) * c.K;
  bf16* drow = c.dst + (((size_t)(b * c.mult + c.add)) * c.Mp + r) * c.Kp;
  bool rowok = r < c.M;
  for (int k = lane; k < c.Kp; k += 64) {
    float v = (rowok && k < c.K) ? srow[k] : 0.f;
    drow[k] = __float2bfloat16(v);
  }
}

// ---------------- CSR build (planes = net*2+br) ----------------
__global__ void hist_kernel(const int* __restrict__ ei1, const int* __restrict__ ei2,
                            int* __restrict__ counts) {
  int z = blockIdx.z;
  int br = z & 1, net = z >> 1;
  const int* base = (br ? ei2 : ei1) + (size_t)net * 2 * NE;
  const int* dst = base + NE;
  int* cnt = counts + (size_t)z * NN;
  int i = blockIdx.x * 256 + threadIdx.x;
  if (i < NE) atomicAdd(&cnt[dst[i]], 1);
}

// 4-wide scan: 1024 counts per round
__global__ void scan_kernel(const int* __restrict__ counts, int* __restrict__ offs) {
  int z = blockIdx.x;
  counts += (size_t)z * NN;
  offs += (size_t)z * (NN + 1);
  __shared__ int sdata[256];
  __shared__ int s_carry;
  int t = threadIdx.x;
  if (t == 0) { s_carry = 0; offs[0] = 0; }
  __syncthreads();
  for (int base = 0; base < NN; base += 1024) {
    int loc = base + t * 4;
    int v[4];
#pragma unroll
    for (int j = 0; j < 4; j++) v[j] = (loc + j < NN) ? counts[loc + j] : 0;
    int sum4 = v[0] + v[1] + v[2] + v[3];
    sdata[t] = sum4;
    __syncthreads();
    for (int o = 1; o < 256; o <<= 1) {
      int x = (t >= o) ? sdata[t - o] : 0;
      __syncthreads();
      sdata[t] += x;
      __syncthreads();
    }
    int running = sdata[t] - sum4 + s_carry;  // exclusive prefix + carry
#pragma unroll
    for (int j = 0; j < 4; j++) {
      running += v[j];
      if (loc + j < NN) offs[loc + j + 1] = running;
    }
    int tot = sdata[255];
    __syncthreads();
    if (t == 0) s_carry += tot;
    __syncthreads();
  }
}

__global__ void scatter_kernel(const int* __restrict__ ei1, const int* __restrict__ ei2,
                               const int* __restrict__ offs, int* __restrict__ fill,
                               int* __restrict__ csrc) {
  int z = blockIdx.z;
  int br = z & 1, net = z >> 1;
  const int* base = (br ? ei2 : ei1) + (size_t)net * 2 * NE;
  const int* src = base;
  const int* dst = base + NE;
  const int* offz = offs + (size_t)z * (NN + 1);
  int* fillz = fill + (size_t)z * NN;
  int* out = csrc + (size_t)z * NE;
  int i = blockIdx.x * 256 + threadIdx.x;
  if (i < NE) {
    int d = dst[i];
    int p = offz[d] + atomicAdd(&fillz[d], 1);
    out[p] = src[i];
  }
}

// ---------------- w_al/w_ar precompute -> bf16 [net][64][64] rows 0-9 al, 16-25 ar ----------
__global__ __launch_bounds__(256) void walr_kernel(const void* __restrict__ W1,
                                                   const void* __restrict__ a1s,
                                                   const void* __restrict__ a1d,
                                                   bf16* __restrict__ walrb) {
  int net = blockIdx.x / 10, head = blockIdx.x % 10;
  int t = threadIdx.x, w = t >> 6, k = t & 63;
  __shared__ float ps[8][64];
  float accs = 0.f, accd = 0.f;
  for (int c = w; c < 128; c += 4) {
    float wv = (k < FXD)
        ? ldf(W1, (size_t)net * 1280 * FXD + (size_t)(head * 128 + c) * FXD + k) : 0.f;
    float vs = ldf(a1s, (size_t)net * 1280 + head * 128 + c);
    float vd = ldf(a1d, (size_t)net * 1280 + head * 128 + c);
    accs = fmaf(wv, vs, accs);
    accd = fmaf(wv, vd, accd);
  }
  ps[w][k] = accs;
  ps[4 + w][k] = accd;
  __syncthreads();
  if (w == 0) {
    float s = ps[0][k] + ps[1][k] + ps[2][k] + ps[3][k];
    float dd = ps[4][k] + ps[5][k] + ps[6][k] + ps[7][k];
    walrb[(size_t)net * 4096 + head * 64 + k] = __float2bfloat16(s);
    walrb[(size_t)net * 4096 + (16 + head) * 64 + k] = __float2bfloat16(dd);
  }
}

// ---------------- alpha precompute: wave per dst, per-head softmax -> bf16 alphas ----------
// Row layout (24B): [5 x u32 packed bf16 alpha pairs][u32 dl], dl = d & 15.
// Real edges at CSR position e -> row e; self-loop of dst d -> row NE + d.
__global__ __launch_bounds__(256) void alpha_kernel(
    const float* __restrict__ alrA, const int* __restrict__ offsA,
    const int* __restrict__ srcsA, unsigned int* __restrict__ alphaG, int planeBase) {
  int z = blockIdx.z;
  int plane = planeBase + z;
  const float* alr = alrA + (size_t)plane * MP * 32;
  const int* offs = offsA + (size_t)plane * (NN + 1);
  const int* srcs = srcsA + (size_t)plane * NE;
  unsigned int* ag = alphaG + (size_t)z * (NE + NN) * 6;
  int wave = threadIdx.x >> 6, lane = threadIdx.x & 63;
  int d = blockIdx.x * 4 + wave;
  if (d >= NN) return;
  int e0 = offs[d], ne = offs[d + 1] - e0;
  int total = ne + 1;  // + self loop
  float arh[10];
#pragma unroll
  for (int h = 0; h < 10; h++) arh[h] = alr[(size_t)d * 32 + 16 + h];
  if (total <= 64) {
    int sc = (lane < ne) ? srcs[e0 + lane] : d;
    bool act = lane < total;
    const float* ap = &alr[(size_t)sc * 32];
    float v[10], m[10];
#pragma unroll
    for (int h = 0; h < 10; h++) {
      v[h] = act ? lky(ap[h] + arh[h]) : -1e30f;
      m[h] = v[h];
    }
#pragma unroll
    for (int o = 32; o > 0; o >>= 1)
#pragma unroll
      for (int h = 0; h < 10; h++) m[h] = fmaxf(m[h], __shfl_xor(m[h], o));
    float p[10], s[10];
#pragma unroll
    for (int h = 0; h < 10; h++) {
      p[h] = act ? __expf(v[h] - m[h]) : 0.f;
      s[h] = p[h];
    }
#pragma unroll
    for (int o = 32; o > 0; o >>= 1)
#pragma unroll
      for (int h = 0; h < 10; h++) s[h] += __shfl_xor(s[h], o);
    if (act) {
      float inv[10];
#pragma unroll
      for (int h = 0; h < 10; h++) inv[h] = 1.f / s[h];
      unsigned int wv[6];
#pragma unroll
      for (int hp = 0; hp < 5; hp++)
        wv[hp] = packbf(p[2 * hp] * inv[2 * hp], p[2 * hp + 1] * inv[2 * hp + 1]);
      wv[5] = (unsigned int)(d & 15);
      size_t row = (lane < ne) ? (size_t)(e0 + lane) : (size_t)(NE + d);
      unsigned int* rp = ag + row * 6;
#pragma unroll
      for (int j = 0; j < 6; j++) rp[j] = wv[j];
    }
  } else {
    // rare fallback: degree+1 > 64, two-pass strided
    float m[10], s[10];
#pragma unroll
    for (int h = 0; h < 10; h++) { m[h] = -1e30f; s[h] = 0.f; }
    for (int idx = lane; idx < total; idx += 64) {
      int sc = (idx < ne) ? srcs[e0 + idx] : d;
      const float* ap = &alr[(size_t)sc * 32];
#pragma unroll
      for (int h = 0; h < 10; h++) {
        float v = lky(ap[h] + arh[h]);
        if (v > m[h]) { s[h] = s[h] * __expf(m[h] - v) + 1.f; m[h] = v; }
        else s[h] += __expf(v - m[h]);
      }
    }
#pragma unroll
    for (int o = 32; o > 0; o >>= 1)
#pragma unroll
      for (int h = 0; h < 10; h++) {
        float mo = __shfl_xor(m[h], o), so = __shfl_xor(s[h], o);
        if (so > 0.f) {
          if (mo > m[h]) { s[h] = s[h] * __expf(m[h] - mo) + so; m[h] = mo; }
          else s[h] += so * __expf(mo - m[h]);
        }
      }
    for (int idx = lane; idx < total; idx += 64) {
      int sc = (idx < ne) ? srcs[e0 + idx] : d;
      const float* ap = &alr[(size_t)sc * 32];
      unsigned int wv[6];
#pragma unroll
      for (int hp = 0; hp < 5; hp++) {
        float v0 = lky(ap[2 * hp] + arh[2 * hp]);
        float v1 = lky(ap[2 * hp + 1] + arh[2 * hp + 1]);
        wv[hp] = packbf(__expf(v0 - m[2 * hp]) / s[2 * hp],
                        __expf(v1 - m[2 * hp + 1]) / s[2 * hp + 1]);
      }
      wv[5] = (unsigned int)(d & 15);
      size_t row = (idx < ne) ? (size_t)(e0 + idx) : (size_t)(NE + d);
      unsigned int* rp = ag + row * 6;
#pragma unroll
      for (int j = 0; j < 6; j++) rp[j] = wv[j];
    }
  }
}

// ---------------- xagg: MFMA alpha @ X, prefetched 2-barrier pipeline ----------------
struct Pref {
  uint4 xv;
  unsigned int a0, a1, a2, a3, a4;
  int dl;
  int av;
};

__device__ __forceinline__ void issue_pref(
    Pref& P, int kb, int e, int fblk, int tid, int nreal, int K_len, int e_begin,
    int d0, const int* __restrict__ srcs, const bf16* __restrict__ xp,
    const unsigned int* __restrict__ ag) {
  int ke = kb + e;
  int src;
  if (ke < nreal) {
    src = srcs[e_begin + ke];
  } else {
    int sl = ke - nreal;
    src = d0 + (sl < 16 ? sl : 0);
  }
  P.xv = *(const uint4*)&xp[(size_t)src * 64 + fblk * 8];
  P.av = 0;
  if (tid < 32 && ke < K_len) {
    P.av = 1;
    size_t row = (ke < nreal) ? (size_t)(e_begin + ke) : (size_t)(NE + d0 + (ke - nreal));
    const unsigned int* rp = ag + row * 6;
    P.a0 = rp[0]; P.a1 = rp[1]; P.a2 = rp[2]; P.a3 = rp[3]; P.a4 = rp[4];
    P.dl = (int)rp[5];
  }
}

__global__ __launch_bounds__(256) void xagg_kernel(
    const bf16* __restrict__ xpadA, const unsigned int* __restrict__ alphaG,
    const int* __restrict__ offsA, const int* __restrict__ srcsA,
    bf16* __restrict__ xagg2, int planeBase) {
  int z = blockIdx.z;
  int plane = planeBase + z;
  bf16* xagg = xagg2 + (size_t)z * 10 * MP * 64;
  int d0 = blockIdx.x * 16;
  int tid = threadIdx.x;

  if (d0 >= NN) {  // padding rows: zero-fill output tile (rows NN..MP-1)
    uint4 zz; zz.x = zz.y = zz.z = zz.w = 0u;
#pragma unroll
    for (int k = 0; k < 5; k++) {
      int i = tid + k * 256;  // 10*16*8 = 1280 uint4
      int h = i >> 7, rem = i & 127, row = rem >> 3, seg = rem & 7;
      *(uint4*)&xagg[((size_t)h * MP + d0 + row) * 64 + seg * 8] = zz;
    }
    return;
  }

  const bf16* xp = xpadA + (size_t)plane * MP * 64;
  const int* offs = offsA + (size_t)plane * (NN + 1);
  const int* srcs = srcsA + (size_t)plane * NE;
  const unsigned int* ag = alphaG + (size_t)z * (NE + NN) * 6;

  __shared__ __align__(16) short A_s[10 * 16 * 40];  // 12800 B
  __shared__ __align__(16) short Xt_s[64 * 40];      // 5120 B

  int e_begin = offs[d0];
  int nreal = offs[d0 + 16] - e_begin;
  int K_len = nreal + 16;

  int e = tid & 31, fblk = tid >> 5;
  int lane = tid & 63, wave = tid >> 6;
  int l15 = lane & 15, quad = lane >> 4;
  int hbase = (wave >> 1) * 5;   // waves 0,1 -> heads 0-4; waves 2,3 -> heads 5-9
  int wcol = (wave & 1) * 32;    // 32 feat cols per wave

  Pref Pn;
  issue_pref(Pn, 0, e, fblk, tid, nreal, K_len, e_begin, d0, srcs, xp, ag);

  // prologue: zero A fully
  {
    f32x4 z4 = (f32x4){0.f, 0.f, 0.f, 0.f};
    for (int i = tid; i < 800; i += 256) ((f32x4*)A_s)[i] = z4;
  }
  f32x4 acc[5][2];
#pragma unroll
  for (int i = 0; i < 5; i++)
#pragma unroll
    for (int j = 0; j < 2; j++) acc[i][j] = (f32x4){0.f, 0.f, 0.f, 0.f};
  int prev_dl = -1;
  __syncthreads();  // A zeroed

  for (int kb = 0; kb < K_len; kb += 32) {
    Pref Pc = Pn;
    // ---- W phase: A clear+scatter (tid<32), Xt stage (all) ----
    if (tid < 32) {
      if (prev_dl >= 0) {
#pragma unroll
        for (int h = 0; h < 10; h++) A_s[(h * 16 + prev_dl) * 40 + e] = 0;
      }
      prev_dl = -1;
      if (Pc.av) {
        int dlc = Pc.dl;
        A_s[(0 * 16 + dlc) * 40 + e] = (short)(Pc.a0 & 0xffff);
        A_s[(1 * 16 + dlc) * 40 + e] = (short)(Pc.a0 >> 16);
        A_s[(2 * 16 + dlc) * 40 + e] = (short)(Pc.a1 & 0xffff);
        A_s[(3 * 16 + dlc) * 40 + e] = (short)(Pc.a1 >> 16);
        A_s[(4 * 16 + dlc) * 40 + e] = (short)(Pc.a2 & 0xffff);
        A_s[(5 * 16 + dlc) * 40 + e] = (short)(Pc.a2 >> 16);
        A_s[(6 * 16 + dlc) * 40 + e] = (short)(Pc.a3 & 0xffff);
        A_s[(7 * 16 + dlc) * 40 + e] = (short)(Pc.a3 >> 16);
        A_s[(8 * 16 + dlc) * 40 + e] = (short)(Pc.a4 & 0xffff);
        A_s[(9 * 16 + dlc) * 40 + e] = (short)(Pc.a4 >> 16);
        prev_dl = dlc;
      }
    }
    {
      int fb8 = fblk * 8;
#pragma unroll
      for (int j = 0; j < 4; j++) {
        unsigned int w = ((const unsigned int*)&Pc.xv)[j];
        Xt_s[(fb8 + 2 * j) * 40 + e] = (short)(w & 0xffff);
        Xt_s[(fb8 + 2 * j + 1) * 40 + e] = (short)(w >> 16);
      }
    }
    // prefetch next chunk (flies over the MFMA phase)
    if (kb + 32 < K_len)
      issue_pref(Pn, kb + 32, e, fblk, tid, nreal, K_len, e_begin, d0, srcs, xp, ag);
    __syncthreads();  // A + Xt ready
    // ---- MFMA phase ----
    bf16x8 b0 = *(const bf16x8*)&Xt_s[(wcol + l15) * 40 + quad * 8];
    bf16x8 b1 = *(const bf16x8*)&Xt_s[(wcol + 16 + l15) * 40 + quad * 8];
#pragma unroll
    for (int hh = 0; hh < 5; hh++) {
      bf16x8 af = *(const bf16x8*)&A_s[((hbase + hh) * 16 + l15) * 40 + quad * 8];
      acc[hh][0] = __builtin_amdgcn_mfma_f32_16x16x32_bf16(af, b0, acc[hh][0], 0, 0, 0);
      acc[hh][1] = __builtin_amdgcn_mfma_f32_16x16x32_bf16(af, b1, acc[hh][1], 0, 0, 0);
    }
    __syncthreads();  // MFMA reads done before next W phase
  }

  // ---- epilogue: direct global stores (D map: row=quad*4+r, col=l15) ----
#pragma unroll
  for (int hh = 0; hh < 5; hh++) {
    int h = hbase + hh;
#pragma unroll
    for (int ft = 0; ft < 2; ft++) {
#pragma unroll
      for (int r = 0; r < 4; r++) {
        int drow = d0 + quad * 4 + r;
        xagg[((size_t)h * MP + drow) * 64 + wcol + ft * 16 + l15] =
            __float2bfloat16(acc[hh][ft][r]);
      }
    }
  }
}

// ---------------- fused L1+L2 GEMM + dots, 512 threads (8 waves), 64-row tile --------
// Same LDS overlay, staging bytes, and 4 barriers/h as the verified R6 kernel —
// only the wave decomposition changes: stage1 wave = 16 P-cols (acc1[4]); stage2
// wave = 16 rows x 64 cols (acc2[4]). 8 waves x 3 blocks = up to 24 waves/CU
// (R6 had 26% occ with 4-wave blocks; LDS-shrink (R7) showed LDS isn't the limiter).
__global__ __launch_bounds__(512) void fused_l1l2_kernel(
    const bf16* __restrict__ xagg2, const bf16* __restrict__ W1b,
    const void* __restrict__ b1raw, const bf16* __restrict__ W2b,
    const void* __restrict__ a2s, const void* __restrict__ a2d,
    float* __restrict__ al2A, float* __restrict__ ar2A,
    bf16* __restrict__ h2all, int planeBase) {
  int zz = blockIdx.z;
  int plane = planeBase + zz;
  int net = plane >> 1;
  long ow1 = (long)net * 1280 * 64;
  long ob1 = (long)net * 1280;
  long ow2 = (long)net * 128 * 1280;
  long oa2 = (long)net * 128;
  const bf16* xagg = xagg2 + (size_t)zz * 10 * MP * 64;
  float* al2p = al2A + (size_t)plane * NN;
  float* ar2p = ar2A + (size_t)plane * NN;
  bf16* h2 = h2all + (size_t)plane * MP * 128;
  int r0 = blockIdx.y * 64;
  __shared__ __align__(16) char uraw[52224];
  bf16* Ah = (bf16*)uraw;             // 64 x 72
  bf16* W1s = Ah + 64 * 72;           // 128 x 72
  bf16* Ps = (bf16*)uraw;             // 64 x 136 (overlays Ah/W1s)
  bf16* W2s = Ps + 64 * 136;          // 128 x 136
  __shared__ float s_dot[4][2][16][2];  // [rowQuad][colHalf][rowLocal][al/ar]
  int tid = threadIdx.x, lane = tid & 63, wave = tid >> 6;
  int l15 = lane & 15, quad = lane >> 4;
  int rowQuad = wave >> 1, colHalf = wave & 1;
  int wr = rowQuad * 16, wc = colHalf * 64;
  f32x4 acc2[4];
#pragma unroll
  for (int j = 0; j < 4; j++) acc2[j] = (f32x4){0.f, 0.f, 0.f, 0.f};

  for (int h = 0; h < 10; h++) {
    __syncthreads();  // prior stage2 done with Ps/W2s
    {  // Ah: 512 uint4, one per thread
      int i = tid;
      *(uint4*)&Ah[(i >> 3) * 72 + (i & 7) * 8] =
          *(const uint4*)&xagg[((size_t)h * MP + r0 + (i >> 3)) * 64 + (i & 7) * 8];
    }
#pragma unroll
    for (int j = 0; j < 2; j++) {  // W1s: 1024 uint4
      int i = tid + j * 512;
      *(uint4*)&W1s[(i >> 3) * 72 + (i & 7) * 8] =
          *(const uint4*)&W1b[ow1 + (size_t)(h * 128 + (i >> 3)) * 64 + (i & 7) * 8];
    }
    __syncthreads();
    // stage 1: P = xagg_h @ W1_h^T (each wave -> 16 of 128 P-cols, all 64 rows)
    f32x4 acc1[4];
#pragma unroll
    for (int i = 0; i < 4; i++) acc1[i] = (f32x4){0.f, 0.f, 0.f, 0.f};
#pragma unroll
    for (int kc = 0; kc < 2; kc++) {
      bf16x8 af[4], bfr;
#pragma unroll
      for (int mi = 0; mi < 4; mi++)
        af[mi] = *(const bf16x8*)&Ah[(mi * 16 + l15) * 72 + kc * 32 + quad * 8];
      bfr = *(const bf16x8*)&W1s[(wave * 16 + l15) * 72 + kc * 32 + quad * 8];
#pragma unroll
      for (int mi = 0; mi < 4; mi++)
        acc1[mi] = __builtin_amdgcn_mfma_f32_16x16x32_bf16(af[mi], bfr, acc1[mi], 0, 0, 0);
    }
    __syncthreads();  // all waves done reading Ah/W1s before Ps overwrite
    // write P (bias + ELU): wave's 16 cols x 64 rows; stage W2s (all 128 rows)
    {
      int pcol = wave * 16 + l15;
      float bv = ldf(b1raw, ob1 + h * 128 + pcol);
#pragma unroll
      for (int mi = 0; mi < 4; mi++)
#pragma unroll
        for (int r = 0; r < 4; r++)
          Ps[(mi * 16 + quad * 4 + r) * 136 + pcol] =
              __float2bfloat16(eluf(acc1[mi][r] + bv));
    }
#pragma unroll
    for (int j = 0; j < 4; j++) {  // W2s: 2048 uint4
      int i = tid + j * 512;
      *(uint4*)&W2s[(i >> 4) * 136 + (i & 15) * 8] =
          *(const uint4*)&W2b[ow2 + (size_t)(i >> 4) * 1280 + h * 128 + (i & 15) * 8];
    }
    __syncthreads();
    // stage 2: acc2 += P @ W2_h^T  (wave: 16 rows x 64 cols)
#pragma unroll
    for (int kc = 0; kc < 4; kc++) {
      bf16x8 pa, pb[4];
      pa = *(const bf16x8*)&Ps[(wr + l15) * 136 + kc * 32 + quad * 8];
#pragma unroll
      for (int ni = 0; ni < 4; ni++)
        pb[ni] = *(const bf16x8*)&W2s[(wc + ni * 16 + l15) * 136 + kc * 32 + quad * 8];
#pragma unroll
      for (int ni = 0; ni < 4; ni++)
        acc2[ni] = __builtin_amdgcn_mfma_f32_16x16x32_bf16(pa, pb[ni], acc2[ni], 0, 0, 0);
    }
  }
  // epilogue: h2 write + attention dots (combined across col-halves in LDS)
  float asv[4], adv[4];
#pragma unroll
  for (int ni = 0; ni < 4; ni++) {
    int col = wc + ni * 16 + l15;
    asv[ni] = ldf(a2s, oa2 + col);
    adv[ni] = ldf(a2d, oa2 + col);
  }
#pragma unroll
  for (int r = 0; r < 4; r++) {
    int rl = quad * 4 + r;  // row-local within this wave's 16
    int row = r0 + wr + rl;
    float psum = 0.f, pdum = 0.f;
#pragma unroll
    for (int ni = 0; ni < 4; ni++) {
      float v = acc2[ni][r];
      h2[(size_t)row * 128 + wc + ni * 16 + l15] = __float2bfloat16(v);
      psum = fmaf(v, asv[ni], psum);
      pdum = fmaf(v, adv[ni], pdum);
    }
#pragma unroll
    for (int o = 1; o < 16; o <<= 1) {
      psum += __shfl_xor(psum, o);
      pdum += __shfl_xor(pdum, o);
    }
    if (l15 == 0) {
      s_dot[rowQuad][colHalf][rl][0] = psum;
      s_dot[rowQuad][colHalf][rl][1] = pdum;
    }
  }
  __syncthreads();
  if (tid < 64) {
    int row = r0 + tid;
    if (row < NN) {
      int rq = tid >> 4, rl = tid & 15;
      al2p[row] = s_dot[rq][0][rl][0] + s_dot[rq][1][rl][0];
      ar2p[row] = s_dot[rq][0][rl][1] + s_dot[rq][1][rl][1];
    }
  }
}

// ---------------- MFMA GEMM 64x64 tile (bias is raw f32 input) ----------------
__global__ __launch_bounds__(256) void mfma_gemm64(
    const bf16* __restrict__ A, long Az, const bf16* __restrict__ B, long Bz, int bdiv,
    const void* __restrict__ bias, long biasoff, long biaszs,
    float* __restrict__ Cf, long Cfz, int ldcf, int accum, int ncols, int brcol,
    bf16* __restrict__ Cb, long Cbz, int ldcb,
    int K, int act, float scale) {
  int z = blockIdx.z;
  int zb = bdiv ? (z >> 1) : z;
  A += (size_t)z * Az;
  B += (size_t)zb * Bz;
  if (Cf) Cf += (size_t)z * Cfz + (size_t)(z & 1) * brcol;
  if (Cb) Cb += (size_t)z * Cbz;
  const bf16* Ag = A + (size_t)blockIdx.y * 64 * K;
  const bf16* Bg = B + (size_t)blockIdx.x * 64 * K;
  __shared__ __align__(16) bf16 Asm[64 * 40];
  __shared__ __align__(16) bf16 Bsm[64 * 40];
  int tid = threadIdx.x;
  int lane = tid & 63, wave = tid >> 6;
  int wr = (wave >> 1) * 32, wc = (wave & 1) * 32;
  int l15 = lane & 15, quad = lane >> 4;
  f32x4 acc[2][2];
#pragma unroll
  for (int i = 0; i < 2; i++)
#pragma unroll
    for (int j = 0; j < 2; j++) acc[i][j] = (f32x4){0.f, 0.f, 0.f, 0.f};
  int isB = tid >> 7;
  int srow = (tid & 127) >> 1, shalf = tid & 1;
  const bf16* G = isB ? Bg : Ag;
  bf16* S = isB ? Bsm : Asm;
  for (int k0 = 0; k0 < K; k0 += 32) {
    const uint4* g = (const uint4*)(G + (size_t)srow * K + k0 + shalf * 16);
    uint4 v0 = g[0], v1 = g[1];
    __syncthreads();
    *(uint4*)&S[srow * 40 + shalf * 16] = v0;
    *(uint4*)&S[srow * 40 + shalf * 16 + 8] = v1;
    __syncthreads();
    bf16x8 af[2], bfr[2];
#pragma unroll
    for (int mi = 0; mi < 2; mi++)
      af[mi] = *(const bf16x8*)&Asm[(wr + mi * 16 + l15) * 40 + quad * 8];
#pragma unroll
    for (int ni = 0; ni < 2; ni++)
      bfr[ni] = *(const bf16x8*)&Bsm[(wc + ni * 16 + l15) * 40 + quad * 8];
#pragma unroll
    for (int mi = 0; mi < 2; mi++)
#pragma unroll
      for (int ni = 0; ni < 2; ni++)
        acc[mi][ni] = __builtin_amdgcn_mfma_f32_16x16x32_bf16(af[mi], bfr[ni], acc[mi][ni], 0, 0, 0);
  }
#pragma unroll
  for (int ni = 0; ni < 2; ni++) {
    int col = blockIdx.x * 64 + wc + ni * 16 + l15;
    if (col >= ncols) continue;
    float bv = bias ? ldf(bias, biasoff + (size_t)zb * biaszs + col) : 0.f;
#pragma unroll
    for (int mi = 0; mi < 2; mi++) {
      int rbase = blockIdx.y * 64 + wr + mi * 16 + quad * 4;
      f32x4 c = acc[mi][ni];
#pragma unroll
      for (int r = 0; r < 4; r++) {
        float v = c[r] + bv;
        if (act == 1) v = fmaxf(v, 0.f);
        else if (act == 2) v = eluf(v);
        v *= scale;
        if (Cf) {
          size_t ci = (size_t)(rbase + r) * ldcf + col;
          if (accum == 1) Cf[ci] += v;
          else if (accum == 2) atomicAdd(&Cf[ci], v);
          else Cf[ci] = v;
        }
        if (Cb) Cb[(size_t)(rbase + r) * ldcb + col] = __float2bfloat16(v);
      }
    }
  }
}

// ---------------- GAT layer-2 aggregation: MFMA alpha @ h2 (xagg skeleton, 1 head) -------
struct Pref2 {
  uint4 xv0, xv1;
  float alv;
  int dl;
  int av;
};

__device__ __forceinline__ void issue_pref2(
    Pref2& P, int kb, int e, int fblk, int tid, int nreal, int K_len, int e_begin,
    int d0, const int* __restrict__ srcs, const bf16* __restrict__ h,
    const float* __restrict__ al, const int* s_offs) {
  int ke = kb + e;
  int src, dl;
  if (ke < nreal) {
    int eg = e_begin + ke;
    src = srcs[eg];
    dl = 0;
#pragma unroll
    for (int jj = 1; jj < 16; jj++) dl += (eg >= s_offs[jj]);
  } else {
    int sl = ke - nreal;
    dl = sl;
    src = d0 + (sl < 16 ? sl : 0);
  }
  P.xv0 = *(const uint4*)&h[(size_t)src * 128 + fblk * 16];
  P.xv1 = *(const uint4*)&h[(size_t)src * 128 + fblk * 16 + 8];
  P.av = 0;
  if (tid < 32 && ke < K_len) {
    P.av = 1;
    P.alv = al[src];
    P.dl = dl;
  }
}

__global__ __launch_bounds__(256) void gat_agg2_kernel(
    const bf16* __restrict__ h2all, const float* __restrict__ alA, const float* __restrict__ arA,
    const int* __restrict__ offsA, const int* __restrict__ srcsA,
    const void* __restrict__ b2, bf16* __restrict__ out2all) {
  int z = blockIdx.z;
  int net = z >> 1;
  const bf16* h = h2all + (size_t)z * MP * 128;
  const float* al = alA + (size_t)z * NN;
  const float* ar = arA + (size_t)z * NN;
  const int* offs = offsA + (size_t)z * (NN + 1);
  const int* srcs = srcsA + (size_t)z * NE;
  int d0 = blockIdx.x * 16;
  int tid = threadIdx.x;

  __shared__ __align__(16) short A_s[16 * 40];     // 1280 B
  __shared__ __align__(16) short Xt_s[128 * 40];   // 10240 B
  __shared__ int s_offs[17];
  __shared__ float s_m[16], s_sinv[16], s_ar[16];

  if (tid < 17) s_offs[tid] = offs[d0 + tid];
  __syncthreads();
  int e_begin = s_offs[0];
  int nreal = s_offs[16] - e_begin;
  int K_len = nreal + 16;

  // ---- phase 1: per-dst 1-head online softmax (16 par-lanes per dst) ----
  {
    int dl = tid >> 4, par = tid & 15;
    int d = d0 + dl;
    float ard = ar[d];
    float m, s;
    if (par == 0) { m = lky(al[d] + ard); s = 1.f; }  // self-loop seed
    else { m = -1e30f; s = 0.f; }
    int ee = s_offs[dl + 1];
    for (int e2 = s_offs[dl] + par; e2 < ee; e2 += 16) {
      float v = lky(al[srcs[e2]] + ard);
      if (v > m) { s = s * __expf(m - v) + 1.f; m = v; }
      else s += __expf(v - m);
    }
#pragma unroll
    for (int o = 8; o >= 1; o >>= 1) {
      float mo = __shfl_xor(m, o), so = __shfl_xor(s, o);
      if (so > 0.f) {
        if (mo > m) { s = s * __expf(m - mo) + so; m = mo; }
        else s += so * __expf(mo - m);
      }
    }
    if (par == 0) { s_m[dl] = m; s_sinv[dl] = 1.f / s; s_ar[dl] = ard; }
  }

  int e = tid & 31, fblk = tid >> 5;  // 8 fblks x 16 feats
  int lane = tid & 63, wave = tid >> 6;
  int l15 = lane & 15, quad = lane >> 4;
  int wcol = wave * 32;

  Pref2 Pn;
  issue_pref2(Pn, 0, e, fblk, tid, nreal, K_len, e_begin, d0, srcs, h, al, s_offs);

  if (tid < 80) {  // zero A_s (1280 B = 80 uint4)
    uint4 zz; zz.x = zz.y = zz.z = zz.w = 0u;
    ((uint4*)A_s)[tid] = zz;
  }
  f32x4 acc[2];
  acc[0] = (f32x4){0.f, 0.f, 0.f, 0.f};
  acc[1] = (f32x4){0.f, 0.f, 0.f, 0.f};
  int prev_dl = -1;
  __syncthreads();  // phase-1 results + A zero visible

  for (int kb = 0; kb < K_len; kb += 32) {
    Pref2 Pc = Pn;
    // ---- W phase: alpha scatter (tid<32) + Xt stage (all) ----
    if (tid < 32) {
      if (prev_dl >= 0) A_s[prev_dl * 40 + e] = 0;
      prev_dl = -1;
      if (Pc.av) {
        float v = lky(Pc.alv + s_ar[Pc.dl]);
        float a = __expf(v - s_m[Pc.dl]) * s_sinv[Pc.dl];
        A_s[Pc.dl * 40 + e] = (short)(packbf(a, 0.f) & 0xffff);
        prev_dl = Pc.dl;
      }
    }
    {
      int fb = fblk * 16;
#pragma unroll
      for (int j = 0; j < 4; j++) {
        unsigned int w0 = ((const unsigned int*)&Pc.xv0)[j];
        Xt_s[(fb + 2 * j) * 40 + e] = (short)(w0 & 0xffff);
        Xt_s[(fb + 2 * j + 1) * 40 + e] = (short)(w0 >> 16);
        unsigned int w1 = ((const unsigned int*)&Pc.xv1)[j];
        Xt_s[(fb + 8 + 2 * j) * 40 + e] = (short)(w1 & 0xffff);
        Xt_s[(fb + 8 + 2 * j + 1) * 40 + e] = (short)(w1 >> 16);
      }
    }
    if (kb + 32 < K_len)
      issue_pref2(Pn, kb + 32, e, fblk, tid, nreal, K_len, e_begin, d0, srcs, h, al, s_offs);
    __syncthreads();  // A + Xt ready
    // ---- MFMA phase ----
    bf16x8 af = *(const bf16x8*)&A_s[l15 * 40 + quad * 8];
    bf16x8 b0 = *(const bf16x8*)&Xt_s[(wcol + l15) * 40 + quad * 8];
    bf16x8 b1 = *(const bf16x8*)&Xt_s[(wcol + 16 + l15) * 40 + quad * 8];
    acc[0] = __builtin_amdgcn_mfma_f32_16x16x32_bf16(af, b0, acc[0], 0, 0, 0);
    acc[1] = __builtin_amdgcn_mfma_f32_16x16x32_bf16(af, b1, acc[1], 0, 0, 0);
    __syncthreads();  // MFMA reads done before next W phase
  }

  // ---- epilogue: bias + ELU, direct stores (row=d0+quad*4+r, col=wcol+ft*16+l15) ----
#pragma unroll
  for (int ft = 0; ft < 2; ft++) {
    int col = wcol + ft * 16 + l15;
    float bv = ldf(b2, (size_t)net * 128 + col);
#pragma unroll
    for (int r = 0; r < 4; r++) {
      int row = d0 + quad * 4 + r;
      out2all[((size_t)z * NN + row) * 128 + col] =
          __float2bfloat16(eluf(acc[ft][r] + bv));
    }
  }
}

// ---------------- global max pool (bf16 in/out), z = plane ----------------
__global__ __launch_bounds__(256) void pool_max_kernel(const bf16* __restrict__ out2all,
                                                       bf16* __restrict__ gall) {
  int z = blockIdx.z;
  const bf16* h = out2all + (size_t)z * NN * 128;
  bf16* g = gall + (size_t)z * BB * 128;
  int wave = threadIdx.x >> 6, lane = threadIdx.x & 63;
  int b = blockIdx.x * 4 + wave;
  if (b >= BB) return;
  int n0 = (b * NN + BB - 1) / BB;
  int n1 = ((b + 1) * NN + BB - 1) / BB;
  if (n1 > NN) n1 = NN;
  float mx = -1e30f, my = -1e30f;
  for (int n = n0; n < n1; n++) {
    __hip_bfloat162 v = ((const __hip_bfloat162*)(h + (size_t)n * 128))[lane];
    mx = fmaxf(mx, __bfloat162float(v.x));
    my = fmaxf(my, __bfloat162float(v.y));
  }
  __hip_bfloat162 o;
  o.x = __float2bfloat16(mx);
  o.y = __float2bfloat16(my);
  ((__hip_bfloat162*)(g + (size_t)b * 128))[lane] = o;
}

// ---------------- l2 normalize rows (f32 in) -> padded bf16 ----------------
__global__ __launch_bounds__(256) void l2norm_b_kernel(const float* __restrict__ x,
                                                       bf16* __restrict__ y, int Din, int Kp) {
  int r = blockIdx.x, t = threadIdx.x;
  __shared__ float red[256];
  float s = 0.f;
  for (int i = t; i < Din; i += 256) {
    float v = x[(size_t)r * Din + i];
    s += v * v;
  }
  red[t] = s;
  __syncthreads();
  for (int o = 128; o > 0; o >>= 1) { if (t < o) red[t] += red[t + o]; __syncthreads(); }
  float inv = 1.f / fmaxf(sqrtf(red[0]), 1e-12f);
  for (int i = t; i < Kp; i += 256) {
    float v = (i < Din) ? x[(size_t)r * Din + i] : 0.f;
    y[(size_t)r * Kp + i] = __float2bfloat16(v * inv);
  }
}

// ---------------- final 512x2 output (f32 out) ----------------
__global__ void final_out_kernel(const float* __restrict__ f3, const void* __restrict__ Wo,
                                 const void* __restrict__ bo, float* __restrict__ out) {
  int r = blockIdx.x;
  int lane = threadIdx.x;
  float x0 = f3[(size_t)r * 128 + lane], x1v = f3[(size_t)r * 128 + 64 + lane];
  float s0 = x0 * ldf(Wo, lane) + x1v * ldf(Wo, 64 + lane);
  float s1 = x0 * ldf(Wo, 128 + lane) + x1v * ldf(Wo, 192 + lane);
#pragma unroll
  for (int o = 32; o > 0; o >>= 1) { s0 += __shfl_down(s0, o); s1 += __shfl_down(s1, o); }
  if (lane == 0) {
    out[r * 2] = s0 + ldf(bo, 0);
    out[r * 2 + 1] = s1 + ldf(bo, 1);
  }
}

// ---------------- host ----------------

extern "C" void kernel_launch(void* const* d_in, const int* in_sizes, int n_in,
                              void* d_out, int out_size, void* d_ws, size_t ws_size,
                              hipStream_t stream) {
  const void* x1 = d_in[0];
  const int* ei1 = (const int*)d_in[1];
  const void* x2 = d_in[3];
  const int* ei2 = (const int*)d_in[4];
  const void* cell = d_in[6];
  const void* W1 = d_in[7];
  const void* a1s = d_in[8];
  const void* a1d = d_in[9];
  const void* b1 = d_in[10];
  const void* W2 = d_in[11];
  const void* a2s = d_in[12];
  const void* a2d = d_in[13];
  const void* b2 = d_in[14];
  const void* Wg = d_in[15];
  const void* bg = d_in[16];
  const void* Wr1 = d_in[17]; const void* br1 = d_in[18];
  const void* Wr2 = d_in[19]; const void* br2 = d_in[20];
  const void* Wr3 = d_in[21]; const void* br3 = d_in[22];
  const void* Wf1 = d_in[23]; const void* bf1 = d_in[24];
  const void* Wf2 = d_in[25]; const void* bf2 = d_in[26];
  const void* Wf3 = d_in[27]; const void* bf3 = d_in[28];
  const void* Wo = d_in[29]; const void* bo = d_in[30];

  char* base = (char*)d_ws;
  size_t off = 0;
  auto alloc = [&](size_t bytes) -> void* {
    void* p = base + off;
    off = (off + bytes + 255) & ~(size_t)255;
    return p;
  };
  bf16* d_xpad = (bf16*)alloc((size_t)10 * MP * 64 * 2);
  bf16* d_W1b = (bf16*)alloc((size_t)5 * 1280 * 64 * 2);
  bf16* d_W2b = (bf16*)alloc((size_t)5 * 128 * 1280 * 2);
  bf16* d_Wgb = (bf16*)alloc((size_t)5 * 128 * 128 * 2);
  bf16* d_Wr1b = (bf16*)alloc((size_t)2048 * 960 * 2);
  bf16* d_Wr2b = (bf16*)alloc((size_t)512 * 2048 * 2);
  bf16* d_Wr3b = (bf16*)alloc((size_t)256 * 512 * 2);
  bf16* d_Wf1b = (bf16*)alloc((size_t)2048 * 512 * 2);
  bf16* d_Wf2b = (bf16*)alloc((size_t)512 * 2048 * 2);
  bf16* d_Wf3b = (bf16*)alloc((size_t)128 * 512 * 2);
  int* d_offs = (int*)alloc((size_t)10 * (NN + 1) * 4);
  int* d_srcs = (int*)alloc((size_t)10 * NE * 4);
  int* d_cnt = (int*)alloc((size_t)10 * NN * 4);
  bf16* d_walrb = (bf16*)alloc((size_t)5 * 64 * 64 * 2);
  float* d_alr = (float*)alloc((size_t)10 * MP * 32 * 4);
  float* d_al2 = (float*)alloc((size_t)20 * NN * 4);  // al2 [10][NN] then ar2 [10][NN]
  float* d_ar2 = d_al2 + (size_t)10 * NN;
  bf16* d_h2all = (bf16*)alloc((size_t)10 * MP * 128 * 2);
  // alpha rows for up to 10 planes: [(NE+NN) rows][24B]
  unsigned int* d_alphaG = (unsigned int*)alloc((size_t)10 * (NE + NN) * 24);
  // uni region: xagg2 (G planes) overlaid with tail buffers.
  char* uni = base + off;
  size_t avail = (ws_size > off) ? (ws_size - off) : 0;
  size_t need10 = (size_t)10 * 10 * MP * 64 * 2;  // 129,433,600
  int G = (avail >= need10 + 65536) ? 10 : 5;
  bf16* d_xagg2 = (bf16*)uni;                // G x 10 x MP x 64 x 2
  bf16* d_out2all = (bf16*)uni;              // 10 x NN x 128 x 2 = 25,600,000 B
  bf16* d_gall = (bf16*)(uni + 25600000);    // 1,310,720 B
  float* d_xc = (float*)(uni + 26910720);    // 1,048,576 B
  bf16* d_xcb = (bf16*)(uni + 27959296);     // 524,288 B
  bf16* d_cnb = (bf16*)(uni + 28483584);     // 983,040 B
  bf16* d_m1b = (bf16*)(uni + 29466624);     // 2,097,152 B
  bf16* d_m2b = (bf16*)(uni + 31563776);     // 524,288 B
  float* d_f3 = (float*)(uni + 32088064);    // 262,144 B

  ConvTable tab;
  tab.d[0] = {x1, d_xpad, NN, FXD, MP, 64, 2, 0, 5, (MP + 3) / 4};
  tab.d[1] = {x2, d_xpad, NN, FXD, MP, 64, 2, 1, 5, (MP + 3) / 4};
  tab.d[2] = {W1, d_W1b, 1280, FXD, 1280, 64, 1, 0, 5, 320};
  tab.d[3] = {W2, d_W2b, 128, 1280, 128, 1280, 1, 0, 5, 32};
  tab.d[4] = {Wg, d_Wgb, 128, 128, 128, 128, 1, 0, 5, 32};
  tab.d[5] = {Wr1, d_Wr1b, 2048, FXT, 2048, 960, 1, 0, 1, 512};
  tab.d[6] = {Wr2, d_Wr2b, 512, 2048, 512, 2048, 1, 0, 1, 128};
  tab.d[7] = {Wr3, d_Wr3b, 256, 512, 256, 512, 1, 0, 1, 64};
  tab.d[8] = {Wf1, d_Wf1b, 2048, 512, 2048, 512, 1, 0, 1, 512};
  tab.d[9] = {Wf2, d_Wf2b, 512, 2048, 512, 2048, 1, 0, 1, 128};
  tab.d[10] = {Wf3, d_Wf3b, 128, 512, 128, 512, 1, 0, 1, 32};
  {
    int cum = 0;
    tab.blk0[0] = 0;
    for (int i = 0; i < 11; i++) {
      cum += tab.d[i].rowBlocks * tab.d[i].batch;
      tab.blk0[i + 1] = cum;
    }
    convert_all_kernel<<<dim3(cum), 256, 0, stream>>>(tab);
  }

  // CSR for all 10 planes
  hipMemsetAsync(d_cnt, 0, (size_t)10 * NN * 4, stream);
  hist_kernel<<<dim3((NE + 255) / 256, 1, 10), 256, 0, stream>>>(ei1, ei2, d_cnt);
  scan_kernel<<<10, 256, 0, stream>>>(d_cnt, d_offs);
  hipMemsetAsync(d_cnt, 0, (size_t)10 * NN * 4, stream);
  scatter_kernel<<<dim3((NE + 255) / 256, 1, 10), 256, 0, stream>>>(ei1, ei2, d_offs, d_cnt, d_srcs);

  // layer-1 attention logits: alr = xpad @ walrb^T (cols 0-9 al, 16-25 ar; others unused)
  walr_kernel<<<50, 256, 0, stream>>>(W1, a1s, a1d, d_walrb);
  mfma_gemm64<<<dim3(1, MP / 64, 10), 256, 0, stream>>>(
      d_xpad, (long)MP * 64, d_walrb, 4096, 1, nullptr, 0, 0,
      d_alr, (long)MP * 32, 32, 0, 32, 0, nullptr, 0, 0, 64, 0, 1.f);

  for (int pb = 0; pb < 10; pb += G) {
    alpha_kernel<<<dim3(NN / 4, 1, G), 256, 0, stream>>>(d_alr, d_offs, d_srcs, d_alphaG, pb);
    xagg_kernel<<<dim3(MP / 16, 1, G), 256, 0, stream>>>(d_xpad, d_alphaG, d_offs, d_srcs, d_xagg2, pb);
    fused_l1l2_kernel<<<dim3(1, MP / 64, G), 512, 0, stream>>>(
        d_xagg2, d_W1b, b1, d_W2b, a2s, a2d, d_al2, d_ar2, d_h2all, pb);
  }

  // batched tail over all 10 planes
  hipMemsetAsync(d_xc, 0, (size_t)BB * 512 * 4, stream);
  gat_agg2_kernel<<<dim3(NN / 16, 1, 10), 256, 0, stream>>>(
      d_h2all, d_al2, d_ar2, d_offs, d_srcs, b2, d_out2all);
  pool_max_kernel<<<dim3(BB / 4, 1, 10), 256, 0, stream>>>(d_out2all, d_gall);
  // xc[:, (z&1)*128 : +128] += relu(g_z @ Wg_{z>>1}^T + bg_{z>>1}) * 0.2, one dispatch
  mfma_gemm64<<<dim3(2, BB / 64, 10), 256, 0, stream>>>(
      d_gall, (long)BB * 128, d_Wgb, 128 * 128, 1,
      bg, 0, 128,
      d_xc, 0, 512, 2, 128, 128, nullptr, 0, 0, 128, 1, 0.2f);

  // cell reduction MLP -> xc[:,256:512]
  l2norm_b_kernel<<<BB, 256, 0, stream>>>((const float*)cell, d_cnb, FXT, 960);
  mfma_gemm64<<<dim3(32, 8, 1), 256, 0, stream>>>(
      d_cnb, 0, d_Wr1b, 0, 0, br1, 0, 0, nullptr, 0, 0, 0, 1 << 30, 0, d_m1b, 0, 2048, 960, 1, 1.f);
  mfma_gemm64<<<dim3(8, 8, 1), 256, 0, stream>>>(
      d_m1b, 0, d_Wr2b, 0, 0, br2, 0, 0, nullptr, 0, 0, 0, 1 << 30, 0, d_m2b, 0, 512, 2048, 1, 1.f);
  mfma_gemm64<<<dim3(4, 8, 1), 256, 0, stream>>>(
      d_m2b, 0, d_Wr3b, 0, 0, br3, 0, 0, d_xc + 256, 0, 512, 0, 1 << 30, 0, nullptr, 0, 0, 512, 1, 1.f);

  // head MLP
  l2norm_b_kernel<<<BB, 256, 0, stream>>>(d_xc, d_xcb, 512, 512);
  mfma_gemm64<<<dim3(32, 8, 1), 256, 0, stream>>>(
      d_xcb, 0, d_Wf1b, 0, 0, bf1, 0, 0, nullptr, 0, 0, 0, 1 << 30, 0, d_m1b, 0, 2048, 512, 1, 1.f);
  mfma_gemm64<<<dim3(8, 8, 1), 256, 0, stream>>>(
      d_m1b, 0, d_Wf2b, 0, 0, bf2, 0, 0, nullptr, 0, 0, 0, 1 << 30, 0, d_m2b, 0, 512, 2048, 1, 1.f);
  mfma_gemm64<<<dim3(2, 8, 1), 256, 0, stream>>>(
      d_m2b, 0, d_Wf3b, 0, 0, bf3, 0, 0, d_f3, 0, 128, 0, 1 << 30, 0, nullptr, 0, 0, 512, 1, 1.f);
  final_out_kernel<<<BB, 64, 0, stream>>>(d_f3, Wo, bo, (float*)d_out);
}

// Round 11
// 895.321 us; speedup vs baseline: 1.1122x; 1.0295x over previous
//
#include <hip/hip_runtime.h>
#include <hip/hip_bf16.h>
#include <math.h>

#define NUM_NET 5
#define NN 10000
#define NE 160000
#define BB 512
#define FXD 62
#define FXT 954
#define MP 10112  // NN padded to multiple of 128

typedef __bf16 bf16x8 __attribute__((ext_vector_type(8)));
typedef float f32x4 __attribute__((ext_vector_type(4)));
typedef __hip_bfloat16 bf16;

// ---------------- helpers (inputs/outputs are f32 — R7-verified) ----------------
__device__ __forceinline__ float ldf(const void* p, size_t i) {
  return ((const float*)p)[i];
}
__device__ __forceinline__ float lky(float v) { return v > 0.f ? v : 0.2f * v; }
__device__ __forceinline__ float eluf(float v) { return v > 0.f ? v : (__expf(v) - 1.f); }
__device__ __forceinline__ unsigned int packbf(float a, float b) {
  __hip_bfloat162 t;
  t.x = __float2bfloat16(a);
  t.y = __float2bfloat16(b);
  return *(unsigned int*)&t;  // a in low 16, b in high 16
}

// ---------------- mega convert: flattened exact grid (no no-op blocks) ----------------
struct ConvDesc {
  const void* src;
  bf16* dst;
  int M, K, Mp, Kp, mult, add, batch, rowBlocks;
};
struct ConvTable { ConvDesc d[11]; int blk0[12]; };

__global__ void convert_all_kernel(ConvTable tab) {
  int bid = blockIdx.x;
  int di = 0;
#pragma unroll
  for (int d = 1; d < 11; d++) di += (bid >= tab.blk0[d]);
  ConvDesc c = tab.d[di];
  int local = bid - tab.blk0[di];
  int b = local / c.rowBlocks;
  int rb = local - b * c.rowBlocks;
  int wave = threadIdx.x >> 6, lane = threadIdx.x & 63;
  int r = rb * 4 + wave;
  if (r >= c.Mp) return;
  const float* srow = (const float*)c.src + ((size_t)b * c.M + r) * c.K;
  bf16* drow = c.dst + (((size_t)(b * c.mult + c.add)) * c.Mp + r) * c.Kp;
  bool rowok = r < c.M;
  for (int k = lane; k < c.Kp; k += 64) {
    float v = (rowok && k < c.K) ? srow[k] : 0.f;
    drow[k] = __float2bfloat16(v);
  }
}

// ---------------- CSR build (planes = net*2+br) ----------------
__global__ void hist_kernel(const int* __restrict__ ei1, const int* __restrict__ ei2,
                            int* __restrict__ counts) {
  int z = blockIdx.z;
  int br = z & 1, net = z >> 1;
  const int* base = (br ? ei2 : ei1) + (size_t)net * 2 * NE;
  const int* dst = base + NE;
  int* cnt = counts + (size_t)z * NN;
  int i = blockIdx.x * 256 + threadIdx.x;
  if (i < NE) atomicAdd(&cnt[dst[i]], 1);
}

// 4-wide scan: 1024 counts per round
__global__ void scan_kernel(const int* __restrict__ counts, int* __restrict__ offs) {
  int z = blockIdx.x;
  counts += (size_t)z * NN;
  offs += (size_t)z * (NN + 1);
  __shared__ int sdata[256];
  __shared__ int s_carry;
  int t = threadIdx.x;
  if (t == 0) { s_carry = 0; offs[0] = 0; }
  __syncthreads();
  for (int base = 0; base < NN; base += 1024) {
    int loc = base + t * 4;
    int v[4];
#pragma unroll
    for (int j = 0; j < 4; j++) v[j] = (loc + j < NN) ? counts[loc + j] : 0;
    int sum4 = v[0] + v[1] + v[2] + v[3];
    sdata[t] = sum4;
    __syncthreads();
    for (int o = 1; o < 256; o <<= 1) {
      int x = (t >= o) ? sdata[t - o] : 0;
      __syncthreads();
      sdata[t] += x;
      __syncthreads();
    }
    int running = sdata[t] - sum4 + s_carry;  // exclusive prefix + carry
#pragma unroll
    for (int j = 0; j < 4; j++) {
      running += v[j];
      if (loc + j < NN) offs[loc + j + 1] = running;
    }
    int tot = sdata[255];
    __syncthreads();
    if (t == 0) s_carry += tot;
    __syncthreads();
  }
}

__global__ void scatter_kernel(const int* __restrict__ ei1, const int* __restrict__ ei2,
                               const int* __restrict__ offs, int* __restrict__ fill,
                               int* __restrict__ csrc) {
  int z = blockIdx.z;
  int br = z & 1, net = z >> 1;
  const int* base = (br ? ei2 : ei1) + (size_t)net * 2 * NE;
  const int* src = base;
  const int* dst = base + NE;
  const int* offz = offs + (size_t)z * (NN + 1);
  int* fillz = fill + (size_t)z * NN;
  int* out = csrc + (size_t)z * NE;
  int i = blockIdx.x * 256 + threadIdx.x;
  if (i < NE) {
    int d = dst[i];
    int p = offz[d] + atomicAdd(&fillz[d], 1);
    out[p] = src[i];
  }
}

// ---------------- w_al/w_ar precompute -> bf16 [net][64][64] rows 0-9 al, 16-25 ar ----------
__global__ __launch_bounds__(256) void walr_kernel(const void* __restrict__ W1,
                                                   const void* __restrict__ a1s,
                                                   const void* __restrict__ a1d,
                                                   bf16* __restrict__ walrb) {
  int net = blockIdx.x / 10, head = blockIdx.x % 10;
  int t = threadIdx.x, w = t >> 6, k = t & 63;
  __shared__ float ps[8][64];
  float accs = 0.f, accd = 0.f;
  for (int c = w; c < 128; c += 4) {
    float wv = (k < FXD)
        ? ldf(W1, (size_t)net * 1280 * FXD + (size_t)(head * 128 + c) * FXD + k) : 0.f;
    float vs = ldf(a1s, (size_t)net * 1280 + head * 128 + c);
    float vd = ldf(a1d, (size_t)net * 1280 + head * 128 + c);
    accs = fmaf(wv, vs, accs);
    accd = fmaf(wv, vd, accd);
  }
  ps[w][k] = accs;
  ps[4 + w][k] = accd;
  __syncthreads();
  if (w == 0) {
    float s = ps[0][k] + ps[1][k] + ps[2][k] + ps[3][k];
    float dd = ps[4][k] + ps[5][k] + ps[6][k] + ps[7][k];
    walrb[(size_t)net * 4096 + head * 64 + k] = __float2bfloat16(s);
    walrb[(size_t)net * 4096 + (16 + head) * 64 + k] = __float2bfloat16(dd);
  }
}

// ---------------- alpha precompute: 16 lanes per dst (4 dsts/wave), 2-pass strided -------
// Row layout (24B): [5 x u32 packed bf16 alpha pairs][u32 dl], dl = d & 15.
// Real edges at CSR position e -> row e; self-loop of dst d -> row NE + d.
// R10 profile: 64-lane-per-dst version was VALU-issue-bound (143us, 54% VALUBusy,
// ~17 useful lanes of 64). 16-lane groups serve 4 dsts/wave; shfl merges (o=8..1)
// stay inside the aligned 16-lane group.
__global__ __launch_bounds__(256) void alpha_kernel(
    const float* __restrict__ alrA, const int* __restrict__ offsA,
    const int* __restrict__ srcsA, unsigned int* __restrict__ alphaG, int planeBase) {
  int z = blockIdx.z;
  int plane = planeBase + z;
  const float* alr = alrA + (size_t)plane * MP * 32;
  const int* offs = offsA + (size_t)plane * (NN + 1);
  const int* srcs = srcsA + (size_t)plane * NE;
  unsigned int* ag = alphaG + (size_t)z * (NE + NN) * 6;
  int wave = threadIdx.x >> 6, lane = threadIdx.x & 63;
  int grp = lane >> 4, par = lane & 15;
  int d = blockIdx.x * 16 + wave * 4 + grp;  // NN = 625*16 -> always < NN
  int e0 = offs[d], ne = offs[d + 1] - e0;
  int total = ne + 1;  // + self loop
  float arh[10];
#pragma unroll
  for (int h = 0; h < 10; h++) arh[h] = alr[(size_t)d * 32 + 16 + h];
  // pass 1: online per-head softmax over slots strided by 16
  float m[10], s[10];
#pragma unroll
  for (int h = 0; h < 10; h++) { m[h] = -1e30f; s[h] = 0.f; }
  for (int idx = par; idx < total; idx += 16) {
    int sc = (idx < ne) ? srcs[e0 + idx] : d;
    const float* ap = &alr[(size_t)sc * 32];
#pragma unroll
    for (int h = 0; h < 10; h++) {
      float v = lky(ap[h] + arh[h]);
      if (v > m[h]) { s[h] = s[h] * __expf(m[h] - v) + 1.f; m[h] = v; }
      else s[h] += __expf(v - m[h]);
    }
  }
#pragma unroll
  for (int o = 8; o > 0; o >>= 1)
#pragma unroll
    for (int h = 0; h < 10; h++) {
      float mo = __shfl_xor(m[h], o), so = __shfl_xor(s[h], o);
      if (so > 0.f) {
        if (mo > m[h]) { s[h] = s[h] * __expf(m[h] - mo) + so; m[h] = mo; }
        else s[h] += so * __expf(mo - m[h]);
      }
    }
  float inv[10];
#pragma unroll
  for (int h = 0; h < 10; h++) inv[h] = 1.f / s[h];
  // pass 2: recompute + write packed alpha rows
  for (int idx = par; idx < total; idx += 16) {
    int sc = (idx < ne) ? srcs[e0 + idx] : d;
    const float* ap = &alr[(size_t)sc * 32];
    unsigned int wv[6];
#pragma unroll
    for (int hp = 0; hp < 5; hp++) {
      float v0 = lky(ap[2 * hp] + arh[2 * hp]);
      float v1 = lky(ap[2 * hp + 1] + arh[2 * hp + 1]);
      wv[hp] = packbf(__expf(v0 - m[2 * hp]) * inv[2 * hp],
                      __expf(v1 - m[2 * hp + 1]) * inv[2 * hp + 1]);
    }
    wv[5] = (unsigned int)(d & 15);
    size_t row = (idx < ne) ? (size_t)(e0 + idx) : (size_t)(NE + d);
    unsigned int* rp = ag + row * 6;
#pragma unroll
    for (int j = 0; j < 6; j++) rp[j] = wv[j];
  }
}

// ---------------- xagg: MFMA alpha @ X, prefetched 2-barrier pipeline ----------------
struct Pref {
  uint4 xv;
  unsigned int a0, a1, a2, a3, a4;
  int dl;
  int av;
};

__device__ __forceinline__ void issue_pref(
    Pref& P, int kb, int e, int fblk, int tid, int nreal, int K_len, int e_begin,
    int d0, const int* __restrict__ srcs, const bf16* __restrict__ xp,
    const unsigned int* __restrict__ ag) {
  int ke = kb + e;
  int src;
  if (ke < nreal) {
    src = srcs[e_begin + ke];
  } else {
    int sl = ke - nreal;
    src = d0 + (sl < 16 ? sl : 0);
  }
  P.xv = *(const uint4*)&xp[(size_t)src * 64 + fblk * 8];
  P.av = 0;
  if (tid < 32 && ke < K_len) {
    P.av = 1;
    size_t row = (ke < nreal) ? (size_t)(e_begin + ke) : (size_t)(NE + d0 + (ke - nreal));
    const unsigned int* rp = ag + row * 6;
    P.a0 = rp[0]; P.a1 = rp[1]; P.a2 = rp[2]; P.a3 = rp[3]; P.a4 = rp[4];
    P.dl = (int)rp[5];
  }
}

__global__ __launch_bounds__(256) void xagg_kernel(
    const bf16* __restrict__ xpadA, const unsigned int* __restrict__ alphaG,
    const int* __restrict__ offsA, const int* __restrict__ srcsA,
    bf16* __restrict__ xagg2, int planeBase) {
  int z = blockIdx.z;
  int plane = planeBase + z;
  bf16* xagg = xagg2 + (size_t)z * 10 * MP * 64;
  int d0 = blockIdx.x * 16;
  int tid = threadIdx.x;

  if (d0 >= NN) {  // padding rows: zero-fill output tile (rows NN..MP-1)
    uint4 zz; zz.x = zz.y = zz.z = zz.w = 0u;
#pragma unroll
    for (int k = 0; k < 5; k++) {
      int i = tid + k * 256;  // 10*16*8 = 1280 uint4
      int h = i >> 7, rem = i & 127, row = rem >> 3, seg = rem & 7;
      *(uint4*)&xagg[((size_t)h * MP + d0 + row) * 64 + seg * 8] = zz;
    }
    return;
  }

  const bf16* xp = xpadA + (size_t)plane * MP * 64;
  const int* offs = offsA + (size_t)plane * (NN + 1);
  const int* srcs = srcsA + (size_t)plane * NE;
  const unsigned int* ag = alphaG + (size_t)z * (NE + NN) * 6;

  __shared__ __align__(16) short A_s[10 * 16 * 40];  // 12800 B
  __shared__ __align__(16) short Xt_s[64 * 40];      // 5120 B

  int e_begin = offs[d0];
  int nreal = offs[d0 + 16] - e_begin;
  int K_len = nreal + 16;

  int e = tid & 31, fblk = tid >> 5;
  int lane = tid & 63, wave = tid >> 6;
  int l15 = lane & 15, quad = lane >> 4;
  int hbase = (wave >> 1) * 5;   // waves 0,1 -> heads 0-4; waves 2,3 -> heads 5-9
  int wcol = (wave & 1) * 32;    // 32 feat cols per wave

  Pref Pn;
  issue_pref(Pn, 0, e, fblk, tid, nreal, K_len, e_begin, d0, srcs, xp, ag);

  // prologue: zero A fully
  {
    f32x4 z4 = (f32x4){0.f, 0.f, 0.f, 0.f};
    for (int i = tid; i < 800; i += 256) ((f32x4*)A_s)[i] = z4;
  }
  f32x4 acc[5][2];
#pragma unroll
  for (int i = 0; i < 5; i++)
#pragma unroll
    for (int j = 0; j < 2; j++) acc[i][j] = (f32x4){0.f, 0.f, 0.f, 0.f};
  int prev_dl = -1;
  __syncthreads();  // A zeroed

  for (int kb = 0; kb < K_len; kb += 32) {
    Pref Pc = Pn;
    // ---- W phase: A clear+scatter (tid<32), Xt stage (all) ----
    if (tid < 32) {
      if (prev_dl >= 0) {
#pragma unroll
        for (int h = 0; h < 10; h++) A_s[(h * 16 + prev_dl) * 40 + e] = 0;
      }
      prev_dl = -1;
      if (Pc.av) {
        int dlc = Pc.dl;
        A_s[(0 * 16 + dlc) * 40 + e] = (short)(Pc.a0 & 0xffff);
        A_s[(1 * 16 + dlc) * 40 + e] = (short)(Pc.a0 >> 16);
        A_s[(2 * 16 + dlc) * 40 + e] = (short)(Pc.a1 & 0xffff);
        A_s[(3 * 16 + dlc) * 40 + e] = (short)(Pc.a1 >> 16);
        A_s[(4 * 16 + dlc) * 40 + e] = (short)(Pc.a2 & 0xffff);
        A_s[(5 * 16 + dlc) * 40 + e] = (short)(Pc.a2 >> 16);
        A_s[(6 * 16 + dlc) * 40 + e] = (short)(Pc.a3 & 0xffff);
        A_s[(7 * 16 + dlc) * 40 + e] = (short)(Pc.a3 >> 16);
        A_s[(8 * 16 + dlc) * 40 + e] = (short)(Pc.a4 & 0xffff);
        A_s[(9 * 16 + dlc) * 40 + e] = (short)(Pc.a4 >> 16);
        prev_dl = dlc;
      }
    }
    {
      int fb8 = fblk * 8;
#pragma unroll
      for (int j = 0; j < 4; j++) {
        unsigned int w = ((const unsigned int*)&Pc.xv)[j];
        Xt_s[(fb8 + 2 * j) * 40 + e] = (short)(w & 0xffff);
        Xt_s[(fb8 + 2 * j + 1) * 40 + e] = (short)(w >> 16);
      }
    }
    // prefetch next chunk (flies over the MFMA phase)
    if (kb + 32 < K_len)
      issue_pref(Pn, kb + 32, e, fblk, tid, nreal, K_len, e_begin, d0, srcs, xp, ag);
    __syncthreads();  // A + Xt ready
    // ---- MFMA phase ----
    bf16x8 b0 = *(const bf16x8*)&Xt_s[(wcol + l15) * 40 + quad * 8];
    bf16x8 b1 = *(const bf16x8*)&Xt_s[(wcol + 16 + l15) * 40 + quad * 8];
#pragma unroll
    for (int hh = 0; hh < 5; hh++) {
      bf16x8 af = *(const bf16x8*)&A_s[((hbase + hh) * 16 + l15) * 40 + quad * 8];
      acc[hh][0] = __builtin_amdgcn_mfma_f32_16x16x32_bf16(af, b0, acc[hh][0], 0, 0, 0);
      acc[hh][1] = __builtin_amdgcn_mfma_f32_16x16x32_bf16(af, b1, acc[hh][1], 0, 0, 0);
    }
    __syncthreads();  // MFMA reads done before next W phase
  }

  // ---- epilogue: direct global stores (D map: row=quad*4+r, col=l15) ----
#pragma unroll
  for (int hh = 0; hh < 5; hh++) {
    int h = hbase + hh;
#pragma unroll
    for (int ft = 0; ft < 2; ft++) {
#pragma unroll
      for (int r = 0; r < 4; r++) {
        int drow = d0 + quad * 4 + r;
        xagg[((size_t)h * MP + drow) * 64 + wcol + ft * 16 + l15] =
            __float2bfloat16(acc[hh][ft][r]);
      }
    }
  }
}

// ---------------- fused L1+L2 GEMM + dots, 512 threads (8 waves), 64-row tile --------
// R9-verified: same LDS overlay/staging/4 barriers per h as R6, 8-wave decomposition.
__global__ __launch_bounds__(512) void fused_l1l2_kernel(
    const bf16* __restrict__ xagg2, const bf16* __restrict__ W1b,
    const void* __restrict__ b1raw, const bf16* __restrict__ W2b,
    const void* __restrict__ a2s, const void* __restrict__ a2d,
    float* __restrict__ al2A, float* __restrict__ ar2A,
    bf16* __restrict__ h2all, int planeBase) {
  int zz = blockIdx.z;
  int plane = planeBase + zz;
  int net = plane >> 1;
  long ow1 = (long)net * 1280 * 64;
  long ob1 = (long)net * 1280;
  long ow2 = (long)net * 128 * 1280;
  long oa2 = (long)net * 128;
  const bf16* xagg = xagg2 + (size_t)zz * 10 * MP * 64;
  float* al2p = al2A + (size_t)plane * NN;
  float* ar2p = ar2A + (size_t)plane * NN;
  bf16* h2 = h2all + (size_t)plane * MP * 128;
  int r0 = blockIdx.y * 64;
  __shared__ __align__(16) char uraw[52224];
  bf16* Ah = (bf16*)uraw;             // 64 x 72
  bf16* W1s = Ah + 64 * 72;           // 128 x 72
  bf16* Ps = (bf16*)uraw;             // 64 x 136 (overlays Ah/W1s)
  bf16* W2s = Ps + 64 * 136;          // 128 x 136
  __shared__ float s_dot[4][2][16][2];  // [rowQuad][colHalf][rowLocal][al/ar]
  int tid = threadIdx.x, lane = tid & 63, wave = tid >> 6;
  int l15 = lane & 15, quad = lane >> 4;
  int rowQuad = wave >> 1, colHalf = wave & 1;
  int wr = rowQuad * 16, wc = colHalf * 64;
  f32x4 acc2[4];
#pragma unroll
  for (int j = 0; j < 4; j++) acc2[j] = (f32x4){0.f, 0.f, 0.f, 0.f};

  for (int h = 0; h < 10; h++) {
    __syncthreads();  // prior stage2 done with Ps/W2s
    {  // Ah: 512 uint4, one per thread
      int i = tid;
      *(uint4*)&Ah[(i >> 3) * 72 + (i & 7) * 8] =
          *(const uint4*)&xagg[((size_t)h * MP + r0 + (i >> 3)) * 64 + (i & 7) * 8];
    }
#pragma unroll
    for (int j = 0; j < 2; j++) {  // W1s: 1024 uint4
      int i = tid + j * 512;
      *(uint4*)&W1s[(i >> 3) * 72 + (i & 7) * 8] =
          *(const uint4*)&W1b[ow1 + (size_t)(h * 128 + (i >> 3)) * 64 + (i & 7) * 8];
    }
    __syncthreads();
    // stage 1: P = xagg_h @ W1_h^T (each wave -> 16 of 128 P-cols, all 64 rows)
    f32x4 acc1[4];
#pragma unroll
    for (int i = 0; i < 4; i++) acc1[i] = (f32x4){0.f, 0.f, 0.f, 0.f};
#pragma unroll
    for (int kc = 0; kc < 2; kc++) {
      bf16x8 af[4], bfr;
#pragma unroll
      for (int mi = 0; mi < 4; mi++)
        af[mi] = *(const bf16x8*)&Ah[(mi * 16 + l15) * 72 + kc * 32 + quad * 8];
      bfr = *(const bf16x8*)&W1s[(wave * 16 + l15) * 72 + kc * 32 + quad * 8];
#pragma unroll
      for (int mi = 0; mi < 4; mi++)
        acc1[mi] = __builtin_amdgcn_mfma_f32_16x16x32_bf16(af[mi], bfr, acc1[mi], 0, 0, 0);
    }
    __syncthreads();  // all waves done reading Ah/W1s before Ps overwrite
    // write P (bias + ELU): wave's 16 cols x 64 rows; stage W2s (all 128 rows)
    {
      int pcol = wave * 16 + l15;
      float bv = ldf(b1raw, ob1 + h * 128 + pcol);
#pragma unroll
      for (int mi = 0; mi < 4; mi++)
#pragma unroll
        for (int r = 0; r < 4; r++)
          Ps[(mi * 16 + quad * 4 + r) * 136 + pcol] =
              __float2bfloat16(eluf(acc1[mi][r] + bv));
    }
#pragma unroll
    for (int j = 0; j < 4; j++) {  // W2s: 2048 uint4
      int i = tid + j * 512;
      *(uint4*)&W2s[(i >> 4) * 136 + (i & 15) * 8] =
          *(const uint4*)&W2b[ow2 + (size_t)(i >> 4) * 1280 + h * 128 + (i & 15) * 8];
    }
    __syncthreads();
    // stage 2: acc2 += P @ W2_h^T  (wave: 16 rows x 64 cols)
#pragma unroll
    for (int kc = 0; kc < 4; kc++) {
      bf16x8 pa, pb[4];
      pa = *(const bf16x8*)&Ps[(wr + l15) * 136 + kc * 32 + quad * 8];
#pragma unroll
      for (int ni = 0; ni < 4; ni++)
        pb[ni] = *(const bf16x8*)&W2s[(wc + ni * 16 + l15) * 136 + kc * 32 + quad * 8];
#pragma unroll
      for (int ni = 0; ni < 4; ni++)
        acc2[ni] = __builtin_amdgcn_mfma_f32_16x16x32_bf16(pa, pb[ni], acc2[ni], 0, 0, 0);
    }
  }
  // epilogue: h2 write + attention dots (combined across col-halves in LDS)
  float asv[4], adv[4];
#pragma unroll
  for (int ni = 0; ni < 4; ni++) {
    int col = wc + ni * 16 + l15;
    asv[ni] = ldf(a2s, oa2 + col);
    adv[ni] = ldf(a2d, oa2 + col);
  }
#pragma unroll
  for (int r = 0; r < 4; r++) {
    int rl = quad * 4 + r;  // row-local within this wave's 16
    int row = r0 + wr + rl;
    float psum = 0.f, pdum = 0.f;
#pragma unroll
    for (int ni = 0; ni < 4; ni++) {
      float v = acc2[ni][r];
      h2[(size_t)row * 128 + wc + ni * 16 + l15] = __float2bfloat16(v);
      psum = fmaf(v, asv[ni], psum);
      pdum = fmaf(v, adv[ni], pdum);
    }
#pragma unroll
    for (int o = 1; o < 16; o <<= 1) {
      psum += __shfl_xor(psum, o);
      pdum += __shfl_xor(pdum, o);
    }
    if (l15 == 0) {
      s_dot[rowQuad][colHalf][rl][0] = psum;
      s_dot[rowQuad][colHalf][rl][1] = pdum;
    }
  }
  __syncthreads();
  if (tid < 64) {
    int row = r0 + tid;
    if (row < NN) {
      int rq = tid >> 4, rl = tid & 15;
      al2p[row] = s_dot[rq][0][rl][0] + s_dot[rq][1][rl][0];
      ar2p[row] = s_dot[rq][0][rl][1] + s_dot[rq][1][rl][1];
    }
  }
}

// ---------------- MFMA GEMM 64x64 tile (bias is raw f32 input) ----------------
__global__ __launch_bounds__(256) void mfma_gemm64(
    const bf16* __restrict__ A, long Az, const bf16* __restrict__ B, long Bz, int bdiv,
    const void* __restrict__ bias, long biasoff, long biaszs,
    float* __restrict__ Cf, long Cfz, int ldcf, int accum, int ncols, int brcol,
    bf16* __restrict__ Cb, long Cbz, int ldcb,
    int K, int act, float scale) {
  int z = blockIdx.z;
  int zb = bdiv ? (z >> 1) : z;
  A += (size_t)z * Az;
  B += (size_t)zb * Bz;
  if (Cf) Cf += (size_t)z * Cfz + (size_t)(z & 1) * brcol;
  if (Cb) Cb += (size_t)z * Cbz;
  const bf16* Ag = A + (size_t)blockIdx.y * 64 * K;
  const bf16* Bg = B + (size_t)blockIdx.x * 64 * K;
  __shared__ __align__(16) bf16 Asm[64 * 40];
  __shared__ __align__(16) bf16 Bsm[64 * 40];
  int tid = threadIdx.x;
  int lane = tid & 63, wave = tid >> 6;
  int wr = (wave >> 1) * 32, wc = (wave & 1) * 32;
  int l15 = lane & 15, quad = lane >> 4;
  f32x4 acc[2][2];
#pragma unroll
  for (int i = 0; i < 2; i++)
#pragma unroll
    for (int j = 0; j < 2; j++) acc[i][j] = (f32x4){0.f, 0.f, 0.f, 0.f};
  int isB = tid >> 7;
  int srow = (tid & 127) >> 1, shalf = tid & 1;
  const bf16* G = isB ? Bg : Ag;
  bf16* S = isB ? Bsm : Asm;
  for (int k0 = 0; k0 < K; k0 += 32) {
    const uint4* g = (const uint4*)(G + (size_t)srow * K + k0 + shalf * 16);
    uint4 v0 = g[0], v1 = g[1];
    __syncthreads();
    *(uint4*)&S[srow * 40 + shalf * 16] = v0;
    *(uint4*)&S[srow * 40 + shalf * 16 + 8] = v1;
    __syncthreads();
    bf16x8 af[2], bfr[2];
#pragma unroll
    for (int mi = 0; mi < 2; mi++)
      af[mi] = *(const bf16x8*)&Asm[(wr + mi * 16 + l15) * 40 + quad * 8];
#pragma unroll
    for (int ni = 0; ni < 2; ni++)
      bfr[ni] = *(const bf16x8*)&Bsm[(wc + ni * 16 + l15) * 40 + quad * 8];
#pragma unroll
    for (int mi = 0; mi < 2; mi++)
#pragma unroll
      for (int ni = 0; ni < 2; ni++)
        acc[mi][ni] = __builtin_amdgcn_mfma_f32_16x16x32_bf16(af[mi], bfr[ni], acc[mi][ni], 0, 0, 0);
  }
#pragma unroll
  for (int ni = 0; ni < 2; ni++) {
    int col = blockIdx.x * 64 + wc + ni * 16 + l15;
    if (col >= ncols) continue;
    float bv = bias ? ldf(bias, biasoff + (size_t)zb * biaszs + col) : 0.f;
#pragma unroll
    for (int mi = 0; mi < 2; mi++) {
      int rbase = blockIdx.y * 64 + wr + mi * 16 + quad * 4;
      f32x4 c = acc[mi][ni];
#pragma unroll
      for (int r = 0; r < 4; r++) {
        float v = c[r] + bv;
        if (act == 1) v = fmaxf(v, 0.f);
        else if (act == 2) v = eluf(v);
        v *= scale;
        if (Cf) {
          size_t ci = (size_t)(rbase + r) * ldcf + col;
          if (accum == 1) Cf[ci] += v;
          else if (accum == 2) atomicAdd(&Cf[ci], v);
          else Cf[ci] = v;
        }
        if (Cb) Cb[(size_t)(rbase + r) * ldcb + col] = __float2bfloat16(v);
      }
    }
  }
}

// ---------------- GAT layer-2 aggregation: MFMA alpha @ h2 (xagg skeleton, 1 head) -------
struct Pref2 {
  uint4 xv0, xv1;
  float alv;
  int dl;
  int av;
};

__device__ __forceinline__ void issue_pref2(
    Pref2& P, int kb, int e, int fblk, int tid, int nreal, int K_len, int e_begin,
    int d0, const int* __restrict__ srcs, const bf16* __restrict__ h,
    const float* __restrict__ al, const int* s_offs) {
  int ke = kb + e;
  int src, dl;
  if (ke < nreal) {
    int eg = e_begin + ke;
    src = srcs[eg];
    dl = 0;
#pragma unroll
    for (int jj = 1; jj < 16; jj++) dl += (eg >= s_offs[jj]);
  } else {
    int sl = ke - nreal;
    dl = sl;
    src = d0 + (sl < 16 ? sl : 0);
  }
  P.xv0 = *(const uint4*)&h[(size_t)src * 128 + fblk * 16];
  P.xv1 = *(const uint4*)&h[(size_t)src * 128 + fblk * 16 + 8];
  P.av = 0;
  if (tid < 32 && ke < K_len) {
    P.av = 1;
    P.alv = al[src];
    P.dl = dl;
  }
}

__global__ __launch_bounds__(256) void gat_agg2_kernel(
    const bf16* __restrict__ h2all, const float* __restrict__ alA, const float* __restrict__ arA,
    const int* __restrict__ offsA, const int* __restrict__ srcsA,
    const void* __restrict__ b2, bf16* __restrict__ out2all) {
  int z = blockIdx.z;
  int net = z >> 1;
  const bf16* h = h2all + (size_t)z * MP * 128;
  const float* al = alA + (size_t)z * NN;
  const float* ar = arA + (size_t)z * NN;
  const int* offs = offsA + (size_t)z * (NN + 1);
  const int* srcs = srcsA + (size_t)z * NE;
  int d0 = blockIdx.x * 16;
  int tid = threadIdx.x;

  __shared__ __align__(16) short A_s[16 * 40];     // 1280 B
  __shared__ __align__(16) short Xt_s[128 * 40];   // 10240 B
  __shared__ int s_offs[17];
  __shared__ float s_m[16], s_sinv[16], s_ar[16];

  if (tid < 17) s_offs[tid] = offs[d0 + tid];
  __syncthreads();
  int e_begin = s_offs[0];
  int nreal = s_offs[16] - e_begin;
  int K_len = nreal + 16;

  // ---- phase 1: per-dst 1-head online softmax (16 par-lanes per dst) ----
  {
    int dl = tid >> 4, par = tid & 15;
    int d = d0 + dl;
    float ard = ar[d];
    float m, s;
    if (par == 0) { m = lky(al[d] + ard); s = 1.f; }  // self-loop seed
    else { m = -1e30f; s = 0.f; }
    int ee = s_offs[dl + 1];
    for (int e2 = s_offs[dl] + par; e2 < ee; e2 += 16) {
      float v = lky(al[srcs[e2]] + ard);
      if (v > m) { s = s * __expf(m - v) + 1.f; m = v; }
      else s += __expf(v - m);
    }
#pragma unroll
    for (int o = 8; o >= 1; o >>= 1) {
      float mo = __shfl_xor(m, o), so = __shfl_xor(s, o);
      if (so > 0.f) {
        if (mo > m) { s = s * __expf(m - mo) + so; m = mo; }
        else s += so * __expf(mo - m);
      }
    }
    if (par == 0) { s_m[dl] = m; s_sinv[dl] = 1.f / s; s_ar[dl] = ard; }
  }

  int e = tid & 31, fblk = tid >> 5;  // 8 fblks x 16 feats
  int lane = tid & 63, wave = tid >> 6;
  int l15 = lane & 15, quad = lane >> 4;
  int wcol = wave * 32;

  Pref2 Pn;
  issue_pref2(Pn, 0, e, fblk, tid, nreal, K_len, e_begin, d0, srcs, h, al, s_offs);

  if (tid < 80) {  // zero A_s (1280 B = 80 uint4)
    uint4 zz; zz.x = zz.y = zz.z = zz.w = 0u;
    ((uint4*)A_s)[tid] = zz;
  }
  f32x4 acc[2];
  acc[0] = (f32x4){0.f, 0.f, 0.f, 0.f};
  acc[1] = (f32x4){0.f, 0.f, 0.f, 0.f};
  int prev_dl = -1;
  __syncthreads();  // phase-1 results + A zero visible

  for (int kb = 0; kb < K_len; kb += 32) {
    Pref2 Pc = Pn;
    // ---- W phase: alpha scatter (tid<32) + Xt stage (all) ----
    if (tid < 32) {
      if (prev_dl >= 0) A_s[prev_dl * 40 + e] = 0;
      prev_dl = -1;
      if (Pc.av) {
        float v = lky(Pc.alv + s_ar[Pc.dl]);
        float a = __expf(v - s_m[Pc.dl]) * s_sinv[Pc.dl];
        A_s[Pc.dl * 40 + e] = (short)(packbf(a, 0.f) & 0xffff);
        prev_dl = Pc.dl;
      }
    }
    {
      int fb = fblk * 16;
#pragma unroll
      for (int j = 0; j < 4; j++) {
        unsigned int w0 = ((const unsigned int*)&Pc.xv0)[j];
        Xt_s[(fb + 2 * j) * 40 + e] = (short)(w0 & 0xffff);
        Xt_s[(fb + 2 * j + 1) * 40 + e] = (short)(w0 >> 16);
        unsigned int w1 = ((const unsigned int*)&Pc.xv1)[j];
        Xt_s[(fb + 8 + 2 * j) * 40 + e] = (short)(w1 & 0xffff);
        Xt_s[(fb + 8 + 2 * j + 1) * 40 + e] = (short)(w1 >> 16);
      }
    }
    if (kb + 32 < K_len)
      issue_pref2(Pn, kb + 32, e, fblk, tid, nreal, K_len, e_begin, d0, srcs, h, al, s_offs);
    __syncthreads();  // A + Xt ready
    // ---- MFMA phase ----
    bf16x8 af = *(const bf16x8*)&A_s[l15 * 40 + quad * 8];
    bf16x8 b0 = *(const bf16x8*)&Xt_s[(wcol + l15) * 40 + quad * 8];
    bf16x8 b1 = *(const bf16x8*)&Xt_s[(wcol + 16 + l15) * 40 + quad * 8];
    acc[0] = __builtin_amdgcn_mfma_f32_16x16x32_bf16(af, b0, acc[0], 0, 0, 0);
    acc[1] = __builtin_amdgcn_mfma_f32_16x16x32_bf16(af, b1, acc[1], 0, 0, 0);
    __syncthreads();  // MFMA reads done before next W phase
  }

  // ---- epilogue: bias + ELU, direct stores (row=d0+quad*4+r, col=wcol+ft*16+l15) ----
#pragma unroll
  for (int ft = 0; ft < 2; ft++) {
    int col = wcol + ft * 16 + l15;
    float bv = ldf(b2, (size_t)net * 128 + col);
#pragma unroll
    for (int r = 0; r < 4; r++) {
      int row = d0 + quad * 4 + r;
      out2all[((size_t)z * NN + row) * 128 + col] =
          __float2bfloat16(eluf(acc[ft][r] + bv));
    }
  }
}

// ---------------- global max pool (bf16 in/out), z = plane ----------------
__global__ __launch_bounds__(256) void pool_max_kernel(const bf16* __restrict__ out2all,
                                                       bf16* __restrict__ gall) {
  int z = blockIdx.z;
  const bf16* h = out2all + (size_t)z * NN * 128;
  bf16* g = gall + (size_t)z * BB * 128;
  int wave = threadIdx.x >> 6, lane = threadIdx.x & 63;
  int b = blockIdx.x * 4 + wave;
  if (b >= BB) return;
  int n0 = (b * NN + BB - 1) / BB;
  int n1 = ((b + 1) * NN + BB - 1) / BB;
  if (n1 > NN) n1 = NN;
  float mx = -1e30f, my = -1e30f;
  for (int n = n0; n < n1; n++) {
    __hip_bfloat162 v = ((const __hip_bfloat162*)(h + (size_t)n * 128))[lane];
    mx = fmaxf(mx, __bfloat162float(v.x));
    my = fmaxf(my, __bfloat162float(v.y));
  }
  __hip_bfloat162 o;
  o.x = __float2bfloat16(mx);
  o.y = __float2bfloat16(my);
  ((__hip_bfloat162*)(g + (size_t)b * 128))[lane] = o;
}

// ---------------- l2 normalize rows (f32 in) -> padded bf16 ----------------
__global__ __launch_bounds__(256) void l2norm_b_kernel(const float* __restrict__ x,
                                                       bf16* __restrict__ y, int Din, int Kp) {
  int r = blockIdx.x, t = threadIdx.x;
  __shared__ float red[256];
  float s = 0.f;
  for (int i = t; i < Din; i += 256) {
    float v = x[(size_t)r * Din + i];
    s += v * v;
  }
  red[t] = s;
  __syncthreads();
  for (int o = 128; o > 0; o >>= 1) { if (t < o) red[t] += red[t + o]; __syncthreads(); }
  float inv = 1.f / fmaxf(sqrtf(red[0]), 1e-12f);
  for (int i = t; i < Kp; i += 256) {
    float v = (i < Din) ? x[(size_t)r * Din + i] : 0.f;
    y[(size_t)r * Kp + i] = __float2bfloat16(v * inv);
  }
}

// ---------------- final 512x2 output (f32 out) ----------------
__global__ void final_out_kernel(const float* __restrict__ f3, const void* __restrict__ Wo,
                                 const void* __restrict__ bo, float* __restrict__ out) {
  int r = blockIdx.x;
  int lane = threadIdx.x;
  float x0 = f3[(size_t)r * 128 + lane], x1v = f3[(size_t)r * 128 + 64 + lane];
  float s0 = x0 * ldf(Wo, lane) + x1v * ldf(Wo, 64 + lane);
  float s1 = x0 * ldf(Wo, 128 + lane) + x1v * ldf(Wo, 192 + lane);
#pragma unroll
  for (int o = 32; o > 0; o >>= 1) { s0 += __shfl_down(s0, o); s1 += __shfl_down(s1, o); }
  if (lane == 0) {
    out[r * 2] = s0 + ldf(bo, 0);
    out[r * 2 + 1] = s1 + ldf(bo, 1);
  }
}

// ---------------- host ----------------

extern "C" void kernel_launch(void* const* d_in, const int* in_sizes, int n_in,
                              void* d_out, int out_size, void* d_ws, size_t ws_size,
                              hipStream_t stream) {
  const void* x1 = d_in[0];
  const int* ei1 = (const int*)d_in[1];
  const void* x2 = d_in[3];
  const int* ei2 = (const int*)d_in[4];
  const void* cell = d_in[6];
  const void* W1 = d_in[7];
  const void* a1s = d_in[8];
  const void* a1d = d_in[9];
  const void* b1 = d_in[10];
  const void* W2 = d_in[11];
  const void* a2s = d_in[12];
  const void* a2d = d_in[13];
  const void* b2 = d_in[14];
  const void* Wg = d_in[15];
  const void* bg = d_in[16];
  const void* Wr1 = d_in[17]; const void* br1 = d_in[18];
  const void* Wr2 = d_in[19]; const void* br2 = d_in[20];
  const void* Wr3 = d_in[21]; const void* br3 = d_in[22];
  const void* Wf1 = d_in[23]; const void* bf1 = d_in[24];
  const void* Wf2 = d_in[25]; const void* bf2 = d_in[26];
  const void* Wf3 = d_in[27]; const void* bf3 = d_in[28];
  const void* Wo = d_in[29]; const void* bo = d_in[30];

  char* base = (char*)d_ws;
  size_t off = 0;
  auto alloc = [&](size_t bytes) -> void* {
    void* p = base + off;
    off = (off + bytes + 255) & ~(size_t)255;
    return p;
  };
  bf16* d_xpad = (bf16*)alloc((size_t)10 * MP * 64 * 2);
  bf16* d_W1b = (bf16*)alloc((size_t)5 * 1280 * 64 * 2);
  bf16* d_W2b = (bf16*)alloc((size_t)5 * 128 * 1280 * 2);
  bf16* d_Wgb = (bf16*)alloc((size_t)5 * 128 * 128 * 2);
  bf16* d_Wr1b = (bf16*)alloc((size_t)2048 * 960 * 2);
  bf16* d_Wr2b = (bf16*)alloc((size_t)512 * 2048 * 2);
  bf16* d_Wr3b = (bf16*)alloc((size_t)256 * 512 * 2);
  bf16* d_Wf1b = (bf16*)alloc((size_t)2048 * 512 * 2);
  bf16* d_Wf2b = (bf16*)alloc((size_t)512 * 2048 * 2);
  bf16* d_Wf3b = (bf16*)alloc((size_t)128 * 512 * 2);
  int* d_offs = (int*)alloc((size_t)10 * (NN + 1) * 4);
  int* d_srcs = (int*)alloc((size_t)10 * NE * 4);
  int* d_cnt = (int*)alloc((size_t)10 * NN * 4);
  bf16* d_walrb = (bf16*)alloc((size_t)5 * 64 * 64 * 2);
  float* d_alr = (float*)alloc((size_t)10 * MP * 32 * 4);
  float* d_al2 = (float*)alloc((size_t)20 * NN * 4);  // al2 [10][NN] then ar2 [10][NN]
  float* d_ar2 = d_al2 + (size_t)10 * NN;
  bf16* d_h2all = (bf16*)alloc((size_t)10 * MP * 128 * 2);
  // alpha rows for up to 10 planes: [(NE+NN) rows][24B]
  unsigned int* d_alphaG = (unsigned int*)alloc((size_t)10 * (NE + NN) * 24);
  // uni region: xagg2 (G planes) overlaid with tail buffers.
  char* uni = base + off;
  size_t avail = (ws_size > off) ? (ws_size - off) : 0;
  size_t need10 = (size_t)10 * 10 * MP * 64 * 2;  // 129,433,600
  int G = (avail >= need10 + 65536) ? 10 : 5;
  bf16* d_xagg2 = (bf16*)uni;                // G x 10 x MP x 64 x 2
  bf16* d_out2all = (bf16*)uni;              // 10 x NN x 128 x 2 = 25,600,000 B
  bf16* d_gall = (bf16*)(uni + 25600000);    // 1,310,720 B
  float* d_xc = (float*)(uni + 26910720);    // 1,048,576 B
  bf16* d_xcb = (bf16*)(uni + 27959296);     // 524,288 B
  bf16* d_cnb = (bf16*)(uni + 28483584);     // 983,040 B
  bf16* d_m1b = (bf16*)(uni + 29466624);     // 2,097,152 B
  bf16* d_m2b = (bf16*)(uni + 31563776);     // 524,288 B
  float* d_f3 = (float*)(uni + 32088064);    // 262,144 B

  ConvTable tab;
  tab.d[0] = {x1, d_xpad, NN, FXD, MP, 64, 2, 0, 5, (MP + 3) / 4};
  tab.d[1] = {x2, d_xpad, NN, FXD, MP, 64, 2, 1, 5, (MP + 3) / 4};
  tab.d[2] = {W1, d_W1b, 1280, FXD, 1280, 64, 1, 0, 5, 320};
  tab.d[3] = {W2, d_W2b, 128, 1280, 128, 1280, 1, 0, 5, 32};
  tab.d[4] = {Wg, d_Wgb, 128, 128, 128, 128, 1, 0, 5, 32};
  tab.d[5] = {Wr1, d_Wr1b, 2048, FXT, 2048, 960, 1, 0, 1, 512};
  tab.d[6] = {Wr2, d_Wr2b, 512, 2048, 512, 2048, 1, 0, 1, 128};
  tab.d[7] = {Wr3, d_Wr3b, 256, 512, 256, 512, 1, 0, 1, 64};
  tab.d[8] = {Wf1, d_Wf1b, 2048, 512, 2048, 512, 1, 0, 1, 512};
  tab.d[9] = {Wf2, d_Wf2b, 512, 2048, 512, 2048, 1, 0, 1, 128};
  tab.d[10] = {Wf3, d_Wf3b, 128, 512, 128, 512, 1, 0, 1, 32};
  {
    int cum = 0;
    tab.blk0[0] = 0;
    for (int i = 0; i < 11; i++) {
      cum += tab.d[i].rowBlocks * tab.d[i].batch;
      tab.blk0[i + 1] = cum;
    }
    convert_all_kernel<<<dim3(cum), 256, 0, stream>>>(tab);
  }

  // CSR for all 10 planes
  hipMemsetAsync(d_cnt, 0, (size_t)10 * NN * 4, stream);
  hist_kernel<<<dim3((NE + 255) / 256, 1, 10), 256, 0, stream>>>(ei1, ei2, d_cnt);
  scan_kernel<<<10, 256, 0, stream>>>(d_cnt, d_offs);
  hipMemsetAsync(d_cnt, 0, (size_t)10 * NN * 4, stream);
  scatter_kernel<<<dim3((NE + 255) / 256, 1, 10), 256, 0, stream>>>(ei1, ei2, d_offs, d_cnt, d_srcs);

  // layer-1 attention logits: alr = xpad @ walrb^T (cols 0-9 al, 16-25 ar; others unused)
  walr_kernel<<<50, 256, 0, stream>>>(W1, a1s, a1d, d_walrb);
  mfma_gemm64<<<dim3(1, MP / 64, 10), 256, 0, stream>>>(
      d_xpad, (long)MP * 64, d_walrb, 4096, 1, nullptr, 0, 0,
      d_alr, (long)MP * 32, 32, 0, 32, 0, nullptr, 0, 0, 64, 0, 1.f);

  for (int pb = 0; pb < 10; pb += G) {
    alpha_kernel<<<dim3(NN / 16, 1, G), 256, 0, stream>>>(d_alr, d_offs, d_srcs, d_alphaG, pb);
    xagg_kernel<<<dim3(MP / 16, 1, G), 256, 0, stream>>>(d_xpad, d_alphaG, d_offs, d_srcs, d_xagg2, pb);
    fused_l1l2_kernel<<<dim3(1, MP / 64, G), 512, 0, stream>>>(
        d_xagg2, d_W1b, b1, d_W2b, a2s, a2d, d_al2, d_ar2, d_h2all, pb);
  }

  // batched tail over all 10 planes
  hipMemsetAsync(d_xc, 0, (size_t)BB * 512 * 4, stream);
  gat_agg2_kernel<<<dim3(NN / 16, 1, 10), 256, 0, stream>>>(
      d_h2all, d_al2, d_ar2, d_offs, d_srcs, b2, d_out2all);
  pool_max_kernel<<<dim3(BB / 4, 1, 10), 256, 0, stream>>>(d_out2all, d_gall);
  // xc[:, (z&1)*128 : +128] += relu(g_z @ Wg_{z>>1}^T + bg_{z>>1}) * 0.2, one dispatch
  mfma_gemm64<<<dim3(2, BB / 64, 10), 256, 0, stream>>>(
      d_gall, (long)BB * 128, d_Wgb, 128 * 128, 1,
      bg, 0, 128,
      d_xc, 0, 512, 2, 128, 128, nullptr, 0, 0, 128, 1, 0.2f);

  // cell reduction MLP -> xc[:,256:512]
  l2norm_b_kernel<<<BB, 256, 0, stream>>>((const float*)cell, d_cnb, FXT, 960);
  mfma_gemm64<<<dim3(32, 8, 1), 256, 0, stream>>>(
      d_cnb, 0, d_Wr1b, 0, 0, br1, 0, 0, nullptr, 0, 0, 0, 1 << 30, 0, d_m1b, 0, 2048, 960, 1, 1.f);
  mfma_gemm64<<<dim3(8, 8, 1), 256, 0, stream>>>(
      d_m1b, 0, d_Wr2b, 0, 0, br2, 0, 0, nullptr, 0, 0, 0, 1 << 30, 0, d_m2b, 0, 512, 2048, 1, 1.f);
  mfma_gemm64<<<dim3(4, 8, 1), 256, 0, stream>>>(
      d_m2b, 0, d_Wr3b, 0, 0, br3, 0, 0, d_xc + 256, 0, 512, 0, 1 << 30, 0, nullptr, 0, 0, 512, 1, 1.f);

  // head MLP
  l2norm_b_kernel<<<BB, 256, 0, stream>>>(d_xc, d_xcb, 512, 512);
  mfma_gemm64<<<dim3(32, 8, 1), 256, 0, stream>>>(
      d_xcb, 0, d_Wf1b, 0, 0, bf1, 0, 0, nullptr, 0, 0, 0, 1 << 30, 0, d_m1b, 0, 2048, 512, 1, 1.f);
  mfma_gemm64<<<dim3(8, 8, 1), 256, 0, stream>>>(
      d_m1b, 0, d_Wf2b, 0, 0, bf2, 0, 0, nullptr, 0, 0, 0, 1 << 30, 0, d_m2b, 0, 512, 2048, 1, 1.f);
  mfma_gemm64<<<dim3(2, 8, 1), 256, 0, stream>>>(
      d_m2b, 0, d_Wf3b, 0, 0, bf3, 0, 0, d_f3, 0, 128, 0, 1 << 30, 0, nullptr, 0, 0, 512, 1, 1.f);
  final_out_kernel<<<BB, 64, 0, stream>>>(d_f3, Wo, bo, (float*)d_out);
}